// Round 8
// baseline (804.426 us; speedup 1.0000x reference)
//
#include <hip/hip_runtime.h>
#include <math.h>

#define NN 100000
#define NE 1600000
#define DF 256
#define HH 64
#define TT 4
#define GG 8
#define BN_EPS 1e-5f

#define SCAN_BLK 1024
#define NB_SCAN ((NN + SCAN_BLK - 1) / SCAN_BLK)   // 98

typedef __attribute__((ext_vector_type(8))) short short8v;
typedef __attribute__((ext_vector_type(4))) float f32x4;
typedef unsigned short ushort_t;
typedef unsigned int uint_t;

__device__ __forceinline__ void atomicMaxF(float* addr, float val) {
  if (val >= 0.f) atomicMax((int*)addr, __float_as_int(val));
  else            atomicMin((unsigned int*)addr, __float_as_uint(val));
}

// fp32 -> bf16 bits, round-to-nearest-even
__device__ __forceinline__ short f2bf(float f) {
  uint_t u = __float_as_uint(f);
  u += 0x7FFFu + ((u >> 16) & 1u);
  return (short)(u >> 16);
}
__device__ __forceinline__ float bflo(uint_t u) { return __uint_as_float(u << 16); }
__device__ __forceinline__ float bfhi(uint_t u) { return __uint_as_float(u & 0xFFFF0000u); }

// ---------------- init ----------------
__global__ void k_init(float* __restrict__ stats, float* __restrict__ maxb) {
  int i = threadIdx.x;
  if (i < 512) stats[i] = 0.f;
  if (i < 64)  maxb[i]  = -INFINITY;
}

// ---------------- prep: fp32 -> bf16 bits ----------------
__global__ void k_prep(const float* __restrict__ W, ushort_t* __restrict__ Wbf, int n) {
  int i = blockIdx.x * 256 + threadIdx.x;
  if (i < n) Wbf[i] = (ushort_t)f2bf(W[i]);
}

// ---------------- GEMM1 (MFMA bf16): h1 = x @ W_first + b, + BN stats ----------------
__global__ __launch_bounds__(256, 2) void k_gemm1_mfma(
    const float* __restrict__ x, const ushort_t* __restrict__ Wbf,
    const float* __restrict__ b, float* __restrict__ h1,
    float* __restrict__ stats) {
  const int lane = threadIdx.x & 63;
  const int li = lane & 15;
  const int lh = lane >> 4;
  const int gw = (blockIdx.x * 256 + (int)threadIdx.x) >> 6;
  const int nw = (gridDim.x * 256) >> 6;

  short8v bf[8][4];
#pragma unroll
  for (int s = 0; s < 8; ++s)
#pragma unroll
    for (int ct = 0; ct < 4; ++ct)
#pragma unroll
      for (int e = 0; e < 8; ++e)
        bf[s][ct][e] = (short)Wbf[(32 * s + 8 * lh + e) * HH + ct * 16 + li];

  float bias[4];
#pragma unroll
  for (int ct = 0; ct < 4; ++ct) bias[ct] = b[ct * 16 + li];

  float ps[4] = {0.f, 0.f, 0.f, 0.f}, pss[4] = {0.f, 0.f, 0.f, 0.f};

  for (int t = gw; t < NN / 16; t += nw) {
    const float* xb = x + (size_t)(t * 16 + li) * DF + 8 * lh;
    f32x4 acc[4];
#pragma unroll
    for (int ct = 0; ct < 4; ++ct) acc[ct] = (f32x4){0.f, 0.f, 0.f, 0.f};

#pragma unroll
    for (int s = 0; s < 8; ++s) {
      float4 a0 = *(const float4*)(xb + 32 * s);
      float4 a1 = *(const float4*)(xb + 32 * s + 4);
      short8v af;
      af[0] = f2bf(a0.x); af[1] = f2bf(a0.y); af[2] = f2bf(a0.z); af[3] = f2bf(a0.w);
      af[4] = f2bf(a1.x); af[5] = f2bf(a1.y); af[6] = f2bf(a1.z); af[7] = f2bf(a1.w);
#pragma unroll
      for (int ct = 0; ct < 4; ++ct)
        acc[ct] = __builtin_amdgcn_mfma_f32_16x16x32_bf16(af, bf[s][ct], acc[ct], 0, 0, 0);
    }

    float* hb = h1 + (size_t)t * 16 * HH;
#pragma unroll
    for (int ct = 0; ct < 4; ++ct) {
#pragma unroll
      for (int r = 0; r < 4; ++r) {
        float h = acc[ct][r] + bias[ct];
        hb[(lh * 4 + r) * HH + ct * 16 + li] = h;
        ps[ct] += h; pss[ct] += h * h;
      }
    }
  }

#pragma unroll
  for (int ct = 0; ct < 4; ++ct) {
    ps[ct]  += __shfl_xor(ps[ct], 16);  ps[ct]  += __shfl_xor(ps[ct], 32);
    pss[ct] += __shfl_xor(pss[ct], 16); pss[ct] += __shfl_xor(pss[ct], 32);
  }
  if (lane < 16) {
#pragma unroll
    for (int ct = 0; ct < 4; ++ct) {
      atomicAdd(&stats[ct * 16 + lane], ps[ct]);
      atomicAdd(&stats[HH + ct * 16 + lane], pss[ct]);
    }
  }
}

// ---------------- BN finalize ----------------
__global__ void k_finalize_bn(const float* __restrict__ sums,
                              const float* __restrict__ gamma,
                              const float* __restrict__ beta,
                              float* __restrict__ ab) {
  int c = threadIdx.x;                                // 64 threads
  float mu  = sums[c] * (1.f / NN);
  float var = sums[HH + c] * (1.f / NN) - mu * mu;
  float a = gamma[c] * rsqrtf(var + BN_EPS);
  ab[c] = a;
  ab[HH + c] = beta[c] - mu * a;
}

// ---------------- fused: normalize(h1)+ReLU -> f; np0 + max-pool via 5th MFMA
//                  column-tile; g = f @ W_conv (bf16 out) ----------------
// A-layout: lane->(row=li, k=8*lh+e). D-layout: lane,reg->(row=lh*4+r, col=li).
__global__ __launch_bounds__(256) void k_norm_gemm2(
    const float* __restrict__ h1, const float* __restrict__ ab,
    const float* __restrict__ Wl0, const float* __restrict__ bl0,
    const int* __restrict__ batch, const ushort_t* __restrict__ Wbf2,
    float* __restrict__ node_pred, float* __restrict__ maxbuf,
    ushort_t* __restrict__ g) {
  __shared__ float lmax[GG * TT];
  if (threadIdx.x < GG * TT) lmax[threadIdx.x] = -INFINITY;
  __syncthreads();

  const int lane = threadIdx.x & 63;
  const int li = lane & 15;
  const int lh = lane >> 4;
  const int gw = (blockIdx.x * 256 + (int)threadIdx.x) >> 6;
  const int nw = (gridDim.x * 256) >> 6;

  short8v bfr[2][4];                    // W_conv B-frags
#pragma unroll
  for (int s = 0; s < 2; ++s)
#pragma unroll
    for (int ct = 0; ct < 4; ++ct)
#pragma unroll
      for (int e = 0; e < 8; ++e)
        bfr[s][ct][e] = (short)Wbf2[(32 * s + 8 * lh + e) * HH + ct * 16 + li];

  short8v bhd[2];                       // head B-frag (zero-padded cols 4..15)
#pragma unroll
  for (int s = 0; s < 2; ++s)
#pragma unroll
    for (int e = 0; e < 8; ++e)
      bhd[s][e] = (li < TT) ? f2bf(Wl0[(32 * s + 8 * lh + e) * TT + li]) : (short)0;

  // BN scale/shift for this lane's k-columns (8lh.. and 32+8lh..)
  const float4 sa0 = *(const float4*)(ab + 8 * lh);
  const float4 sa1 = *(const float4*)(ab + 8 * lh + 4);
  const float4 sb0 = *(const float4*)(ab + HH + 8 * lh);
  const float4 sb1 = *(const float4*)(ab + HH + 8 * lh + 4);
  const float4 ta0 = *(const float4*)(ab + 32 + 8 * lh);
  const float4 ta1 = *(const float4*)(ab + 32 + 8 * lh + 4);
  const float4 tb0 = *(const float4*)(ab + HH + 32 + 8 * lh);
  const float4 tb1 = *(const float4*)(ab + HH + 32 + 8 * lh + 4);
  const float blv = (li < TT) ? bl0[li] : 0.f;

  for (int t = gw; t < NN / 16; t += nw) {
    const float* hb = h1 + (size_t)(t * 16 + li) * HH + 8 * lh;
    float4 x0 = *(const float4*)(hb);
    float4 x1 = *(const float4*)(hb + 4);
    float4 x2 = *(const float4*)(hb + 32);
    float4 x3 = *(const float4*)(hb + 36);

    short8v af0, af1;
    af0[0] = f2bf(fmaxf(fmaf(sa0.x, x0.x, sb0.x), 0.f));
    af0[1] = f2bf(fmaxf(fmaf(sa0.y, x0.y, sb0.y), 0.f));
    af0[2] = f2bf(fmaxf(fmaf(sa0.z, x0.z, sb0.z), 0.f));
    af0[3] = f2bf(fmaxf(fmaf(sa0.w, x0.w, sb0.w), 0.f));
    af0[4] = f2bf(fmaxf(fmaf(sa1.x, x1.x, sb1.x), 0.f));
    af0[5] = f2bf(fmaxf(fmaf(sa1.y, x1.y, sb1.y), 0.f));
    af0[6] = f2bf(fmaxf(fmaf(sa1.z, x1.z, sb1.z), 0.f));
    af0[7] = f2bf(fmaxf(fmaf(sa1.w, x1.w, sb1.w), 0.f));
    af1[0] = f2bf(fmaxf(fmaf(ta0.x, x2.x, tb0.x), 0.f));
    af1[1] = f2bf(fmaxf(fmaf(ta0.y, x2.y, tb0.y), 0.f));
    af1[2] = f2bf(fmaxf(fmaf(ta0.z, x2.z, tb0.z), 0.f));
    af1[3] = f2bf(fmaxf(fmaf(ta0.w, x2.w, tb0.w), 0.f));
    af1[4] = f2bf(fmaxf(fmaf(ta1.x, x3.x, tb1.x), 0.f));
    af1[5] = f2bf(fmaxf(fmaf(ta1.y, x3.y, tb1.y), 0.f));
    af1[6] = f2bf(fmaxf(fmaf(ta1.z, x3.z, tb1.z), 0.f));
    af1[7] = f2bf(fmaxf(fmaf(ta1.w, x3.w, tb1.w), 0.f));

    f32x4 acc[4], acch;
#pragma unroll
    for (int ct = 0; ct < 4; ++ct) {
      acc[ct] = (f32x4){0.f, 0.f, 0.f, 0.f};
      acc[ct] = __builtin_amdgcn_mfma_f32_16x16x32_bf16(af0, bfr[0][ct], acc[ct], 0, 0, 0);
      acc[ct] = __builtin_amdgcn_mfma_f32_16x16x32_bf16(af1, bfr[1][ct], acc[ct], 0, 0, 0);
    }
    acch = (f32x4){0.f, 0.f, 0.f, 0.f};
    acch = __builtin_amdgcn_mfma_f32_16x16x32_bf16(af0, bhd[0], acch, 0, 0, 0);
    acch = __builtin_amdgcn_mfma_f32_16x16x32_bf16(af1, bhd[1], acch, 0, 0, 0);

    ushort_t* gb = g + (size_t)t * 16 * HH;
#pragma unroll
    for (int ct = 0; ct < 4; ++ct)
#pragma unroll
      for (int r = 0; r < 4; ++r)
        gb[(lh * 4 + r) * HH + ct * 16 + li] = (ushort_t)f2bf(acc[ct][r]);

    if (li < TT) {
#pragma unroll
      for (int r = 0; r < 4; ++r) {
        int row = t * 16 + lh * 4 + r;
        float np = acch[r] + blv;
        atomicMaxF(&lmax[batch[row] * TT + li], np);
        node_pred[(size_t)row * TT + li] = np;
      }
    }
  }
  __syncthreads();
  if (threadIdx.x < GG * TT) atomicMaxF(&maxbuf[threadIdx.x], lmax[threadIdx.x]);
}

// ---------------- normalize+ReLU + head + max-pool (layer 1 epilogue) ----------------
template <int WRITEF, int ADDOUT>
__global__ __launch_bounds__(256) void k_norm_np(
    const float* __restrict__ hin, ushort_t* __restrict__ fout,
    const float* __restrict__ ab, const float* __restrict__ Wlin,
    const float* __restrict__ blin, const int* __restrict__ batch,
    float* __restrict__ node_pred, float* __restrict__ maxbuf, int rpb) {
  __shared__ float lmax[GG * TT];
  if (threadIdx.x < GG * TT) lmax[threadIdx.x] = -INFINITY;
  __syncthreads();

  const int lane = threadIdx.x & 63;
  const int wid  = threadIdx.x >> 6;
  const float a  = ab[lane];
  const float b2 = ab[HH + lane];
  const float4 w = ((const float4*)Wlin)[lane];       // W[lane][0..3]
  const float4 bl = *(const float4*)blin;
  int r0 = blockIdx.x * rpb;
  int r1 = min(r0 + rpb, NN);

  for (int r = r0 + wid; r < r1; r += 4) {
    float h = hin[(size_t)r * HH + lane];
    float f = fmaxf(fmaf(a, h, b2), 0.f);
    if (WRITEF) fout[(size_t)r * HH + lane] = (ushort_t)f2bf(f);
    float p0 = f * w.x, p1 = f * w.y, p2 = f * w.z, p3 = f * w.w;
#pragma unroll
    for (int off = 32; off; off >>= 1) {
      p0 += __shfl_xor(p0, off);
      p1 += __shfl_xor(p1, off);
      p2 += __shfl_xor(p2, off);
      p3 += __shfl_xor(p3, off);
    }
    if (lane == 0) {
      float4 np;
      np.x = p0 + bl.x; np.y = p1 + bl.y; np.z = p2 + bl.z; np.w = p3 + bl.w;
      int g = batch[r];
      atomicMaxF(&lmax[g * TT + 0], np.x);
      atomicMaxF(&lmax[g * TT + 1], np.y);
      atomicMaxF(&lmax[g * TT + 2], np.z);
      atomicMaxF(&lmax[g * TT + 3], np.w);
      float4* op = (float4*)(node_pred + (size_t)r * TT);
      if (ADDOUT) {
        float4 o = *op;
        np.x += o.x; np.y += o.y; np.z += o.z; np.w += o.w;
      }
      *op = np;
    }
  }
  __syncthreads();
  if (threadIdx.x < GG * TT) atomicMaxF(&maxbuf[threadIdx.x], lmax[threadIdx.x]);
}

// ---------------- CSR build ----------------
__global__ __launch_bounds__(256) void k_count(const int* __restrict__ ei,
                                               int* __restrict__ deg) {
  int i = blockIdx.x * blockDim.x + threadIdx.x;
  int n = gridDim.x * blockDim.x;
  for (int e = i; e < NE; e += n) atomicAdd(&deg[ei[NE + e]], 1);
}

__global__ __launch_bounds__(256) void k_scanA(const int* __restrict__ deg,
                                               int* __restrict__ rowstart,
                                               int* __restrict__ bsum) {
  __shared__ int s[256];
  int t = threadIdx.x;
  int base = blockIdx.x * SCAN_BLK + t * 4;
  int d0 = 0, d1 = 0, d2 = 0, d3 = 0;
  if (base + 3 < NN) {
    int4 v = *(const int4*)(deg + base);
    d0 = v.x; d1 = v.y; d2 = v.z; d3 = v.w;
  } else {
    if (base + 0 < NN) d0 = deg[base + 0];
    if (base + 1 < NN) d1 = deg[base + 1];
    if (base + 2 < NN) d2 = deg[base + 2];
    if (base + 3 < NN) d3 = deg[base + 3];
  }
  int ts = d0 + d1 + d2 + d3;
  s[t] = ts;
  __syncthreads();
  for (int off = 1; off < 256; off <<= 1) {
    int v = (t >= off) ? s[t - off] : 0;
    __syncthreads();
    s[t] += v;
    __syncthreads();
  }
  int excl = s[t] - ts;
  if (base + 0 < NN) rowstart[base + 0] = excl;  excl += d0;
  if (base + 1 < NN) rowstart[base + 1] = excl;  excl += d1;
  if (base + 2 < NN) rowstart[base + 2] = excl;  excl += d2;
  if (base + 3 < NN) rowstart[base + 3] = excl;
  if (t == 255) bsum[blockIdx.x] = s[255];
}

__global__ void k_scanB(const int* __restrict__ bsum, int* __restrict__ bscan) {
  __shared__ int s[128];
  int t = threadIdx.x;
  int v = (t < NB_SCAN) ? bsum[t] : 0;
  s[t] = v;
  __syncthreads();
  for (int off = 1; off < 128; off <<= 1) {
    int u = (t >= off) ? s[t - off] : 0;
    __syncthreads();
    s[t] += u;
    __syncthreads();
  }
  if (t < NB_SCAN) bscan[t] = s[t] - v;
}

__global__ __launch_bounds__(256) void k_scanC(int* __restrict__ rowstart,
                                               const int* __restrict__ bscan,
                                               int* __restrict__ cursor) {
  int off = bscan[blockIdx.x];
  int base = blockIdx.x * SCAN_BLK + threadIdx.x * 4;
#pragma unroll
  for (int j = 0; j < 4; ++j) {
    int i = base + j;
    if (i < NN) {
      int r = rowstart[i] + off;
      rowstart[i] = r;
      cursor[i] = r;
    }
  }
}

__global__ __launch_bounds__(256) void k_fill(const int* __restrict__ ei,
                                              int* __restrict__ cursor,
                                              int* __restrict__ srcl) {
  int i = blockIdx.x * blockDim.x + threadIdx.x;
  int n = gridDim.x * blockDim.x;
  for (int e = i; e < NE; e += n) {
    int src = ei[e];
    int dst = ei[NE + e];
    int p = atomicAdd(&cursor[dst], 1);
    srcl[p] = src;
  }
}

// ---------------- gather: h2[r] = b + g[r] + sum g[src], + BN stats ----------------
// bf16 g (128B/row), half-wave per row (32 lanes x uint), block-contiguous rows,
// inline-asm 8/4-deep gather blocks force loads in flight.
__global__ __launch_bounds__(256) void k_gather(
    const ushort_t* __restrict__ g, const int* __restrict__ rowstart,
    const int* __restrict__ deg, const int* __restrict__ srcl,
    const float* __restrict__ bias, float* __restrict__ h2,
    float* __restrict__ stats, int rpb) {
  const int lane = threadIdx.x & 63;
  const int wid  = threadIdx.x >> 6;
  const int hf   = lane >> 5;
  const int ql   = lane & 31;           // cols 2ql, 2ql+1
  const float2 bb = ((const float2*)bias)[ql];
  const uint_t* grow = (const uint_t*)g + ql;   // row r -> grow[r*32]
  int r0 = blockIdx.x * rpb;
  int r1 = min(r0 + rpb, NN);
  float psx = 0.f, psy = 0.f, pqx = 0.f, pqy = 0.f;

  for (int row = r0 + wid * 2 + hf; row < r1; row += 8) {
    int s0 = rowstart[row];
    int d  = deg[row];
    uint_t sv = grow[(size_t)row * 32];
    float ax = bb.x + bflo(sv);
    float ay = bb.y + bfhi(sv);
    int e = 0;
    for (; e + 8 <= d; e += 8) {
      int i0 = srcl[s0 + e + 0]; int i1 = srcl[s0 + e + 1];
      int i2 = srcl[s0 + e + 2]; int i3 = srcl[s0 + e + 3];
      int i4 = srcl[s0 + e + 4]; int i5 = srcl[s0 + e + 5];
      int i6 = srcl[s0 + e + 6]; int i7 = srcl[s0 + e + 7];
      const uint_t* p0 = grow + (size_t)i0 * 32;
      const uint_t* p1 = grow + (size_t)i1 * 32;
      const uint_t* p2 = grow + (size_t)i2 * 32;
      const uint_t* p3 = grow + (size_t)i3 * 32;
      const uint_t* p4 = grow + (size_t)i4 * 32;
      const uint_t* p5 = grow + (size_t)i5 * 32;
      const uint_t* p6 = grow + (size_t)i6 * 32;
      const uint_t* p7 = grow + (size_t)i7 * 32;
      uint_t v0, v1, v2, v3, v4, v5, v6, v7;
      asm volatile(
        "global_load_dword %0, %8, off\n\t"
        "global_load_dword %1, %9, off\n\t"
        "global_load_dword %2, %10, off\n\t"
        "global_load_dword %3, %11, off\n\t"
        "global_load_dword %4, %12, off\n\t"
        "global_load_dword %5, %13, off\n\t"
        "global_load_dword %6, %14, off\n\t"
        "global_load_dword %7, %15, off\n\t"
        "s_waitcnt vmcnt(0)"
        : "=&v"(v0), "=&v"(v1), "=&v"(v2), "=&v"(v3),
          "=&v"(v4), "=&v"(v5), "=&v"(v6), "=&v"(v7)
        : "v"(p0), "v"(p1), "v"(p2), "v"(p3),
          "v"(p4), "v"(p5), "v"(p6), "v"(p7)
        : "memory");
      ax += (bflo(v0) + bflo(v1)) + (bflo(v2) + bflo(v3))
          + (bflo(v4) + bflo(v5)) + (bflo(v6) + bflo(v7));
      ay += (bfhi(v0) + bfhi(v1)) + (bfhi(v2) + bfhi(v3))
          + (bfhi(v4) + bfhi(v5)) + (bfhi(v6) + bfhi(v7));
    }
    if (e + 4 <= d) {
      int i0 = srcl[s0 + e + 0]; int i1 = srcl[s0 + e + 1];
      int i2 = srcl[s0 + e + 2]; int i3 = srcl[s0 + e + 3];
      const uint_t* p0 = grow + (size_t)i0 * 32;
      const uint_t* p1 = grow + (size_t)i1 * 32;
      const uint_t* p2 = grow + (size_t)i2 * 32;
      const uint_t* p3 = grow + (size_t)i3 * 32;
      uint_t v0, v1, v2, v3;
      asm volatile(
        "global_load_dword %0, %4, off\n\t"
        "global_load_dword %1, %5, off\n\t"
        "global_load_dword %2, %6, off\n\t"
        "global_load_dword %3, %7, off\n\t"
        "s_waitcnt vmcnt(0)"
        : "=&v"(v0), "=&v"(v1), "=&v"(v2), "=&v"(v3)
        : "v"(p0), "v"(p1), "v"(p2), "v"(p3)
        : "memory");
      ax += (bflo(v0) + bflo(v1)) + (bflo(v2) + bflo(v3));
      ay += (bfhi(v0) + bfhi(v1)) + (bfhi(v2) + bfhi(v3));
      e += 4;
    }
    for (; e < d; ++e) {
      uint_t v = grow[(size_t)srcl[s0 + e] * 32];
      ax += bflo(v); ay += bfhi(v);
    }
    float2 o; o.x = ax; o.y = ay;
    *(float2*)(h2 + (size_t)row * HH + ql * 2) = o;
    psx += ax; psy += ay; pqx += ax * ax; pqy += ay * ay;
  }

  psx += __shfl_xor(psx, 32); psy += __shfl_xor(psy, 32);
  pqx += __shfl_xor(pqx, 32); pqy += __shfl_xor(pqy, 32);
  if (lane < 32) {
    atomicAdd(&stats[ql * 2 + 0], psx);
    atomicAdd(&stats[ql * 2 + 1], psy);
    atomicAdd(&stats[HH + ql * 2 + 0], pqx);
    atomicAdd(&stats[HH + ql * 2 + 1], pqy);
  }
}

// ---------------- final: wsi = max0 + max1 ----------------
__global__ void k_wsi(const float* __restrict__ m0, const float* __restrict__ m1,
                      float* __restrict__ out) {
  int i = threadIdx.x;
  out[i] = m0[i] + m1[i];
}

extern "C" void kernel_launch(void* const* d_in, const int* in_sizes, int n_in,
                              void* d_out, int out_size, void* d_ws, size_t ws_size,
                              hipStream_t stream) {
  const float* x    = (const float*)d_in[0];
  const int*   ei   = (const int*)d_in[1];
  const int*   bat  = (const int*)d_in[2];
  const float* Wf   = (const float*)d_in[3];
  const float* bf   = (const float*)d_in[4];
  const float* g1   = (const float*)d_in[5];
  const float* be1  = (const float*)d_in[6];
  const float* Wl0  = (const float*)d_in[7];
  const float* bl0  = (const float*)d_in[8];
  const float* Wc   = (const float*)d_in[9];
  const float* bc   = (const float*)d_in[10];
  const float* g2   = (const float*)d_in[11];
  const float* be2  = (const float*)d_in[12];
  const float* Wl1  = (const float*)d_in[13];
  const float* bl1  = (const float*)d_in[14];

  float* out   = (float*)d_out;
  float* wsi   = out;                 // [8,4]
  float* npred = out + GG * TT;       // [N,4]

  float*    ws     = (float*)d_ws;
  float*    hbuf   = ws;                              // N*H fp32 (h1, then h2)
  ushort_t* gbf    = (ushort_t*)(hbuf + (size_t)NN * HH);  // N*H bf16 (g)
  float*    stats1 = (float*)(gbf + (size_t)NN * HH); // 256
  float*    stats2 = stats1 + 256;                    // 256
  float*    maxb   = stats2 + 256;                    // 64
  int*      deg      = (int*)(maxb + 64);             // N
  int*      rowstart = deg + NN;                      // N
  int*      cursor   = rowstart + NN;                 // N
  int*      bsum     = cursor + NN;                   // 128
  int*      bscan    = bsum + 128;                    // 128
  int*      srcl     = bscan + 128;                   // NE
  ushort_t* Wbf      = (ushort_t*)(srcl + NE);        // DF*HH
  ushort_t* Wbf2     = Wbf + DF * HH;                 // HH*HH

  hipMemsetAsync(deg, 0, NN * sizeof(int), stream);
  k_init<<<dim3(1), dim3(512), 0, stream>>>(stats1, maxb);
  k_prep<<<dim3(64), dim3(256), 0, stream>>>(Wf, Wbf, DF * HH);
  k_prep<<<dim3(16), dim3(256), 0, stream>>>(Wc, Wbf2, HH * HH);

  // CSR build
  k_count<<<dim3(1024), dim3(256), 0, stream>>>(ei, deg);
  k_scanA<<<dim3(NB_SCAN), dim3(256), 0, stream>>>(deg, rowstart, bsum);
  k_scanB<<<dim3(1), dim3(128), 0, stream>>>(bsum, bscan);
  k_scanC<<<dim3(NB_SCAN), dim3(256), 0, stream>>>(rowstart, bscan, cursor);
  k_fill<<<dim3(1024), dim3(256), 0, stream>>>(ei, cursor, srcl);

  // Layer 0: GEMM + stats
  k_gemm1_mfma<<<dim3(512), dim3(256), 0, stream>>>(x, Wbf, bf, hbuf, stats1);
  k_finalize_bn<<<dim3(1), dim3(64), 0, stream>>>(stats1, g1, be1, stats1 + 128);
  // fused: norm+ReLU + head0 + pool + g = f@Wc (bf16)
  k_norm_gemm2<<<dim3(512), dim3(256), 0, stream>>>(
      hbuf, stats1 + 128, Wl0, bl0, bat, Wbf2, npred, maxb, gbf);

  // Layer 1: h2 = b + g + A.g
  {
    int rpb = 48;
    int nb = (NN + rpb - 1) / rpb;            // 2084
    k_gather<<<dim3(nb), dim3(256), 0, stream>>>(
        gbf, rowstart, deg, srcl, bc, hbuf, stats2, rpb);
  }
  k_finalize_bn<<<dim3(1), dim3(64), 0, stream>>>(stats2, g2, be2, stats2 + 128);
  k_norm_np<0, 1><<<dim3(512), dim3(256), 0, stream>>>(
      hbuf, gbf, stats2 + 128, Wl1, bl1, bat, npred, maxb + 32, (NN + 511) / 512);

  k_wsi<<<dim3(1), dim3(32), 0, stream>>>(maxb, maxb + 32, wsi);
}

// Round 9
// 552.257 us; speedup vs baseline: 1.4566x; 1.4566x over previous
//
#include <hip/hip_runtime.h>
#include <math.h>

#define NN 100000
#define NE 1600000
#define DF 256
#define HH 64
#define TT 4
#define GG 8
#define BN_EPS 1e-5f

#define SCAN_BLK 1024
#define NB_SCAN ((NN + SCAN_BLK - 1) / SCAN_BLK)   // 98

typedef __attribute__((ext_vector_type(8))) short short8v;
typedef __attribute__((ext_vector_type(4))) float f32x4;
typedef unsigned short ushort_t;
typedef unsigned int uint_t;

__device__ __forceinline__ void atomicMaxF(float* addr, float val) {
  if (val >= 0.f) atomicMax((int*)addr, __float_as_int(val));
  else            atomicMin((unsigned int*)addr, __float_as_uint(val));
}

// fp32 -> bf16 bits, round-to-nearest-even
__device__ __forceinline__ short f2bf(float f) {
  uint_t u = __float_as_uint(f);
  u += 0x7FFFu + ((u >> 16) & 1u);
  return (short)(u >> 16);
}
__device__ __forceinline__ float bf2f(uint_t u) { return __uint_as_float(u << 16); }

// ---------------- init ----------------
__global__ void k_init(float* __restrict__ stats, float* __restrict__ maxb) {
  int i = threadIdx.x;
  if (i < 512) stats[i] = 0.f;
  if (i < 64)  maxb[i]  = -INFINITY;
}

// ---------------- prep: fp32 -> bf16 bits ----------------
__global__ void k_prep(const float* __restrict__ W, ushort_t* __restrict__ Wbf, int n) {
  int i = blockIdx.x * 256 + threadIdx.x;
  if (i < n) Wbf[i] = (ushort_t)f2bf(W[i]);
}

// ---------------- GEMM1 (MFMA bf16): h1 = x @ W_first + b, + BN stats ----------------
__global__ __launch_bounds__(256, 2) void k_gemm1_mfma(
    const float* __restrict__ x, const ushort_t* __restrict__ Wbf,
    const float* __restrict__ b, float* __restrict__ h1,
    float* __restrict__ stats) {
  const int lane = threadIdx.x & 63;
  const int li = lane & 15;
  const int lh = lane >> 4;
  const int gw = (blockIdx.x * 256 + (int)threadIdx.x) >> 6;
  const int nw = (gridDim.x * 256) >> 6;

  short8v bf[8][4];
#pragma unroll
  for (int s = 0; s < 8; ++s)
#pragma unroll
    for (int ct = 0; ct < 4; ++ct)
#pragma unroll
      for (int e = 0; e < 8; ++e)
        bf[s][ct][e] = (short)Wbf[(32 * s + 8 * lh + e) * HH + ct * 16 + li];

  float bias[4];
#pragma unroll
  for (int ct = 0; ct < 4; ++ct) bias[ct] = b[ct * 16 + li];

  float ps[4] = {0.f, 0.f, 0.f, 0.f}, pss[4] = {0.f, 0.f, 0.f, 0.f};

  for (int t = gw; t < NN / 16; t += nw) {
    const float* xb = x + (size_t)(t * 16 + li) * DF + 8 * lh;
    f32x4 acc[4];
#pragma unroll
    for (int ct = 0; ct < 4; ++ct) acc[ct] = (f32x4){0.f, 0.f, 0.f, 0.f};

#pragma unroll
    for (int s = 0; s < 8; ++s) {
      float4 a0 = *(const float4*)(xb + 32 * s);
      float4 a1 = *(const float4*)(xb + 32 * s + 4);
      short8v af;
      af[0] = f2bf(a0.x); af[1] = f2bf(a0.y); af[2] = f2bf(a0.z); af[3] = f2bf(a0.w);
      af[4] = f2bf(a1.x); af[5] = f2bf(a1.y); af[6] = f2bf(a1.z); af[7] = f2bf(a1.w);
#pragma unroll
      for (int ct = 0; ct < 4; ++ct)
        acc[ct] = __builtin_amdgcn_mfma_f32_16x16x32_bf16(af, bf[s][ct], acc[ct], 0, 0, 0);
    }

    float* hb = h1 + (size_t)t * 16 * HH;
#pragma unroll
    for (int ct = 0; ct < 4; ++ct) {
#pragma unroll
      for (int r = 0; r < 4; ++r) {
        float h = acc[ct][r] + bias[ct];
        hb[(lh * 4 + r) * HH + ct * 16 + li] = h;
        ps[ct] += h; pss[ct] += h * h;
      }
    }
  }

#pragma unroll
  for (int ct = 0; ct < 4; ++ct) {
    ps[ct]  += __shfl_xor(ps[ct], 16);  ps[ct]  += __shfl_xor(ps[ct], 32);
    pss[ct] += __shfl_xor(pss[ct], 16); pss[ct] += __shfl_xor(pss[ct], 32);
  }
  if (lane < 16) {
#pragma unroll
    for (int ct = 0; ct < 4; ++ct) {
      atomicAdd(&stats[ct * 16 + lane], ps[ct]);
      atomicAdd(&stats[HH + ct * 16 + lane], pss[ct]);
    }
  }
}

// ---------------- BN finalize ----------------
__global__ void k_finalize_bn(const float* __restrict__ sums,
                              const float* __restrict__ gamma,
                              const float* __restrict__ beta,
                              float* __restrict__ ab) {
  int c = threadIdx.x;                                // 64 threads
  float mu  = sums[c] * (1.f / NN);
  float var = sums[HH + c] * (1.f / NN) - mu * mu;
  float a = gamma[c] * rsqrtf(var + BN_EPS);
  ab[c] = a;
  ab[HH + c] = beta[c] - mu * a;
}

// ---------------- fused: normalize(h1)+ReLU; np0 + pool via 5th MFMA tile;
//                  g = f @ W_conv (bf16 out) ----------------
__global__ __launch_bounds__(256) void k_norm_gemm2(
    const float* __restrict__ h1, const float* __restrict__ ab,
    const float* __restrict__ Wl0, const float* __restrict__ bl0,
    const int* __restrict__ batch, const ushort_t* __restrict__ Wbf2,
    float* __restrict__ node_pred, float* __restrict__ maxbuf,
    ushort_t* __restrict__ g) {
  __shared__ float lmax[GG * TT];
  if (threadIdx.x < GG * TT) lmax[threadIdx.x] = -INFINITY;
  __syncthreads();

  const int lane = threadIdx.x & 63;
  const int li = lane & 15;
  const int lh = lane >> 4;
  const int gw = (blockIdx.x * 256 + (int)threadIdx.x) >> 6;
  const int nw = (gridDim.x * 256) >> 6;

  short8v bfr[2][4];                    // W_conv B-frags
#pragma unroll
  for (int s = 0; s < 2; ++s)
#pragma unroll
    for (int ct = 0; ct < 4; ++ct)
#pragma unroll
      for (int e = 0; e < 8; ++e)
        bfr[s][ct][e] = (short)Wbf2[(32 * s + 8 * lh + e) * HH + ct * 16 + li];

  short8v bhd[2];                       // head B-frag (zero-padded cols 4..15)
#pragma unroll
  for (int s = 0; s < 2; ++s)
#pragma unroll
    for (int e = 0; e < 8; ++e)
      bhd[s][e] = (li < TT) ? f2bf(Wl0[(32 * s + 8 * lh + e) * TT + li]) : (short)0;

  const float4 sa0 = *(const float4*)(ab + 8 * lh);
  const float4 sa1 = *(const float4*)(ab + 8 * lh + 4);
  const float4 sb0 = *(const float4*)(ab + HH + 8 * lh);
  const float4 sb1 = *(const float4*)(ab + HH + 8 * lh + 4);
  const float4 ta0 = *(const float4*)(ab + 32 + 8 * lh);
  const float4 ta1 = *(const float4*)(ab + 32 + 8 * lh + 4);
  const float4 tb0 = *(const float4*)(ab + HH + 32 + 8 * lh);
  const float4 tb1 = *(const float4*)(ab + HH + 32 + 8 * lh + 4);
  const float blv = (li < TT) ? bl0[li] : 0.f;

  for (int t = gw; t < NN / 16; t += nw) {
    const float* hb = h1 + (size_t)(t * 16 + li) * HH + 8 * lh;
    float4 x0 = *(const float4*)(hb);
    float4 x1 = *(const float4*)(hb + 4);
    float4 x2 = *(const float4*)(hb + 32);
    float4 x3 = *(const float4*)(hb + 36);

    short8v af0, af1;
    af0[0] = f2bf(fmaxf(fmaf(sa0.x, x0.x, sb0.x), 0.f));
    af0[1] = f2bf(fmaxf(fmaf(sa0.y, x0.y, sb0.y), 0.f));
    af0[2] = f2bf(fmaxf(fmaf(sa0.z, x0.z, sb0.z), 0.f));
    af0[3] = f2bf(fmaxf(fmaf(sa0.w, x0.w, sb0.w), 0.f));
    af0[4] = f2bf(fmaxf(fmaf(sa1.x, x1.x, sb1.x), 0.f));
    af0[5] = f2bf(fmaxf(fmaf(sa1.y, x1.y, sb1.y), 0.f));
    af0[6] = f2bf(fmaxf(fmaf(sa1.z, x1.z, sb1.z), 0.f));
    af0[7] = f2bf(fmaxf(fmaf(sa1.w, x1.w, sb1.w), 0.f));
    af1[0] = f2bf(fmaxf(fmaf(ta0.x, x2.x, tb0.x), 0.f));
    af1[1] = f2bf(fmaxf(fmaf(ta0.y, x2.y, tb0.y), 0.f));
    af1[2] = f2bf(fmaxf(fmaf(ta0.z, x2.z, tb0.z), 0.f));
    af1[3] = f2bf(fmaxf(fmaf(ta0.w, x2.w, tb0.w), 0.f));
    af1[4] = f2bf(fmaxf(fmaf(ta1.x, x3.x, tb1.x), 0.f));
    af1[5] = f2bf(fmaxf(fmaf(ta1.y, x3.y, tb1.y), 0.f));
    af1[6] = f2bf(fmaxf(fmaf(ta1.z, x3.z, tb1.z), 0.f));
    af1[7] = f2bf(fmaxf(fmaf(ta1.w, x3.w, tb1.w), 0.f));

    f32x4 acc[4], acch;
#pragma unroll
    for (int ct = 0; ct < 4; ++ct) {
      acc[ct] = (f32x4){0.f, 0.f, 0.f, 0.f};
      acc[ct] = __builtin_amdgcn_mfma_f32_16x16x32_bf16(af0, bfr[0][ct], acc[ct], 0, 0, 0);
      acc[ct] = __builtin_amdgcn_mfma_f32_16x16x32_bf16(af1, bfr[1][ct], acc[ct], 0, 0, 0);
    }
    acch = (f32x4){0.f, 0.f, 0.f, 0.f};
    acch = __builtin_amdgcn_mfma_f32_16x16x32_bf16(af0, bhd[0], acch, 0, 0, 0);
    acch = __builtin_amdgcn_mfma_f32_16x16x32_bf16(af1, bhd[1], acch, 0, 0, 0);

    ushort_t* gb = g + (size_t)t * 16 * HH;
#pragma unroll
    for (int ct = 0; ct < 4; ++ct)
#pragma unroll
      for (int r = 0; r < 4; ++r)
        gb[(lh * 4 + r) * HH + ct * 16 + li] = (ushort_t)f2bf(acc[ct][r]);

    if (li < TT) {
#pragma unroll
      for (int r = 0; r < 4; ++r) {
        int row = t * 16 + lh * 4 + r;
        float np = acch[r] + blv;
        atomicMaxF(&lmax[batch[row] * TT + li], np);
        node_pred[(size_t)row * TT + li] = np;
      }
    }
  }
  __syncthreads();
  if (threadIdx.x < GG * TT) atomicMaxF(&maxbuf[threadIdx.x], lmax[threadIdx.x]);
}

// ---------------- normalize+ReLU + head + max-pool (layer 1 epilogue) ----------------
template <int WRITEF, int ADDOUT>
__global__ __launch_bounds__(256) void k_norm_np(
    const float* __restrict__ hin, ushort_t* __restrict__ fout,
    const float* __restrict__ ab, const float* __restrict__ Wlin,
    const float* __restrict__ blin, const int* __restrict__ batch,
    float* __restrict__ node_pred, float* __restrict__ maxbuf, int rpb) {
  __shared__ float lmax[GG * TT];
  if (threadIdx.x < GG * TT) lmax[threadIdx.x] = -INFINITY;
  __syncthreads();

  const int lane = threadIdx.x & 63;
  const int wid  = threadIdx.x >> 6;
  const float a  = ab[lane];
  const float b2 = ab[HH + lane];
  const float4 w = ((const float4*)Wlin)[lane];       // W[lane][0..3]
  const float4 bl = *(const float4*)blin;
  int r0 = blockIdx.x * rpb;
  int r1 = min(r0 + rpb, NN);

  for (int r = r0 + wid; r < r1; r += 4) {
    float h = hin[(size_t)r * HH + lane];
    float f = fmaxf(fmaf(a, h, b2), 0.f);
    if (WRITEF) fout[(size_t)r * HH + lane] = (ushort_t)f2bf(f);
    float p0 = f * w.x, p1 = f * w.y, p2 = f * w.z, p3 = f * w.w;
#pragma unroll
    for (int off = 32; off; off >>= 1) {
      p0 += __shfl_xor(p0, off);
      p1 += __shfl_xor(p1, off);
      p2 += __shfl_xor(p2, off);
      p3 += __shfl_xor(p3, off);
    }
    if (lane == 0) {
      float4 np;
      np.x = p0 + bl.x; np.y = p1 + bl.y; np.z = p2 + bl.z; np.w = p3 + bl.w;
      int g = batch[r];
      atomicMaxF(&lmax[g * TT + 0], np.x);
      atomicMaxF(&lmax[g * TT + 1], np.y);
      atomicMaxF(&lmax[g * TT + 2], np.z);
      atomicMaxF(&lmax[g * TT + 3], np.w);
      float4* op = (float4*)(node_pred + (size_t)r * TT);
      if (ADDOUT) {
        float4 o = *op;
        np.x += o.x; np.y += o.y; np.z += o.z; np.w += o.w;
      }
      *op = np;
    }
  }
  __syncthreads();
  if (threadIdx.x < GG * TT) atomicMaxF(&maxbuf[threadIdx.x], lmax[threadIdx.x]);
}

// ---------------- CSR build ----------------
__global__ __launch_bounds__(256) void k_count(const int* __restrict__ ei,
                                               int* __restrict__ deg) {
  int i = blockIdx.x * blockDim.x + threadIdx.x;
  int n = gridDim.x * blockDim.x;
  for (int e = i; e < NE; e += n) atomicAdd(&deg[ei[NE + e]], 1);
}

__global__ __launch_bounds__(256) void k_scanA(const int* __restrict__ deg,
                                               int* __restrict__ rowstart,
                                               int* __restrict__ bsum) {
  __shared__ int s[256];
  int t = threadIdx.x;
  int base = blockIdx.x * SCAN_BLK + t * 4;
  int d0 = 0, d1 = 0, d2 = 0, d3 = 0;
  if (base + 3 < NN) {
    int4 v = *(const int4*)(deg + base);
    d0 = v.x; d1 = v.y; d2 = v.z; d3 = v.w;
  } else {
    if (base + 0 < NN) d0 = deg[base + 0];
    if (base + 1 < NN) d1 = deg[base + 1];
    if (base + 2 < NN) d2 = deg[base + 2];
    if (base + 3 < NN) d3 = deg[base + 3];
  }
  int ts = d0 + d1 + d2 + d3;
  s[t] = ts;
  __syncthreads();
  for (int off = 1; off < 256; off <<= 1) {
    int v = (t >= off) ? s[t - off] : 0;
    __syncthreads();
    s[t] += v;
    __syncthreads();
  }
  int excl = s[t] - ts;
  if (base + 0 < NN) rowstart[base + 0] = excl;  excl += d0;
  if (base + 1 < NN) rowstart[base + 1] = excl;  excl += d1;
  if (base + 2 < NN) rowstart[base + 2] = excl;  excl += d2;
  if (base + 3 < NN) rowstart[base + 3] = excl;
  if (t == 255) bsum[blockIdx.x] = s[255];
}

__global__ void k_scanB(const int* __restrict__ bsum, int* __restrict__ bscan) {
  __shared__ int s[128];
  int t = threadIdx.x;
  int v = (t < NB_SCAN) ? bsum[t] : 0;
  s[t] = v;
  __syncthreads();
  for (int off = 1; off < 128; off <<= 1) {
    int u = (t >= off) ? s[t - off] : 0;
    __syncthreads();
    s[t] += u;
    __syncthreads();
  }
  if (t < NB_SCAN) bscan[t] = s[t] - v;
}

__global__ __launch_bounds__(256) void k_scanC(int* __restrict__ rowstart,
                                               const int* __restrict__ bscan,
                                               int* __restrict__ cursor) {
  int off = bscan[blockIdx.x];
  int base = blockIdx.x * SCAN_BLK + threadIdx.x * 4;
#pragma unroll
  for (int j = 0; j < 4; ++j) {
    int i = base + j;
    if (i < NN) {
      int r = rowstart[i] + off;
      rowstart[i] = r;
      cursor[i] = r;
    }
  }
}

__global__ __launch_bounds__(256) void k_fill(const int* __restrict__ ei,
                                              int* __restrict__ cursor,
                                              int* __restrict__ srcl) {
  int i = blockIdx.x * blockDim.x + threadIdx.x;
  int n = gridDim.x * blockDim.x;
  for (int e = i; e < NE; e += n) {
    int src = ei[e];
    int dst = ei[NE + e];
    int p = atomicAdd(&cursor[dst], 1);
    srcl[p] = src;
  }
}

// ---------------- gather: h2[r] = b + g[r] + sum g[src], + BN stats ----------------
// FULL wave per row (lane = column, bf16 ushort loads, 128B/row/instr).
// Row index wave-uniform -> CSR metadata + edge indices in SGPRs (scalar pipe);
// gathers use vaddr(lane*2) + saddr(SGPR pair per edge). 16-deep asm blocks:
// one vmcnt wait covers a whole average-degree row.
__global__ __launch_bounds__(256) void k_gather(
    const ushort_t* __restrict__ g, const int* __restrict__ rowstart,
    const int* __restrict__ deg, const int* __restrict__ srcl,
    const float* __restrict__ bias, float* __restrict__ h2,
    float* __restrict__ stats, int rpb) {
  const int lane = threadIdx.x & 63;
  const int wid  = threadIdx.x >> 6;
  const float bc = bias[lane];
  const uint_t voff = lane * 2;          // byte offset within bf16 row
  int r0 = blockIdx.x * rpb;
  int r1 = min(r0 + rpb, NN);
  float ps = 0.f, pss = 0.f;

#define SPTR(I) (g + (size_t)(I) * HH)
  for (int row = r0 + wid; row < r1; row += 4) {
    int s0 = __builtin_amdgcn_readfirstlane(rowstart[row]);
    int d  = __builtin_amdgcn_readfirstlane(deg[row]);
    float acc = bc + bf2f(g[(size_t)row * HH + lane]);
    int e = 0;
    for (; e + 16 <= d; e += 16) {
      int i0  = __builtin_amdgcn_readfirstlane(srcl[s0 + e + 0]);
      int i1  = __builtin_amdgcn_readfirstlane(srcl[s0 + e + 1]);
      int i2  = __builtin_amdgcn_readfirstlane(srcl[s0 + e + 2]);
      int i3  = __builtin_amdgcn_readfirstlane(srcl[s0 + e + 3]);
      int i4  = __builtin_amdgcn_readfirstlane(srcl[s0 + e + 4]);
      int i5  = __builtin_amdgcn_readfirstlane(srcl[s0 + e + 5]);
      int i6  = __builtin_amdgcn_readfirstlane(srcl[s0 + e + 6]);
      int i7  = __builtin_amdgcn_readfirstlane(srcl[s0 + e + 7]);
      int i8  = __builtin_amdgcn_readfirstlane(srcl[s0 + e + 8]);
      int i9  = __builtin_amdgcn_readfirstlane(srcl[s0 + e + 9]);
      int i10 = __builtin_amdgcn_readfirstlane(srcl[s0 + e + 10]);
      int i11 = __builtin_amdgcn_readfirstlane(srcl[s0 + e + 11]);
      int i12 = __builtin_amdgcn_readfirstlane(srcl[s0 + e + 12]);
      int i13 = __builtin_amdgcn_readfirstlane(srcl[s0 + e + 13]);
      int i14 = __builtin_amdgcn_readfirstlane(srcl[s0 + e + 14]);
      int i15 = __builtin_amdgcn_readfirstlane(srcl[s0 + e + 15]);
      uint_t v0, v1, v2, v3, v4, v5, v6, v7;
      uint_t v8, v9, v10, v11, v12, v13, v14, v15;
      asm volatile(
        "global_load_ushort %0, %16, %17\n\t"
        "global_load_ushort %1, %16, %18\n\t"
        "global_load_ushort %2, %16, %19\n\t"
        "global_load_ushort %3, %16, %20\n\t"
        "global_load_ushort %4, %16, %21\n\t"
        "global_load_ushort %5, %16, %22\n\t"
        "global_load_ushort %6, %16, %23\n\t"
        "global_load_ushort %7, %16, %24\n\t"
        "global_load_ushort %8, %16, %25\n\t"
        "global_load_ushort %9, %16, %26\n\t"
        "global_load_ushort %10, %16, %27\n\t"
        "global_load_ushort %11, %16, %28\n\t"
        "global_load_ushort %12, %16, %29\n\t"
        "global_load_ushort %13, %16, %30\n\t"
        "global_load_ushort %14, %16, %31\n\t"
        "global_load_ushort %15, %16, %32\n\t"
        "s_waitcnt vmcnt(0)"
        : "=&v"(v0), "=&v"(v1), "=&v"(v2), "=&v"(v3),
          "=&v"(v4), "=&v"(v5), "=&v"(v6), "=&v"(v7),
          "=&v"(v8), "=&v"(v9), "=&v"(v10), "=&v"(v11),
          "=&v"(v12), "=&v"(v13), "=&v"(v14), "=&v"(v15)
        : "v"(voff),
          "s"(SPTR(i0)), "s"(SPTR(i1)), "s"(SPTR(i2)), "s"(SPTR(i3)),
          "s"(SPTR(i4)), "s"(SPTR(i5)), "s"(SPTR(i6)), "s"(SPTR(i7)),
          "s"(SPTR(i8)), "s"(SPTR(i9)), "s"(SPTR(i10)), "s"(SPTR(i11)),
          "s"(SPTR(i12)), "s"(SPTR(i13)), "s"(SPTR(i14)), "s"(SPTR(i15))
        : "memory");
      acc += ((bf2f(v0) + bf2f(v1)) + (bf2f(v2) + bf2f(v3)))
           + ((bf2f(v4) + bf2f(v5)) + (bf2f(v6) + bf2f(v7)))
           + ((bf2f(v8) + bf2f(v9)) + (bf2f(v10) + bf2f(v11)))
           + ((bf2f(v12) + bf2f(v13)) + (bf2f(v14) + bf2f(v15)));
    }
    if (e + 8 <= d) {
      int i0 = __builtin_amdgcn_readfirstlane(srcl[s0 + e + 0]);
      int i1 = __builtin_amdgcn_readfirstlane(srcl[s0 + e + 1]);
      int i2 = __builtin_amdgcn_readfirstlane(srcl[s0 + e + 2]);
      int i3 = __builtin_amdgcn_readfirstlane(srcl[s0 + e + 3]);
      int i4 = __builtin_amdgcn_readfirstlane(srcl[s0 + e + 4]);
      int i5 = __builtin_amdgcn_readfirstlane(srcl[s0 + e + 5]);
      int i6 = __builtin_amdgcn_readfirstlane(srcl[s0 + e + 6]);
      int i7 = __builtin_amdgcn_readfirstlane(srcl[s0 + e + 7]);
      uint_t v0, v1, v2, v3, v4, v5, v6, v7;
      asm volatile(
        "global_load_ushort %0, %8, %9\n\t"
        "global_load_ushort %1, %8, %10\n\t"
        "global_load_ushort %2, %8, %11\n\t"
        "global_load_ushort %3, %8, %12\n\t"
        "global_load_ushort %4, %8, %13\n\t"
        "global_load_ushort %5, %8, %14\n\t"
        "global_load_ushort %6, %8, %15\n\t"
        "global_load_ushort %7, %8, %16\n\t"
        "s_waitcnt vmcnt(0)"
        : "=&v"(v0), "=&v"(v1), "=&v"(v2), "=&v"(v3),
          "=&v"(v4), "=&v"(v5), "=&v"(v6), "=&v"(v7)
        : "v"(voff),
          "s"(SPTR(i0)), "s"(SPTR(i1)), "s"(SPTR(i2)), "s"(SPTR(i3)),
          "s"(SPTR(i4)), "s"(SPTR(i5)), "s"(SPTR(i6)), "s"(SPTR(i7))
        : "memory");
      acc += ((bf2f(v0) + bf2f(v1)) + (bf2f(v2) + bf2f(v3)))
           + ((bf2f(v4) + bf2f(v5)) + (bf2f(v6) + bf2f(v7)));
      e += 8;
    }
    if (e + 4 <= d) {
      int i0 = __builtin_amdgcn_readfirstlane(srcl[s0 + e + 0]);
      int i1 = __builtin_amdgcn_readfirstlane(srcl[s0 + e + 1]);
      int i2 = __builtin_amdgcn_readfirstlane(srcl[s0 + e + 2]);
      int i3 = __builtin_amdgcn_readfirstlane(srcl[s0 + e + 3]);
      uint_t v0, v1, v2, v3;
      asm volatile(
        "global_load_ushort %0, %4, %5\n\t"
        "global_load_ushort %1, %4, %6\n\t"
        "global_load_ushort %2, %4, %7\n\t"
        "global_load_ushort %3, %4, %8\n\t"
        "s_waitcnt vmcnt(0)"
        : "=&v"(v0), "=&v"(v1), "=&v"(v2), "=&v"(v3)
        : "v"(voff),
          "s"(SPTR(i0)), "s"(SPTR(i1)), "s"(SPTR(i2)), "s"(SPTR(i3))
        : "memory");
      acc += (bf2f(v0) + bf2f(v1)) + (bf2f(v2) + bf2f(v3));
      e += 4;
    }
    for (; e < d; ++e)
      acc += bf2f(g[(size_t)srcl[s0 + e] * HH + lane]);

    h2[(size_t)row * HH + lane] = acc;
    ps += acc; pss += acc * acc;
  }
#undef SPTR
  atomicAdd(&stats[lane], ps);
  atomicAdd(&stats[HH + lane], pss);
}

// ---------------- final: wsi = max0 + max1 ----------------
__global__ void k_wsi(const float* __restrict__ m0, const float* __restrict__ m1,
                      float* __restrict__ out) {
  int i = threadIdx.x;
  out[i] = m0[i] + m1[i];
}

extern "C" void kernel_launch(void* const* d_in, const int* in_sizes, int n_in,
                              void* d_out, int out_size, void* d_ws, size_t ws_size,
                              hipStream_t stream) {
  const float* x    = (const float*)d_in[0];
  const int*   ei   = (const int*)d_in[1];
  const int*   bat  = (const int*)d_in[2];
  const float* Wf   = (const float*)d_in[3];
  const float* bf   = (const float*)d_in[4];
  const float* g1   = (const float*)d_in[5];
  const float* be1  = (const float*)d_in[6];
  const float* Wl0  = (const float*)d_in[7];
  const float* bl0  = (const float*)d_in[8];
  const float* Wc   = (const float*)d_in[9];
  const float* bc   = (const float*)d_in[10];
  const float* g2   = (const float*)d_in[11];
  const float* be2  = (const float*)d_in[12];
  const float* Wl1  = (const float*)d_in[13];
  const float* bl1  = (const float*)d_in[14];

  float* out   = (float*)d_out;
  float* wsi   = out;                 // [8,4]
  float* npred = out + GG * TT;       // [N,4]

  float*    ws     = (float*)d_ws;
  float*    hbuf   = ws;                              // N*H fp32 (h1, then h2)
  ushort_t* gbf    = (ushort_t*)(hbuf + (size_t)NN * HH);  // N*H bf16 (g)
  float*    stats1 = (float*)(gbf + (size_t)NN * HH); // 256
  float*    stats2 = stats1 + 256;                    // 256
  float*    maxb   = stats2 + 256;                    // 64
  int*      deg      = (int*)(maxb + 64);             // N
  int*      rowstart = deg + NN;                      // N
  int*      cursor   = rowstart + NN;                 // N
  int*      bsum     = cursor + NN;                   // 128
  int*      bscan    = bsum + 128;                    // 128
  int*      srcl     = bscan + 128;                   // NE
  ushort_t* Wbf      = (ushort_t*)(srcl + NE);        // DF*HH
  ushort_t* Wbf2     = Wbf + DF * HH;                 // HH*HH

  hipMemsetAsync(deg, 0, NN * sizeof(int), stream);
  k_init<<<dim3(1), dim3(512), 0, stream>>>(stats1, maxb);
  k_prep<<<dim3(64), dim3(256), 0, stream>>>(Wf, Wbf, DF * HH);
  k_prep<<<dim3(16), dim3(256), 0, stream>>>(Wc, Wbf2, HH * HH);

  // CSR build
  k_count<<<dim3(1024), dim3(256), 0, stream>>>(ei, deg);
  k_scanA<<<dim3(NB_SCAN), dim3(256), 0, stream>>>(deg, rowstart, bsum);
  k_scanB<<<dim3(1), dim3(128), 0, stream>>>(bsum, bscan);
  k_scanC<<<dim3(NB_SCAN), dim3(256), 0, stream>>>(rowstart, bscan, cursor);
  k_fill<<<dim3(1024), dim3(256), 0, stream>>>(ei, cursor, srcl);

  // Layer 0: GEMM + stats
  k_gemm1_mfma<<<dim3(512), dim3(256), 0, stream>>>(x, Wbf, bf, hbuf, stats1);
  k_finalize_bn<<<dim3(1), dim3(64), 0, stream>>>(stats1, g1, be1, stats1 + 128);
  // fused: norm+ReLU + head0 + pool + g = f@Wc (bf16)
  k_norm_gemm2<<<dim3(512), dim3(256), 0, stream>>>(
      hbuf, stats1 + 128, Wl0, bl0, bat, Wbf2, npred, maxb, gbf);

  // Layer 1: h2 = b + g + A.g
  {
    int rpb = 64;
    int nb = (NN + rpb - 1) / rpb;            // 1563
    k_gather<<<dim3(nb), dim3(256), 0, stream>>>(
        gbf, rowstart, deg, srcl, bc, hbuf, stats2, rpb);
  }
  k_finalize_bn<<<dim3(1), dim3(64), 0, stream>>>(stats2, g2, be2, stats2 + 128);
  k_norm_np<0, 1><<<dim3(512), dim3(256), 0, stream>>>(
      hbuf, gbf, stats2 + 128, Wl1, bl1, bat, npred, maxb + 32, (NN + 511) / 512);

  k_wsi<<<dim3(1), dim3(32), 0, stream>>>(maxb, maxb + 32, wsi);
}

// Round 10
// 452.315 us; speedup vs baseline: 1.7785x; 1.2210x over previous
//
#include <hip/hip_runtime.h>
#include <math.h>

#define NN 100000
#define NE 1600000
#define DF 256
#define HH 64
#define TT 4
#define GG 8
#define BN_EPS 1e-5f
#define NTOT (NE + NN)               // srcl entries incl. self-loops

#define SCAN_BLK 1024
#define NB_SCAN ((NN + SCAN_BLK - 1) / SCAN_BLK)   // 98

typedef __attribute__((ext_vector_type(8))) short short8v;
typedef __attribute__((ext_vector_type(4))) float f32x4;
typedef unsigned short ushort_t;
typedef unsigned int uint_t;

__device__ __forceinline__ void atomicMaxF(float* addr, float val) {
  if (val >= 0.f) atomicMax((int*)addr, __float_as_int(val));
  else            atomicMin((unsigned int*)addr, __float_as_uint(val));
}

__device__ __forceinline__ short f2bf(float f) {
  uint_t u = __float_as_uint(f);
  u += 0x7FFFu + ((u >> 16) & 1u);
  return (short)(u >> 16);
}
__device__ __forceinline__ float bf2f(uint_t u) { return __uint_as_float(u << 16); }

// ---------------- init ----------------
__global__ void k_init(float* __restrict__ stats, float* __restrict__ maxb) {
  int i = threadIdx.x;
  if (i < 512) stats[i] = 0.f;
  if (i < 64)  maxb[i]  = -INFINITY;
}

// ---------------- prep: fp32 -> bf16 bits ----------------
__global__ void k_prep(const float* __restrict__ W, ushort_t* __restrict__ Wbf, int n) {
  int i = blockIdx.x * 256 + threadIdx.x;
  if (i < n) Wbf[i] = (ushort_t)f2bf(W[i]);
}

// ---------------- GEMM1 (MFMA bf16): h1 = x @ W_first + b, + BN stats ----------------
__global__ __launch_bounds__(256, 2) void k_gemm1_mfma(
    const float* __restrict__ x, const ushort_t* __restrict__ Wbf,
    const float* __restrict__ b, float* __restrict__ h1,
    float* __restrict__ stats) {
  const int lane = threadIdx.x & 63;
  const int li = lane & 15;
  const int lh = lane >> 4;
  const int gw = (blockIdx.x * 256 + (int)threadIdx.x) >> 6;
  const int nw = (gridDim.x * 256) >> 6;

  short8v bf[8][4];
#pragma unroll
  for (int s = 0; s < 8; ++s)
#pragma unroll
    for (int ct = 0; ct < 4; ++ct)
#pragma unroll
      for (int e = 0; e < 8; ++e)
        bf[s][ct][e] = (short)Wbf[(32 * s + 8 * lh + e) * HH + ct * 16 + li];

  float bias[4];
#pragma unroll
  for (int ct = 0; ct < 4; ++ct) bias[ct] = b[ct * 16 + li];

  float ps[4] = {0.f, 0.f, 0.f, 0.f}, pss[4] = {0.f, 0.f, 0.f, 0.f};

  for (int t = gw; t < NN / 16; t += nw) {
    const float* xb = x + (size_t)(t * 16 + li) * DF + 8 * lh;
    f32x4 acc[4];
#pragma unroll
    for (int ct = 0; ct < 4; ++ct) acc[ct] = (f32x4){0.f, 0.f, 0.f, 0.f};

#pragma unroll
    for (int s = 0; s < 8; ++s) {
      float4 a0 = *(const float4*)(xb + 32 * s);
      float4 a1 = *(const float4*)(xb + 32 * s + 4);
      short8v af;
      af[0] = f2bf(a0.x); af[1] = f2bf(a0.y); af[2] = f2bf(a0.z); af[3] = f2bf(a0.w);
      af[4] = f2bf(a1.x); af[5] = f2bf(a1.y); af[6] = f2bf(a1.z); af[7] = f2bf(a1.w);
#pragma unroll
      for (int ct = 0; ct < 4; ++ct)
        acc[ct] = __builtin_amdgcn_mfma_f32_16x16x32_bf16(af, bf[s][ct], acc[ct], 0, 0, 0);
    }

    float* hb = h1 + (size_t)t * 16 * HH;
#pragma unroll
    for (int ct = 0; ct < 4; ++ct) {
#pragma unroll
      for (int r = 0; r < 4; ++r) {
        float h = acc[ct][r] + bias[ct];
        hb[(lh * 4 + r) * HH + ct * 16 + li] = h;
        ps[ct] += h; pss[ct] += h * h;
      }
    }
  }

#pragma unroll
  for (int ct = 0; ct < 4; ++ct) {
    ps[ct]  += __shfl_xor(ps[ct], 16);  ps[ct]  += __shfl_xor(ps[ct], 32);
    pss[ct] += __shfl_xor(pss[ct], 16); pss[ct] += __shfl_xor(pss[ct], 32);
  }
  if (lane < 16) {
#pragma unroll
    for (int ct = 0; ct < 4; ++ct) {
      atomicAdd(&stats[ct * 16 + lane], ps[ct]);
      atomicAdd(&stats[HH + ct * 16 + lane], pss[ct]);
    }
  }
}

// ---------------- BN finalize ----------------
__global__ void k_finalize_bn(const float* __restrict__ sums,
                              const float* __restrict__ gamma,
                              const float* __restrict__ beta,
                              float* __restrict__ ab) {
  int c = threadIdx.x;                                // 64 threads
  float mu  = sums[c] * (1.f / NN);
  float var = sums[HH + c] * (1.f / NN) - mu * mu;
  float a = gamma[c] * rsqrtf(var + BN_EPS);
  ab[c] = a;
  ab[HH + c] = beta[c] - mu * a;
}

// ---------------- fused: normalize(h1)+ReLU; np0 + pool via 5th MFMA tile;
//                  g = f @ W_conv (bf16 out) ----------------
__global__ __launch_bounds__(256) void k_norm_gemm2(
    const float* __restrict__ h1, const float* __restrict__ ab,
    const float* __restrict__ Wl0, const float* __restrict__ bl0,
    const int* __restrict__ batch, const ushort_t* __restrict__ Wbf2,
    float* __restrict__ node_pred, float* __restrict__ maxbuf,
    ushort_t* __restrict__ g) {
  __shared__ float lmax[GG * TT];
  if (threadIdx.x < GG * TT) lmax[threadIdx.x] = -INFINITY;
  __syncthreads();

  const int lane = threadIdx.x & 63;
  const int li = lane & 15;
  const int lh = lane >> 4;
  const int gw = (blockIdx.x * 256 + (int)threadIdx.x) >> 6;
  const int nw = (gridDim.x * 256) >> 6;

  short8v bfr[2][4];
#pragma unroll
  for (int s = 0; s < 2; ++s)
#pragma unroll
    for (int ct = 0; ct < 4; ++ct)
#pragma unroll
      for (int e = 0; e < 8; ++e)
        bfr[s][ct][e] = (short)Wbf2[(32 * s + 8 * lh + e) * HH + ct * 16 + li];

  short8v bhd[2];
#pragma unroll
  for (int s = 0; s < 2; ++s)
#pragma unroll
    for (int e = 0; e < 8; ++e)
      bhd[s][e] = (li < TT) ? f2bf(Wl0[(32 * s + 8 * lh + e) * TT + li]) : (short)0;

  const float4 sa0 = *(const float4*)(ab + 8 * lh);
  const float4 sa1 = *(const float4*)(ab + 8 * lh + 4);
  const float4 sb0 = *(const float4*)(ab + HH + 8 * lh);
  const float4 sb1 = *(const float4*)(ab + HH + 8 * lh + 4);
  const float4 ta0 = *(const float4*)(ab + 32 + 8 * lh);
  const float4 ta1 = *(const float4*)(ab + 32 + 8 * lh + 4);
  const float4 tb0 = *(const float4*)(ab + HH + 32 + 8 * lh);
  const float4 tb1 = *(const float4*)(ab + HH + 32 + 8 * lh + 4);
  const float blv = (li < TT) ? bl0[li] : 0.f;

  for (int t = gw; t < NN / 16; t += nw) {
    const float* hb = h1 + (size_t)(t * 16 + li) * HH + 8 * lh;
    float4 x0 = *(const float4*)(hb);
    float4 x1 = *(const float4*)(hb + 4);
    float4 x2 = *(const float4*)(hb + 32);
    float4 x3 = *(const float4*)(hb + 36);

    short8v af0, af1;
    af0[0] = f2bf(fmaxf(fmaf(sa0.x, x0.x, sb0.x), 0.f));
    af0[1] = f2bf(fmaxf(fmaf(sa0.y, x0.y, sb0.y), 0.f));
    af0[2] = f2bf(fmaxf(fmaf(sa0.z, x0.z, sb0.z), 0.f));
    af0[3] = f2bf(fmaxf(fmaf(sa0.w, x0.w, sb0.w), 0.f));
    af0[4] = f2bf(fmaxf(fmaf(sa1.x, x1.x, sb1.x), 0.f));
    af0[5] = f2bf(fmaxf(fmaf(sa1.y, x1.y, sb1.y), 0.f));
    af0[6] = f2bf(fmaxf(fmaf(sa1.z, x1.z, sb1.z), 0.f));
    af0[7] = f2bf(fmaxf(fmaf(sa1.w, x1.w, sb1.w), 0.f));
    af1[0] = f2bf(fmaxf(fmaf(ta0.x, x2.x, tb0.x), 0.f));
    af1[1] = f2bf(fmaxf(fmaf(ta0.y, x2.y, tb0.y), 0.f));
    af1[2] = f2bf(fmaxf(fmaf(ta0.z, x2.z, tb0.z), 0.f));
    af1[3] = f2bf(fmaxf(fmaf(ta0.w, x2.w, tb0.w), 0.f));
    af1[4] = f2bf(fmaxf(fmaf(ta1.x, x3.x, tb1.x), 0.f));
    af1[5] = f2bf(fmaxf(fmaf(ta1.y, x3.y, tb1.y), 0.f));
    af1[6] = f2bf(fmaxf(fmaf(ta1.z, x3.z, tb1.z), 0.f));
    af1[7] = f2bf(fmaxf(fmaf(ta1.w, x3.w, tb1.w), 0.f));

    f32x4 acc[4], acch;
#pragma unroll
    for (int ct = 0; ct < 4; ++ct) {
      acc[ct] = (f32x4){0.f, 0.f, 0.f, 0.f};
      acc[ct] = __builtin_amdgcn_mfma_f32_16x16x32_bf16(af0, bfr[0][ct], acc[ct], 0, 0, 0);
      acc[ct] = __builtin_amdgcn_mfma_f32_16x16x32_bf16(af1, bfr[1][ct], acc[ct], 0, 0, 0);
    }
    acch = (f32x4){0.f, 0.f, 0.f, 0.f};
    acch = __builtin_amdgcn_mfma_f32_16x16x32_bf16(af0, bhd[0], acch, 0, 0, 0);
    acch = __builtin_amdgcn_mfma_f32_16x16x32_bf16(af1, bhd[1], acch, 0, 0, 0);

    ushort_t* gb = g + (size_t)t * 16 * HH;
#pragma unroll
    for (int ct = 0; ct < 4; ++ct)
#pragma unroll
      for (int r = 0; r < 4; ++r)
        gb[(lh * 4 + r) * HH + ct * 16 + li] = (ushort_t)f2bf(acc[ct][r]);

    if (li < TT) {
#pragma unroll
      for (int r = 0; r < 4; ++r) {
        int row = t * 16 + lh * 4 + r;
        float np = acch[r] + blv;
        atomicMaxF(&lmax[batch[row] * TT + li], np);
        node_pred[(size_t)row * TT + li] = np;
      }
    }
  }
  __syncthreads();
  if (threadIdx.x < GG * TT) atomicMaxF(&maxbuf[threadIdx.x], lmax[threadIdx.x]);
}

// ---------------- normalize+ReLU + head + max-pool (layer 1 epilogue) ----------------
template <int WRITEF, int ADDOUT>
__global__ __launch_bounds__(256) void k_norm_np(
    const float* __restrict__ hin, ushort_t* __restrict__ fout,
    const float* __restrict__ ab, const float* __restrict__ Wlin,
    const float* __restrict__ blin, const int* __restrict__ batch,
    float* __restrict__ node_pred, float* __restrict__ maxbuf, int rpb) {
  __shared__ float lmax[GG * TT];
  if (threadIdx.x < GG * TT) lmax[threadIdx.x] = -INFINITY;
  __syncthreads();

  const int lane = threadIdx.x & 63;
  const int wid  = threadIdx.x >> 6;
  const float a  = ab[lane];
  const float b2 = ab[HH + lane];
  const float4 w = ((const float4*)Wlin)[lane];
  const float4 bl = *(const float4*)blin;
  int r0 = blockIdx.x * rpb;
  int r1 = min(r0 + rpb, NN);

  for (int r = r0 + wid; r < r1; r += 4) {
    float h = hin[(size_t)r * HH + lane];
    float f = fmaxf(fmaf(a, h, b2), 0.f);
    if (WRITEF) fout[(size_t)r * HH + lane] = (ushort_t)f2bf(f);
    float p0 = f * w.x, p1 = f * w.y, p2 = f * w.z, p3 = f * w.w;
#pragma unroll
    for (int off = 32; off; off >>= 1) {
      p0 += __shfl_xor(p0, off);
      p1 += __shfl_xor(p1, off);
      p2 += __shfl_xor(p2, off);
      p3 += __shfl_xor(p3, off);
    }
    if (lane == 0) {
      float4 np;
      np.x = p0 + bl.x; np.y = p1 + bl.y; np.z = p2 + bl.z; np.w = p3 + bl.w;
      int g = batch[r];
      atomicMaxF(&lmax[g * TT + 0], np.x);
      atomicMaxF(&lmax[g * TT + 1], np.y);
      atomicMaxF(&lmax[g * TT + 2], np.z);
      atomicMaxF(&lmax[g * TT + 3], np.w);
      float4* op = (float4*)(node_pred + (size_t)r * TT);
      if (ADDOUT) {
        float4 o = *op;
        np.x += o.x; np.y += o.y; np.z += o.z; np.w += o.w;
      }
      *op = np;
    }
  }
  __syncthreads();
  if (threadIdx.x < GG * TT) atomicMaxF(&maxbuf[threadIdx.x], lmax[threadIdx.x]);
}

// ---------------- CSR build (with self-loops: row i = [self, edges...]) ----------------
__global__ __launch_bounds__(256) void k_count(const int* __restrict__ ei,
                                               int* __restrict__ deg) {
  int i = blockIdx.x * blockDim.x + threadIdx.x;
  int n = gridDim.x * blockDim.x;
  for (int e = i; e < NE; e += n) atomicAdd(&deg[ei[NE + e]], 1);
}

__global__ __launch_bounds__(256) void k_scanA(const int* __restrict__ deg,
                                               int* __restrict__ rowstart,
                                               int* __restrict__ bsum) {
  __shared__ int s[256];
  int t = threadIdx.x;
  int base = blockIdx.x * SCAN_BLK + t * 4;
  int d0 = 0, d1 = 0, d2 = 0, d3 = 0;
  if (base + 3 < NN) {
    int4 v = *(const int4*)(deg + base);
    d0 = v.x; d1 = v.y; d2 = v.z; d3 = v.w;
  } else {
    if (base + 0 < NN) d0 = deg[base + 0];
    if (base + 1 < NN) d1 = deg[base + 1];
    if (base + 2 < NN) d2 = deg[base + 2];
    if (base + 3 < NN) d3 = deg[base + 3];
  }
  // +1 per valid node for the self-loop slot
  int c0 = (base + 0 < NN) ? d0 + 1 : 0;
  int c1 = (base + 1 < NN) ? d1 + 1 : 0;
  int c2 = (base + 2 < NN) ? d2 + 1 : 0;
  int c3 = (base + 3 < NN) ? d3 + 1 : 0;
  int ts = c0 + c1 + c2 + c3;
  s[t] = ts;
  __syncthreads();
  for (int off = 1; off < 256; off <<= 1) {
    int v = (t >= off) ? s[t - off] : 0;
    __syncthreads();
    s[t] += v;
    __syncthreads();
  }
  int excl = s[t] - ts;
  if (base + 0 < NN) rowstart[base + 0] = excl;  excl += c0;
  if (base + 1 < NN) rowstart[base + 1] = excl;  excl += c1;
  if (base + 2 < NN) rowstart[base + 2] = excl;  excl += c2;
  if (base + 3 < NN) rowstart[base + 3] = excl;
  if (t == 255) bsum[blockIdx.x] = s[255];
}

__global__ void k_scanB(const int* __restrict__ bsum, int* __restrict__ bscan) {
  __shared__ int s[128];
  int t = threadIdx.x;
  int v = (t < NB_SCAN) ? bsum[t] : 0;
  s[t] = v;
  __syncthreads();
  for (int off = 1; off < 128; off <<= 1) {
    int u = (t >= off) ? s[t - off] : 0;
    __syncthreads();
    s[t] += u;
    __syncthreads();
  }
  if (t < NB_SCAN) bscan[t] = s[t] - v;
}

__global__ __launch_bounds__(256) void k_scanC(int* __restrict__ rowstart,
                                               const int* __restrict__ bscan,
                                               int* __restrict__ cursor,
                                               int* __restrict__ srcl) {
  int off = bscan[blockIdx.x];
  int base = blockIdx.x * SCAN_BLK + threadIdx.x * 4;
#pragma unroll
  for (int j = 0; j < 4; ++j) {
    int i = base + j;
    if (i < NN) {
      int r = rowstart[i] + off;
      rowstart[i] = r;
      srcl[r] = i;            // self-loop first entry
      cursor[i] = r + 1;
    }
  }
}

__global__ __launch_bounds__(256) void k_fill(const int* __restrict__ ei,
                                              int* __restrict__ cursor,
                                              int* __restrict__ srcl) {
  int i = blockIdx.x * blockDim.x + threadIdx.x;
  int n = gridDim.x * blockDim.x;
  for (int e = i; e < NE; e += n) {
    int src = ei[e];
    int dst = ei[NE + e];
    int p = atomicAdd(&cursor[dst], 1);
    srcl[p] = src;
  }
}

// ---------------- gather: h2[r] = b + sum_{srcl entries incl self} g[s] ----------------
// Flat edge stream per wave (8 contiguous rows), 2-deep ping-pong pipeline:
// issue chunk k+1 (16 loads), wait vmcnt(16) -> chunk k done, consume with
// row-boundary walk (boundaries preloaded via readlane). sched_barrier after
// each waitcnt (rule: compiler hoists reg-only consumes past asm waits).
#define RF(x) __builtin_amdgcn_readfirstlane(x)
#define GLD(V, I) asm volatile("global_load_ushort %0, %1, %2" \
    : "=v"(V) : "v"(voff), "s"(g + (size_t)(I) * HH) : "memory")
#define WAIT16 do { asm volatile("s_waitcnt vmcnt(16)" ::: "memory"); \
    __builtin_amdgcn_sched_barrier(0); } while (0)
#define WAIT0 do { asm volatile("s_waitcnt vmcnt(0)" ::: "memory"); \
    __builtin_amdgcn_sched_barrier(0); } while (0)
#define ISSUE16(P, EB) do { \
  int j0 = RF(srcl[(EB) + 0]),  j1 = RF(srcl[(EB) + 1]); \
  int j2 = RF(srcl[(EB) + 2]),  j3 = RF(srcl[(EB) + 3]); \
  int j4 = RF(srcl[(EB) + 4]),  j5 = RF(srcl[(EB) + 5]); \
  int j6 = RF(srcl[(EB) + 6]),  j7 = RF(srcl[(EB) + 7]); \
  int j8 = RF(srcl[(EB) + 8]),  j9 = RF(srcl[(EB) + 9]); \
  int j10 = RF(srcl[(EB) + 10]), j11 = RF(srcl[(EB) + 11]); \
  int j12 = RF(srcl[(EB) + 12]), j13 = RF(srcl[(EB) + 13]); \
  int j14 = RF(srcl[(EB) + 14]), j15 = RF(srcl[(EB) + 15]); \
  GLD(P##0, j0);  GLD(P##1, j1);  GLD(P##2, j2);  GLD(P##3, j3); \
  GLD(P##4, j4);  GLD(P##5, j5);  GLD(P##6, j6);  GLD(P##7, j7); \
  GLD(P##8, j8);  GLD(P##9, j9);  GLD(P##10, j10); GLD(P##11, j11); \
  GLD(P##12, j12); GLD(P##13, j13); GLD(P##14, j14); GLD(P##15, j15); \
} while (0)
#define CJ(V, EI) do { \
  if ((EI) == nb) { \
    h2[(size_t)cur * HH + lane] = acc; ps += acc; pss += acc * acc; \
    cur++; nb = __builtin_amdgcn_readlane(rsv, cur - wra); acc = bc; \
  } \
  acc += bf2f(V); } while (0)
#define CONS16(P, EB) do { \
  CJ(P##0, (EB) + 0);  CJ(P##1, (EB) + 1);  CJ(P##2, (EB) + 2);  CJ(P##3, (EB) + 3); \
  CJ(P##4, (EB) + 4);  CJ(P##5, (EB) + 5);  CJ(P##6, (EB) + 6);  CJ(P##7, (EB) + 7); \
  CJ(P##8, (EB) + 8);  CJ(P##9, (EB) + 9);  CJ(P##10, (EB) + 10); CJ(P##11, (EB) + 11); \
  CJ(P##12, (EB) + 12); CJ(P##13, (EB) + 13); CJ(P##14, (EB) + 14); CJ(P##15, (EB) + 15); \
} while (0)

__global__ __launch_bounds__(256) void k_gather(
    const ushort_t* __restrict__ g, const int* __restrict__ rowstart,
    const int* __restrict__ srcl, const float* __restrict__ bias,
    float* __restrict__ h2, float* __restrict__ stats) {
  const int lane = threadIdx.x & 63;
  const int wid  = threadIdx.x >> 6;
  const float bc = bias[lane];
  const uint_t voff = lane * 2;
  const int wra = (blockIdx.x * 4 + wid) * 8;        // 8 rows per wave, exact cover

  // preload the 8 row-end boundaries into lanes 0..7
  int ridx = wra + 1 + lane;
  int rsv = (ridx < NN) ? rowstart[ridx] : NTOT;

  int e    = RF(rowstart[wra]);
  int eEnd = __builtin_amdgcn_readlane(rsv, 7);
  int cur  = wra;
  int nb   = __builtin_amdgcn_readlane(rsv, 0);
  float acc = bc, ps = 0.f, pss = 0.f;

  uint_t A0, A1, A2, A3, A4, A5, A6, A7, A8, A9, A10, A11, A12, A13, A14, A15;
  uint_t B0, B1, B2, B3, B4, B5, B6, B7, B8, B9, B10, B11, B12, B13, B14, B15;

  int n = (eEnd - e) >> 4;
  if (n > 0) {
    int pend = e;
    ISSUE16(A, e); e += 16; n--;
    while (n >= 2) {
      int eb = e;
      ISSUE16(B, e); e += 16; n--;
      WAIT16; CONS16(A, pend); pend = eb;
      int ea = e;
      ISSUE16(A, e); e += 16; n--;
      WAIT16; CONS16(B, pend); pend = ea;
    }
    if (n == 1) {
      int eb = e;
      ISSUE16(B, e); e += 16;
      WAIT16; CONS16(A, pend); pend = eb;
      WAIT0;  CONS16(B, pend);
    } else {
      WAIT0;  CONS16(A, pend);
    }
  }
  for (; e < eEnd; ++e) {
    if (e == nb) {
      h2[(size_t)cur * HH + lane] = acc; ps += acc; pss += acc * acc;
      cur++; nb = __builtin_amdgcn_readlane(rsv, cur - wra); acc = bc;
    }
    int i = RF(srcl[e]);
    acc += bf2f(g[(size_t)i * HH + lane]);
  }
  h2[(size_t)cur * HH + lane] = acc; ps += acc; pss += acc * acc;

  // block-level reduction before stats atomics
  __shared__ float sred[4][128];
  sred[wid][lane] = ps;
  sred[wid][64 + lane] = pss;
  __syncthreads();
  if (wid == 0) {
    float s0 = sred[0][lane] + sred[1][lane] + sred[2][lane] + sred[3][lane];
    float q0 = sred[0][64 + lane] + sred[1][64 + lane] + sred[2][64 + lane] + sred[3][64 + lane];
    atomicAdd(&stats[lane], s0);
    atomicAdd(&stats[HH + lane], q0);
  }
}

// ---------------- final: wsi = max0 + max1 ----------------
__global__ void k_wsi(const float* __restrict__ m0, const float* __restrict__ m1,
                      float* __restrict__ out) {
  int i = threadIdx.x;
  out[i] = m0[i] + m1[i];
}

extern "C" void kernel_launch(void* const* d_in, const int* in_sizes, int n_in,
                              void* d_out, int out_size, void* d_ws, size_t ws_size,
                              hipStream_t stream) {
  const float* x    = (const float*)d_in[0];
  const int*   ei   = (const int*)d_in[1];
  const int*   bat  = (const int*)d_in[2];
  const float* Wf   = (const float*)d_in[3];
  const float* bf   = (const float*)d_in[4];
  const float* g1   = (const float*)d_in[5];
  const float* be1  = (const float*)d_in[6];
  const float* Wl0  = (const float*)d_in[7];
  const float* bl0  = (const float*)d_in[8];
  const float* Wc   = (const float*)d_in[9];
  const float* bc   = (const float*)d_in[10];
  const float* g2   = (const float*)d_in[11];
  const float* be2  = (const float*)d_in[12];
  const float* Wl1  = (const float*)d_in[13];
  const float* bl1  = (const float*)d_in[14];

  float* out   = (float*)d_out;
  float* wsi   = out;                 // [8,4]
  float* npred = out + GG * TT;       // [N,4]

  float*    ws     = (float*)d_ws;
  float*    hbuf   = ws;                              // N*H fp32 (h1, then h2)
  ushort_t* gbf    = (ushort_t*)(hbuf + (size_t)NN * HH);  // N*H bf16 (g)
  float*    stats1 = (float*)(gbf + (size_t)NN * HH); // 256
  float*    stats2 = stats1 + 256;                    // 256
  float*    maxb   = stats2 + 256;                    // 64
  int*      deg      = (int*)(maxb + 64);             // N
  int*      rowstart = deg + NN;                      // N
  int*      cursor   = rowstart + NN;                 // N
  int*      bsum     = cursor + NN;                   // 128
  int*      bscan    = bsum + 128;                    // 128
  int*      srcl     = bscan + 128;                   // NE+NN (self-loops)
  ushort_t* Wbf      = (ushort_t*)(srcl + NTOT);      // DF*HH
  ushort_t* Wbf2     = Wbf + DF * HH;                 // HH*HH

  hipMemsetAsync(deg, 0, NN * sizeof(int), stream);
  k_init<<<dim3(1), dim3(512), 0, stream>>>(stats1, maxb);
  k_prep<<<dim3(64), dim3(256), 0, stream>>>(Wf, Wbf, DF * HH);
  k_prep<<<dim3(16), dim3(256), 0, stream>>>(Wc, Wbf2, HH * HH);

  // CSR build (self-loop slot reserved per row)
  k_count<<<dim3(1024), dim3(256), 0, stream>>>(ei, deg);
  k_scanA<<<dim3(NB_SCAN), dim3(256), 0, stream>>>(deg, rowstart, bsum);
  k_scanB<<<dim3(1), dim3(128), 0, stream>>>(bsum, bscan);
  k_scanC<<<dim3(NB_SCAN), dim3(256), 0, stream>>>(rowstart, bscan, cursor, srcl);
  k_fill<<<dim3(1024), dim3(256), 0, stream>>>(ei, cursor, srcl);

  // Layer 0: GEMM + stats
  k_gemm1_mfma<<<dim3(512), dim3(256), 0, stream>>>(x, Wbf, bf, hbuf, stats1);
  k_finalize_bn<<<dim3(1), dim3(64), 0, stream>>>(stats1, g1, be1, stats1 + 128);
  k_norm_gemm2<<<dim3(512), dim3(256), 0, stream>>>(
      hbuf, stats1 + 128, Wl0, bl0, bat, Wbf2, npred, maxb, gbf);

  // Layer 1: h2 = b + g + A.g (pipelined flat-stream gather)
  k_gather<<<dim3(NN / 32), dim3(256), 0, stream>>>(
      gbf, rowstart, srcl, bc, hbuf, stats2);
  k_finalize_bn<<<dim3(1), dim3(64), 0, stream>>>(stats2, g2, be2, stats2 + 128);
  k_norm_np<0, 1><<<dim3(512), dim3(256), 0, stream>>>(
      hbuf, gbf, stats2 + 128, Wl1, bl1, bat, npred, maxb + 32, (NN + 511) / 512);

  k_wsi<<<dim3(1), dim3(32), 0, stream>>>(maxb, maxb + 32, wsi);
}

// Round 11
// 434.176 us; speedup vs baseline: 1.8528x; 1.0418x over previous
//
#include <hip/hip_runtime.h>
#include <math.h>

#define NN 100000
#define NE 1600000
#define DF 256
#define HH 64
#define TT 4
#define GG 8
#define BN_EPS 1e-5f
#define NTOT (NE + NN)               // srcl entries incl. self-loops

#define SCAN_BLK 1024
#define NB_SCAN ((NN + SCAN_BLK - 1) / SCAN_BLK)   // 98

typedef __attribute__((ext_vector_type(8))) short short8v;
typedef __attribute__((ext_vector_type(4))) float f32x4;
typedef unsigned short ushort_t;
typedef unsigned int uint_t;

__device__ __forceinline__ void atomicMaxF(float* addr, float val) {
  if (val >= 0.f) atomicMax((int*)addr, __float_as_int(val));
  else            atomicMin((unsigned int*)addr, __float_as_uint(val));
}

__device__ __forceinline__ short f2bf(float f) {
  uint_t u = __float_as_uint(f);
  u += 0x7FFFu + ((u >> 16) & 1u);
  return (short)(u >> 16);
}
__device__ __forceinline__ float bf2f(uint_t u) { return __uint_as_float(u << 16); }

// ---------------- init ----------------
__global__ void k_init(float* __restrict__ stats, float* __restrict__ maxb) {
  int i = threadIdx.x;
  if (i < 512) stats[i] = 0.f;
  if (i < 64)  maxb[i]  = -INFINITY;
}

// ---------------- prep: fp32 -> bf16 bits ----------------
__global__ void k_prep(const float* __restrict__ W, ushort_t* __restrict__ Wbf, int n) {
  int i = blockIdx.x * 256 + threadIdx.x;
  if (i < n) Wbf[i] = (ushort_t)f2bf(W[i]);
}

// ---------------- GEMM1 (MFMA bf16): h1 = x @ W_first + b, + BN stats ----------------
__global__ __launch_bounds__(256, 2) void k_gemm1_mfma(
    const float* __restrict__ x, const ushort_t* __restrict__ Wbf,
    const float* __restrict__ b, float* __restrict__ h1,
    float* __restrict__ stats) {
  const int lane = threadIdx.x & 63;
  const int li = lane & 15;
  const int lh = lane >> 4;
  const int gw = (blockIdx.x * 256 + (int)threadIdx.x) >> 6;
  const int nw = (gridDim.x * 256) >> 6;

  short8v bf[8][4];
#pragma unroll
  for (int s = 0; s < 8; ++s)
#pragma unroll
    for (int ct = 0; ct < 4; ++ct)
#pragma unroll
      for (int e = 0; e < 8; ++e)
        bf[s][ct][e] = (short)Wbf[(32 * s + 8 * lh + e) * HH + ct * 16 + li];

  float bias[4];
#pragma unroll
  for (int ct = 0; ct < 4; ++ct) bias[ct] = b[ct * 16 + li];

  float ps[4] = {0.f, 0.f, 0.f, 0.f}, pss[4] = {0.f, 0.f, 0.f, 0.f};

  for (int t = gw; t < NN / 16; t += nw) {
    const float* xb = x + (size_t)(t * 16 + li) * DF + 8 * lh;
    f32x4 acc[4];
#pragma unroll
    for (int ct = 0; ct < 4; ++ct) acc[ct] = (f32x4){0.f, 0.f, 0.f, 0.f};

#pragma unroll
    for (int s = 0; s < 8; ++s) {
      float4 a0 = *(const float4*)(xb + 32 * s);
      float4 a1 = *(const float4*)(xb + 32 * s + 4);
      short8v af;
      af[0] = f2bf(a0.x); af[1] = f2bf(a0.y); af[2] = f2bf(a0.z); af[3] = f2bf(a0.w);
      af[4] = f2bf(a1.x); af[5] = f2bf(a1.y); af[6] = f2bf(a1.z); af[7] = f2bf(a1.w);
#pragma unroll
      for (int ct = 0; ct < 4; ++ct)
        acc[ct] = __builtin_amdgcn_mfma_f32_16x16x32_bf16(af, bf[s][ct], acc[ct], 0, 0, 0);
    }

    float* hb = h1 + (size_t)t * 16 * HH;
#pragma unroll
    for (int ct = 0; ct < 4; ++ct) {
#pragma unroll
      for (int r = 0; r < 4; ++r) {
        float h = acc[ct][r] + bias[ct];
        hb[(lh * 4 + r) * HH + ct * 16 + li] = h;
        ps[ct] += h; pss[ct] += h * h;
      }
    }
  }

#pragma unroll
  for (int ct = 0; ct < 4; ++ct) {
    ps[ct]  += __shfl_xor(ps[ct], 16);  ps[ct]  += __shfl_xor(ps[ct], 32);
    pss[ct] += __shfl_xor(pss[ct], 16); pss[ct] += __shfl_xor(pss[ct], 32);
  }
  if (lane < 16) {
#pragma unroll
    for (int ct = 0; ct < 4; ++ct) {
      atomicAdd(&stats[ct * 16 + lane], ps[ct]);
      atomicAdd(&stats[HH + ct * 16 + lane], pss[ct]);
    }
  }
}

// ---------------- BN finalize ----------------
__global__ void k_finalize_bn(const float* __restrict__ sums,
                              const float* __restrict__ gamma,
                              const float* __restrict__ beta,
                              float* __restrict__ ab) {
  int c = threadIdx.x;                                // 64 threads
  float mu  = sums[c] * (1.f / NN);
  float var = sums[HH + c] * (1.f / NN) - mu * mu;
  float a = gamma[c] * rsqrtf(var + BN_EPS);
  ab[c] = a;
  ab[HH + c] = beta[c] - mu * a;
}

// ---------------- fused: normalize(h1)+ReLU; np0 + pool via 5th MFMA tile;
//                  g = f @ W_conv (bf16 out) ----------------
__global__ __launch_bounds__(256) void k_norm_gemm2(
    const float* __restrict__ h1, const float* __restrict__ ab,
    const float* __restrict__ Wl0, const float* __restrict__ bl0,
    const int* __restrict__ batch, const ushort_t* __restrict__ Wbf2,
    float* __restrict__ node_pred, float* __restrict__ maxbuf,
    ushort_t* __restrict__ g) {
  __shared__ float lmax[GG * TT];
  if (threadIdx.x < GG * TT) lmax[threadIdx.x] = -INFINITY;
  __syncthreads();

  const int lane = threadIdx.x & 63;
  const int li = lane & 15;
  const int lh = lane >> 4;
  const int gw = (blockIdx.x * 256 + (int)threadIdx.x) >> 6;
  const int nw = (gridDim.x * 256) >> 6;

  short8v bfr[2][4];
#pragma unroll
  for (int s = 0; s < 2; ++s)
#pragma unroll
    for (int ct = 0; ct < 4; ++ct)
#pragma unroll
      for (int e = 0; e < 8; ++e)
        bfr[s][ct][e] = (short)Wbf2[(32 * s + 8 * lh + e) * HH + ct * 16 + li];

  short8v bhd[2];
#pragma unroll
  for (int s = 0; s < 2; ++s)
#pragma unroll
    for (int e = 0; e < 8; ++e)
      bhd[s][e] = (li < TT) ? f2bf(Wl0[(32 * s + 8 * lh + e) * TT + li]) : (short)0;

  const float4 sa0 = *(const float4*)(ab + 8 * lh);
  const float4 sa1 = *(const float4*)(ab + 8 * lh + 4);
  const float4 sb0 = *(const float4*)(ab + HH + 8 * lh);
  const float4 sb1 = *(const float4*)(ab + HH + 8 * lh + 4);
  const float4 ta0 = *(const float4*)(ab + 32 + 8 * lh);
  const float4 ta1 = *(const float4*)(ab + 32 + 8 * lh + 4);
  const float4 tb0 = *(const float4*)(ab + HH + 32 + 8 * lh);
  const float4 tb1 = *(const float4*)(ab + HH + 32 + 8 * lh + 4);
  const float blv = (li < TT) ? bl0[li] : 0.f;

  for (int t = gw; t < NN / 16; t += nw) {
    const float* hb = h1 + (size_t)(t * 16 + li) * HH + 8 * lh;
    float4 x0 = *(const float4*)(hb);
    float4 x1 = *(const float4*)(hb + 4);
    float4 x2 = *(const float4*)(hb + 32);
    float4 x3 = *(const float4*)(hb + 36);

    short8v af0, af1;
    af0[0] = f2bf(fmaxf(fmaf(sa0.x, x0.x, sb0.x), 0.f));
    af0[1] = f2bf(fmaxf(fmaf(sa0.y, x0.y, sb0.y), 0.f));
    af0[2] = f2bf(fmaxf(fmaf(sa0.z, x0.z, sb0.z), 0.f));
    af0[3] = f2bf(fmaxf(fmaf(sa0.w, x0.w, sb0.w), 0.f));
    af0[4] = f2bf(fmaxf(fmaf(sa1.x, x1.x, sb1.x), 0.f));
    af0[5] = f2bf(fmaxf(fmaf(sa1.y, x1.y, sb1.y), 0.f));
    af0[6] = f2bf(fmaxf(fmaf(sa1.z, x1.z, sb1.z), 0.f));
    af0[7] = f2bf(fmaxf(fmaf(sa1.w, x1.w, sb1.w), 0.f));
    af1[0] = f2bf(fmaxf(fmaf(ta0.x, x2.x, tb0.x), 0.f));
    af1[1] = f2bf(fmaxf(fmaf(ta0.y, x2.y, tb0.y), 0.f));
    af1[2] = f2bf(fmaxf(fmaf(ta0.z, x2.z, tb0.z), 0.f));
    af1[3] = f2bf(fmaxf(fmaf(ta0.w, x2.w, tb0.w), 0.f));
    af1[4] = f2bf(fmaxf(fmaf(ta1.x, x3.x, tb1.x), 0.f));
    af1[5] = f2bf(fmaxf(fmaf(ta1.y, x3.y, tb1.y), 0.f));
    af1[6] = f2bf(fmaxf(fmaf(ta1.z, x3.z, tb1.z), 0.f));
    af1[7] = f2bf(fmaxf(fmaf(ta1.w, x3.w, tb1.w), 0.f));

    f32x4 acc[4], acch;
#pragma unroll
    for (int ct = 0; ct < 4; ++ct) {
      acc[ct] = (f32x4){0.f, 0.f, 0.f, 0.f};
      acc[ct] = __builtin_amdgcn_mfma_f32_16x16x32_bf16(af0, bfr[0][ct], acc[ct], 0, 0, 0);
      acc[ct] = __builtin_amdgcn_mfma_f32_16x16x32_bf16(af1, bfr[1][ct], acc[ct], 0, 0, 0);
    }
    acch = (f32x4){0.f, 0.f, 0.f, 0.f};
    acch = __builtin_amdgcn_mfma_f32_16x16x32_bf16(af0, bhd[0], acch, 0, 0, 0);
    acch = __builtin_amdgcn_mfma_f32_16x16x32_bf16(af1, bhd[1], acch, 0, 0, 0);

    ushort_t* gb = g + (size_t)t * 16 * HH;
#pragma unroll
    for (int ct = 0; ct < 4; ++ct)
#pragma unroll
      for (int r = 0; r < 4; ++r)
        gb[(lh * 4 + r) * HH + ct * 16 + li] = (ushort_t)f2bf(acc[ct][r]);

    if (li < TT) {
#pragma unroll
      for (int r = 0; r < 4; ++r) {
        int row = t * 16 + lh * 4 + r;
        float np = acch[r] + blv;
        atomicMaxF(&lmax[batch[row] * TT + li], np);
        node_pred[(size_t)row * TT + li] = np;
      }
    }
  }
  __syncthreads();
  if (threadIdx.x < GG * TT) atomicMaxF(&maxbuf[threadIdx.x], lmax[threadIdx.x]);
}

// ---------------- normalize+ReLU + head + max-pool (layer 1 epilogue) ----------------
template <int WRITEF, int ADDOUT>
__global__ __launch_bounds__(256) void k_norm_np(
    const float* __restrict__ hin, ushort_t* __restrict__ fout,
    const float* __restrict__ ab, const float* __restrict__ Wlin,
    const float* __restrict__ blin, const int* __restrict__ batch,
    float* __restrict__ node_pred, float* __restrict__ maxbuf, int rpb) {
  __shared__ float lmax[GG * TT];
  if (threadIdx.x < GG * TT) lmax[threadIdx.x] = -INFINITY;
  __syncthreads();

  const int lane = threadIdx.x & 63;
  const int wid  = threadIdx.x >> 6;
  const float a  = ab[lane];
  const float b2 = ab[HH + lane];
  const float4 w = ((const float4*)Wlin)[lane];
  const float4 bl = *(const float4*)blin;
  int r0 = blockIdx.x * rpb;
  int r1 = min(r0 + rpb, NN);

  for (int r = r0 + wid; r < r1; r += 4) {
    float h = hin[(size_t)r * HH + lane];
    float f = fmaxf(fmaf(a, h, b2), 0.f);
    if (WRITEF) fout[(size_t)r * HH + lane] = (ushort_t)f2bf(f);
    float p0 = f * w.x, p1 = f * w.y, p2 = f * w.z, p3 = f * w.w;
#pragma unroll
    for (int off = 32; off; off >>= 1) {
      p0 += __shfl_xor(p0, off);
      p1 += __shfl_xor(p1, off);
      p2 += __shfl_xor(p2, off);
      p3 += __shfl_xor(p3, off);
    }
    if (lane == 0) {
      float4 np;
      np.x = p0 + bl.x; np.y = p1 + bl.y; np.z = p2 + bl.z; np.w = p3 + bl.w;
      int g = batch[r];
      atomicMaxF(&lmax[g * TT + 0], np.x);
      atomicMaxF(&lmax[g * TT + 1], np.y);
      atomicMaxF(&lmax[g * TT + 2], np.z);
      atomicMaxF(&lmax[g * TT + 3], np.w);
      float4* op = (float4*)(node_pred + (size_t)r * TT);
      if (ADDOUT) {
        float4 o = *op;
        np.x += o.x; np.y += o.y; np.z += o.z; np.w += o.w;
      }
      *op = np;
    }
  }
  __syncthreads();
  if (threadIdx.x < GG * TT) atomicMaxF(&maxbuf[threadIdx.x], lmax[threadIdx.x]);
}

// ---------------- CSR build (with self-loops: row i = [self, edges...]) ----------------
__global__ __launch_bounds__(256) void k_count(const int* __restrict__ ei,
                                               int* __restrict__ deg) {
  int i = blockIdx.x * blockDim.x + threadIdx.x;
  int n = gridDim.x * blockDim.x;
  for (int e = i; e < NE; e += n) atomicAdd(&deg[ei[NE + e]], 1);
}

__global__ __launch_bounds__(256) void k_scanA(const int* __restrict__ deg,
                                               int* __restrict__ rowstart,
                                               int* __restrict__ bsum) {
  __shared__ int s[256];
  int t = threadIdx.x;
  int base = blockIdx.x * SCAN_BLK + t * 4;
  int d0 = 0, d1 = 0, d2 = 0, d3 = 0;
  if (base + 3 < NN) {
    int4 v = *(const int4*)(deg + base);
    d0 = v.x; d1 = v.y; d2 = v.z; d3 = v.w;
  } else {
    if (base + 0 < NN) d0 = deg[base + 0];
    if (base + 1 < NN) d1 = deg[base + 1];
    if (base + 2 < NN) d2 = deg[base + 2];
    if (base + 3 < NN) d3 = deg[base + 3];
  }
  int c0 = (base + 0 < NN) ? d0 + 1 : 0;
  int c1 = (base + 1 < NN) ? d1 + 1 : 0;
  int c2 = (base + 2 < NN) ? d2 + 1 : 0;
  int c3 = (base + 3 < NN) ? d3 + 1 : 0;
  int ts = c0 + c1 + c2 + c3;
  s[t] = ts;
  __syncthreads();
  for (int off = 1; off < 256; off <<= 1) {
    int v = (t >= off) ? s[t - off] : 0;
    __syncthreads();
    s[t] += v;
    __syncthreads();
  }
  int excl = s[t] - ts;
  if (base + 0 < NN) rowstart[base + 0] = excl;  excl += c0;
  if (base + 1 < NN) rowstart[base + 1] = excl;  excl += c1;
  if (base + 2 < NN) rowstart[base + 2] = excl;  excl += c2;
  if (base + 3 < NN) rowstart[base + 3] = excl;
  if (t == 255) bsum[blockIdx.x] = s[255];
}

__global__ void k_scanB(const int* __restrict__ bsum, int* __restrict__ bscan) {
  __shared__ int s[128];
  int t = threadIdx.x;
  int v = (t < NB_SCAN) ? bsum[t] : 0;
  s[t] = v;
  __syncthreads();
  for (int off = 1; off < 128; off <<= 1) {
    int u = (t >= off) ? s[t - off] : 0;
    __syncthreads();
    s[t] += u;
    __syncthreads();
  }
  if (t < NB_SCAN) bscan[t] = s[t] - v;
}

__global__ __launch_bounds__(256) void k_scanC(int* __restrict__ rowstart,
                                               const int* __restrict__ bscan,
                                               int* __restrict__ cursor,
                                               int* __restrict__ srcl) {
  int off = bscan[blockIdx.x];
  int base = blockIdx.x * SCAN_BLK + threadIdx.x * 4;
#pragma unroll
  for (int j = 0; j < 4; ++j) {
    int i = base + j;
    if (i < NN) {
      int r = rowstart[i] + off;
      rowstart[i] = r;
      srcl[r] = i;            // self-loop first entry
      cursor[i] = r + 1;
    }
  }
}

// ---------------- CSR fill: 6-deep pipelined cursor atomics ----------------
// Each thread owns 6 strided edges: load all pairs (coalesced, independent),
// issue 6 atomic-with-return back-to-back (inline asm), ONE vmcnt wait, 6 stores.
// Kills the per-edge atomic->wait->store serial chain (R10: VGPR=4, VALUBusy 0.3%).
#define AADD(P, D) asm volatile("global_atomic_add %0, %1, %2, off sc0" \
    : "=v"(P) : "v"(cursor + (D)), "v"(one) : "memory")

__global__ __launch_bounds__(256) void k_fill(const int* __restrict__ ei,
                                              int* __restrict__ cursor,
                                              int* __restrict__ srcl) {
  const int T = gridDim.x * blockDim.x;            // 262144
  const int tid = blockIdx.x * blockDim.x + threadIdx.x;
  int one = 1;

  int e = tid;
  int s0 = ei[e], d0 = ei[NE + e]; e += T;
  int s1 = ei[e], d1 = ei[NE + e]; e += T;
  int s2 = ei[e], d2 = ei[NE + e]; e += T;
  int s3 = ei[e], d3 = ei[NE + e]; e += T;
  int s4 = ei[e], d4 = ei[NE + e]; e += T;
  int s5 = ei[e], d5 = ei[NE + e]; e += T;

  int p0, p1, p2, p3, p4, p5;
  AADD(p0, d0); AADD(p1, d1); AADD(p2, d2);
  AADD(p3, d3); AADD(p4, d4); AADD(p5, d5);
  asm volatile("s_waitcnt vmcnt(0)" ::: "memory");
  __builtin_amdgcn_sched_barrier(0);
  srcl[p0] = s0; srcl[p1] = s1; srcl[p2] = s2;
  srcl[p3] = s3; srcl[p4] = s4; srcl[p5] = s5;

  if (e < NE) {                                    // tail (27136 threads)
    int s = ei[e], d = ei[NE + e];
    int p = atomicAdd(&cursor[d], 1);
    srcl[p] = s;
  }
}

// ---------------- gather: h2[r] = b + sum_{srcl entries incl self} g[s] ----------------
#define RF(x) __builtin_amdgcn_readfirstlane(x)
#define GLD(V, I) asm volatile("global_load_ushort %0, %1, %2" \
    : "=v"(V) : "v"(voff), "s"(g + (size_t)(I) * HH) : "memory")
#define WAIT16 do { asm volatile("s_waitcnt vmcnt(16)" ::: "memory"); \
    __builtin_amdgcn_sched_barrier(0); } while (0)
#define WAIT0 do { asm volatile("s_waitcnt vmcnt(0)" ::: "memory"); \
    __builtin_amdgcn_sched_barrier(0); } while (0)
#define ISSUE16(P, EB) do { \
  int j0 = RF(srcl[(EB) + 0]),  j1 = RF(srcl[(EB) + 1]); \
  int j2 = RF(srcl[(EB) + 2]),  j3 = RF(srcl[(EB) + 3]); \
  int j4 = RF(srcl[(EB) + 4]),  j5 = RF(srcl[(EB) + 5]); \
  int j6 = RF(srcl[(EB) + 6]),  j7 = RF(srcl[(EB) + 7]); \
  int j8 = RF(srcl[(EB) + 8]),  j9 = RF(srcl[(EB) + 9]); \
  int j10 = RF(srcl[(EB) + 10]), j11 = RF(srcl[(EB) + 11]); \
  int j12 = RF(srcl[(EB) + 12]), j13 = RF(srcl[(EB) + 13]); \
  int j14 = RF(srcl[(EB) + 14]), j15 = RF(srcl[(EB) + 15]); \
  GLD(P##0, j0);  GLD(P##1, j1);  GLD(P##2, j2);  GLD(P##3, j3); \
  GLD(P##4, j4);  GLD(P##5, j5);  GLD(P##6, j6);  GLD(P##7, j7); \
  GLD(P##8, j8);  GLD(P##9, j9);  GLD(P##10, j10); GLD(P##11, j11); \
  GLD(P##12, j12); GLD(P##13, j13); GLD(P##14, j14); GLD(P##15, j15); \
} while (0)
#define CJ(V, EI) do { \
  if ((EI) == nb) { \
    h2[(size_t)cur * HH + lane] = acc; ps += acc; pss += acc * acc; \
    cur++; nb = __builtin_amdgcn_readlane(rsv, cur - wra); acc = bc; \
  } \
  acc += bf2f(V); } while (0)
#define CONS16(P, EB) do { \
  CJ(P##0, (EB) + 0);  CJ(P##1, (EB) + 1);  CJ(P##2, (EB) + 2);  CJ(P##3, (EB) + 3); \
  CJ(P##4, (EB) + 4);  CJ(P##5, (EB) + 5);  CJ(P##6, (EB) + 6);  CJ(P##7, (EB) + 7); \
  CJ(P##8, (EB) + 8);  CJ(P##9, (EB) + 9);  CJ(P##10, (EB) + 10); CJ(P##11, (EB) + 11); \
  CJ(P##12, (EB) + 12); CJ(P##13, (EB) + 13); CJ(P##14, (EB) + 14); CJ(P##15, (EB) + 15); \
} while (0)

__global__ __launch_bounds__(256) void k_gather(
    const ushort_t* __restrict__ g, const int* __restrict__ rowstart,
    const int* __restrict__ srcl, const float* __restrict__ bias,
    float* __restrict__ h2, float* __restrict__ stats) {
  const int lane = threadIdx.x & 63;
  const int wid  = threadIdx.x >> 6;
  const float bc = bias[lane];
  const uint_t voff = lane * 2;
  const int wra = (blockIdx.x * 4 + wid) * 8;

  int ridx = wra + 1 + lane;
  int rsv = (ridx < NN) ? rowstart[ridx] : NTOT;

  int e    = RF(rowstart[wra]);
  int eEnd = __builtin_amdgcn_readlane(rsv, 7);
  int cur  = wra;
  int nb   = __builtin_amdgcn_readlane(rsv, 0);
  float acc = bc, ps = 0.f, pss = 0.f;

  uint_t A0, A1, A2, A3, A4, A5, A6, A7, A8, A9, A10, A11, A12, A13, A14, A15;
  uint_t B0, B1, B2, B3, B4, B5, B6, B7, B8, B9, B10, B11, B12, B13, B14, B15;

  int n = (eEnd - e) >> 4;
  if (n > 0) {
    int pend = e;
    ISSUE16(A, e); e += 16; n--;
    while (n >= 2) {
      int eb = e;
      ISSUE16(B, e); e += 16; n--;
      WAIT16; CONS16(A, pend); pend = eb;
      int ea = e;
      ISSUE16(A, e); e += 16; n--;
      WAIT16; CONS16(B, pend); pend = ea;
    }
    if (n == 1) {
      int eb = e;
      ISSUE16(B, e); e += 16;
      WAIT16; CONS16(A, pend); pend = eb;
      WAIT0;  CONS16(B, pend);
    } else {
      WAIT0;  CONS16(A, pend);
    }
  }
  for (; e < eEnd; ++e) {
    if (e == nb) {
      h2[(size_t)cur * HH + lane] = acc; ps += acc; pss += acc * acc;
      cur++; nb = __builtin_amdgcn_readlane(rsv, cur - wra); acc = bc;
    }
    int i = RF(srcl[e]);
    acc += bf2f(g[(size_t)i * HH + lane]);
  }
  h2[(size_t)cur * HH + lane] = acc; ps += acc; pss += acc * acc;

  __shared__ float sred[4][128];
  sred[wid][lane] = ps;
  sred[wid][64 + lane] = pss;
  __syncthreads();
  if (wid == 0) {
    float s0 = sred[0][lane] + sred[1][lane] + sred[2][lane] + sred[3][lane];
    float q0 = sred[0][64 + lane] + sred[1][64 + lane] + sred[2][64 + lane] + sred[3][64 + lane];
    atomicAdd(&stats[lane], s0);
    atomicAdd(&stats[HH + lane], q0);
  }
}

// ---------------- final: wsi = max0 + max1 ----------------
__global__ void k_wsi(const float* __restrict__ m0, const float* __restrict__ m1,
                      float* __restrict__ out) {
  int i = threadIdx.x;
  out[i] = m0[i] + m1[i];
}

extern "C" void kernel_launch(void* const* d_in, const int* in_sizes, int n_in,
                              void* d_out, int out_size, void* d_ws, size_t ws_size,
                              hipStream_t stream) {
  const float* x    = (const float*)d_in[0];
  const int*   ei   = (const int*)d_in[1];
  const int*   bat  = (const int*)d_in[2];
  const float* Wf   = (const float*)d_in[3];
  const float* bf   = (const float*)d_in[4];
  const float* g1   = (const float*)d_in[5];
  const float* be1  = (const float*)d_in[6];
  const float* Wl0  = (const float*)d_in[7];
  const float* bl0  = (const float*)d_in[8];
  const float* Wc   = (const float*)d_in[9];
  const float* bc   = (const float*)d_in[10];
  const float* g2   = (const float*)d_in[11];
  const float* be2  = (const float*)d_in[12];
  const float* Wl1  = (const float*)d_in[13];
  const float* bl1  = (const float*)d_in[14];

  float* out   = (float*)d_out;
  float* wsi   = out;                 // [8,4]
  float* npred = out + GG * TT;       // [N,4]

  float*    ws     = (float*)d_ws;
  float*    hbuf   = ws;                              // N*H fp32 (h1, then h2)
  ushort_t* gbf    = (ushort_t*)(hbuf + (size_t)NN * HH);  // N*H bf16 (g)
  float*    stats1 = (float*)(gbf + (size_t)NN * HH); // 256
  float*    stats2 = stats1 + 256;                    // 256
  float*    maxb   = stats2 + 256;                    // 64
  int*      deg      = (int*)(maxb + 64);             // N
  int*      rowstart = deg + NN;                      // N
  int*      cursor   = rowstart + NN;                 // N
  int*      bsum     = cursor + NN;                   // 128
  int*      bscan    = bsum + 128;                    // 128
  int*      srcl     = bscan + 128;                   // NE+NN (self-loops)
  ushort_t* Wbf      = (ushort_t*)(srcl + NTOT);      // DF*HH
  ushort_t* Wbf2     = Wbf + DF * HH;                 // HH*HH

  hipMemsetAsync(deg, 0, NN * sizeof(int), stream);
  k_init<<<dim3(1), dim3(512), 0, stream>>>(stats1, maxb);
  k_prep<<<dim3(64), dim3(256), 0, stream>>>(Wf, Wbf, DF * HH);
  k_prep<<<dim3(16), dim3(256), 0, stream>>>(Wc, Wbf2, HH * HH);

  // CSR build (self-loop slot reserved per row)
  k_count<<<dim3(1024), dim3(256), 0, stream>>>(ei, deg);
  k_scanA<<<dim3(NB_SCAN), dim3(256), 0, stream>>>(deg, rowstart, bsum);
  k_scanB<<<dim3(1), dim3(128), 0, stream>>>(bsum, bscan);
  k_scanC<<<dim3(NB_SCAN), dim3(256), 0, stream>>>(rowstart, bscan, cursor, srcl);
  k_fill<<<dim3(1024), dim3(256), 0, stream>>>(ei, cursor, srcl);

  // Layer 0: GEMM + stats
  k_gemm1_mfma<<<dim3(512), dim3(256), 0, stream>>>(x, Wbf, bf, hbuf, stats1);
  k_finalize_bn<<<dim3(1), dim3(64), 0, stream>>>(stats1, g1, be1, stats1 + 128);
  k_norm_gemm2<<<dim3(512), dim3(256), 0, stream>>>(
      hbuf, stats1 + 128, Wl0, bl0, bat, Wbf2, npred, maxb, gbf);

  // Layer 1: h2 = b + g + A.g (pipelined flat-stream gather)
  k_gather<<<dim3(NN / 32), dim3(256), 0, stream>>>(
      gbf, rowstart, srcl, bc, hbuf, stats2);
  k_finalize_bn<<<dim3(1), dim3(64), 0, stream>>>(stats2, g2, be2, stats2 + 128);
  k_norm_np<0, 1><<<dim3(512), dim3(256), 0, stream>>>(
      hbuf, gbf, stats2 + 128, Wl1, bl1, bat, npred, maxb + 32, (NN + 511) / 512);

  k_wsi<<<dim3(1), dim3(32), 0, stream>>>(maxb, maxb + 32, wsi);
}

// Round 12
// 374.107 us; speedup vs baseline: 2.1503x; 1.1606x over previous
//
#include <hip/hip_runtime.h>
#include <math.h>

#define NN 100000
#define NE 1600000
#define DF 256
#define HH 64
#define TT 4
#define GG 8
#define BN_EPS 1e-5f
#define NTOT (NE + NN)               // srcl entries incl. self-loops

#define SCAN_BLK 1024
#define NB_SCAN ((NN + SCAN_BLK - 1) / SCAN_BLK)   // 98

#define BROWS 512                    // rows per fill bucket
#define NBK ((NN + BROWS - 1) / BROWS)   // 196
#define PCHUNK 1600
#define NPB (NE / PCHUNK)            // 1000

typedef __attribute__((ext_vector_type(8))) short short8v;
typedef __attribute__((ext_vector_type(4))) float f32x4;
typedef unsigned short ushort_t;
typedef unsigned int uint_t;

__device__ __forceinline__ void atomicMaxF(float* addr, float val) {
  if (val >= 0.f) atomicMax((int*)addr, __float_as_int(val));
  else            atomicMin((unsigned int*)addr, __float_as_uint(val));
}

__device__ __forceinline__ short f2bf(float f) {
  uint_t u = __float_as_uint(f);
  u += 0x7FFFu + ((u >> 16) & 1u);
  return (short)(u >> 16);
}
__device__ __forceinline__ float bf2f(uint_t u) { return __uint_as_float(u << 16); }

// ---------------- init ----------------
__global__ void k_init(float* __restrict__ stats, float* __restrict__ maxb) {
  int i = threadIdx.x;
  if (i < 512) stats[i] = 0.f;
  if (i < 64)  maxb[i]  = -INFINITY;
}

// ---------------- prep: fp32 -> bf16 bits ----------------
__global__ void k_prep(const float* __restrict__ W, ushort_t* __restrict__ Wbf, int n) {
  int i = blockIdx.x * 256 + threadIdx.x;
  if (i < n) Wbf[i] = (ushort_t)f2bf(W[i]);
}

// ---------------- GEMM1 (MFMA bf16): h1 = x @ W_first + b, + BN stats ----------------
__global__ __launch_bounds__(256, 2) void k_gemm1_mfma(
    const float* __restrict__ x, const ushort_t* __restrict__ Wbf,
    const float* __restrict__ b, float* __restrict__ h1,
    float* __restrict__ stats) {
  const int lane = threadIdx.x & 63;
  const int li = lane & 15;
  const int lh = lane >> 4;
  const int gw = (blockIdx.x * 256 + (int)threadIdx.x) >> 6;
  const int nw = (gridDim.x * 256) >> 6;

  short8v bf[8][4];
#pragma unroll
  for (int s = 0; s < 8; ++s)
#pragma unroll
    for (int ct = 0; ct < 4; ++ct)
#pragma unroll
      for (int e = 0; e < 8; ++e)
        bf[s][ct][e] = (short)Wbf[(32 * s + 8 * lh + e) * HH + ct * 16 + li];

  float bias[4];
#pragma unroll
  for (int ct = 0; ct < 4; ++ct) bias[ct] = b[ct * 16 + li];

  float ps[4] = {0.f, 0.f, 0.f, 0.f}, pss[4] = {0.f, 0.f, 0.f, 0.f};

  for (int t = gw; t < NN / 16; t += nw) {
    const float* xb = x + (size_t)(t * 16 + li) * DF + 8 * lh;
    f32x4 acc[4];
#pragma unroll
    for (int ct = 0; ct < 4; ++ct) acc[ct] = (f32x4){0.f, 0.f, 0.f, 0.f};

#pragma unroll
    for (int s = 0; s < 8; ++s) {
      float4 a0 = *(const float4*)(xb + 32 * s);
      float4 a1 = *(const float4*)(xb + 32 * s + 4);
      short8v af;
      af[0] = f2bf(a0.x); af[1] = f2bf(a0.y); af[2] = f2bf(a0.z); af[3] = f2bf(a0.w);
      af[4] = f2bf(a1.x); af[5] = f2bf(a1.y); af[6] = f2bf(a1.z); af[7] = f2bf(a1.w);
#pragma unroll
      for (int ct = 0; ct < 4; ++ct)
        acc[ct] = __builtin_amdgcn_mfma_f32_16x16x32_bf16(af, bf[s][ct], acc[ct], 0, 0, 0);
    }

    float* hb = h1 + (size_t)t * 16 * HH;
#pragma unroll
    for (int ct = 0; ct < 4; ++ct) {
#pragma unroll
      for (int r = 0; r < 4; ++r) {
        float h = acc[ct][r] + bias[ct];
        hb[(lh * 4 + r) * HH + ct * 16 + li] = h;
        ps[ct] += h; pss[ct] += h * h;
      }
    }
  }

#pragma unroll
  for (int ct = 0; ct < 4; ++ct) {
    ps[ct]  += __shfl_xor(ps[ct], 16);  ps[ct]  += __shfl_xor(ps[ct], 32);
    pss[ct] += __shfl_xor(pss[ct], 16); pss[ct] += __shfl_xor(pss[ct], 32);
  }
  if (lane < 16) {
#pragma unroll
    for (int ct = 0; ct < 4; ++ct) {
      atomicAdd(&stats[ct * 16 + lane], ps[ct]);
      atomicAdd(&stats[HH + ct * 16 + lane], pss[ct]);
    }
  }
}

// ---------------- BN finalize ----------------
__global__ void k_finalize_bn(const float* __restrict__ sums,
                              const float* __restrict__ gamma,
                              const float* __restrict__ beta,
                              float* __restrict__ ab) {
  int c = threadIdx.x;                                // 64 threads
  float mu  = sums[c] * (1.f / NN);
  float var = sums[HH + c] * (1.f / NN) - mu * mu;
  float a = gamma[c] * rsqrtf(var + BN_EPS);
  ab[c] = a;
  ab[HH + c] = beta[c] - mu * a;
}

// ---------------- fused: normalize(h1)+ReLU; np0 + pool via 5th MFMA tile;
//                  g = f @ W_conv (bf16 out) ----------------
__global__ __launch_bounds__(256) void k_norm_gemm2(
    const float* __restrict__ h1, const float* __restrict__ ab,
    const float* __restrict__ Wl0, const float* __restrict__ bl0,
    const int* __restrict__ batch, const ushort_t* __restrict__ Wbf2,
    float* __restrict__ node_pred, float* __restrict__ maxbuf,
    ushort_t* __restrict__ g) {
  __shared__ float lmax[GG * TT];
  if (threadIdx.x < GG * TT) lmax[threadIdx.x] = -INFINITY;
  __syncthreads();

  const int lane = threadIdx.x & 63;
  const int li = lane & 15;
  const int lh = lane >> 4;
  const int gw = (blockIdx.x * 256 + (int)threadIdx.x) >> 6;
  const int nw = (gridDim.x * 256) >> 6;

  short8v bfr[2][4];
#pragma unroll
  for (int s = 0; s < 2; ++s)
#pragma unroll
    for (int ct = 0; ct < 4; ++ct)
#pragma unroll
      for (int e = 0; e < 8; ++e)
        bfr[s][ct][e] = (short)Wbf2[(32 * s + 8 * lh + e) * HH + ct * 16 + li];

  short8v bhd[2];
#pragma unroll
  for (int s = 0; s < 2; ++s)
#pragma unroll
    for (int e = 0; e < 8; ++e)
      bhd[s][e] = (li < TT) ? f2bf(Wl0[(32 * s + 8 * lh + e) * TT + li]) : (short)0;

  const float4 sa0 = *(const float4*)(ab + 8 * lh);
  const float4 sa1 = *(const float4*)(ab + 8 * lh + 4);
  const float4 sb0 = *(const float4*)(ab + HH + 8 * lh);
  const float4 sb1 = *(const float4*)(ab + HH + 8 * lh + 4);
  const float4 ta0 = *(const float4*)(ab + 32 + 8 * lh);
  const float4 ta1 = *(const float4*)(ab + 32 + 8 * lh + 4);
  const float4 tb0 = *(const float4*)(ab + HH + 32 + 8 * lh);
  const float4 tb1 = *(const float4*)(ab + HH + 32 + 8 * lh + 4);
  const float blv = (li < TT) ? bl0[li] : 0.f;

  for (int t = gw; t < NN / 16; t += nw) {
    const float* hb = h1 + (size_t)(t * 16 + li) * HH + 8 * lh;
    float4 x0 = *(const float4*)(hb);
    float4 x1 = *(const float4*)(hb + 4);
    float4 x2 = *(const float4*)(hb + 32);
    float4 x3 = *(const float4*)(hb + 36);

    short8v af0, af1;
    af0[0] = f2bf(fmaxf(fmaf(sa0.x, x0.x, sb0.x), 0.f));
    af0[1] = f2bf(fmaxf(fmaf(sa0.y, x0.y, sb0.y), 0.f));
    af0[2] = f2bf(fmaxf(fmaf(sa0.z, x0.z, sb0.z), 0.f));
    af0[3] = f2bf(fmaxf(fmaf(sa0.w, x0.w, sb0.w), 0.f));
    af0[4] = f2bf(fmaxf(fmaf(sa1.x, x1.x, sb1.x), 0.f));
    af0[5] = f2bf(fmaxf(fmaf(sa1.y, x1.y, sb1.y), 0.f));
    af0[6] = f2bf(fmaxf(fmaf(sa1.z, x1.z, sb1.z), 0.f));
    af0[7] = f2bf(fmaxf(fmaf(sa1.w, x1.w, sb1.w), 0.f));
    af1[0] = f2bf(fmaxf(fmaf(ta0.x, x2.x, tb0.x), 0.f));
    af1[1] = f2bf(fmaxf(fmaf(ta0.y, x2.y, tb0.y), 0.f));
    af1[2] = f2bf(fmaxf(fmaf(ta0.z, x2.z, tb0.z), 0.f));
    af1[3] = f2bf(fmaxf(fmaf(ta0.w, x2.w, tb0.w), 0.f));
    af1[4] = f2bf(fmaxf(fmaf(ta1.x, x3.x, tb1.x), 0.f));
    af1[5] = f2bf(fmaxf(fmaf(ta1.y, x3.y, tb1.y), 0.f));
    af1[6] = f2bf(fmaxf(fmaf(ta1.z, x3.z, tb1.z), 0.f));
    af1[7] = f2bf(fmaxf(fmaf(ta1.w, x3.w, tb1.w), 0.f));

    f32x4 acc[4], acch;
#pragma unroll
    for (int ct = 0; ct < 4; ++ct) {
      acc[ct] = (f32x4){0.f, 0.f, 0.f, 0.f};
      acc[ct] = __builtin_amdgcn_mfma_f32_16x16x32_bf16(af0, bfr[0][ct], acc[ct], 0, 0, 0);
      acc[ct] = __builtin_amdgcn_mfma_f32_16x16x32_bf16(af1, bfr[1][ct], acc[ct], 0, 0, 0);
    }
    acch = (f32x4){0.f, 0.f, 0.f, 0.f};
    acch = __builtin_amdgcn_mfma_f32_16x16x32_bf16(af0, bhd[0], acch, 0, 0, 0);
    acch = __builtin_amdgcn_mfma_f32_16x16x32_bf16(af1, bhd[1], acch, 0, 0, 0);

    ushort_t* gb = g + (size_t)t * 16 * HH;
#pragma unroll
    for (int ct = 0; ct < 4; ++ct)
#pragma unroll
      for (int r = 0; r < 4; ++r)
        gb[(lh * 4 + r) * HH + ct * 16 + li] = (ushort_t)f2bf(acc[ct][r]);

    if (li < TT) {
#pragma unroll
      for (int r = 0; r < 4; ++r) {
        int row = t * 16 + lh * 4 + r;
        float np = acch[r] + blv;
        atomicMaxF(&lmax[batch[row] * TT + li], np);
        node_pred[(size_t)row * TT + li] = np;
      }
    }
  }
  __syncthreads();
  if (threadIdx.x < GG * TT) atomicMaxF(&maxbuf[threadIdx.x], lmax[threadIdx.x]);
}

// ---------------- normalize+ReLU + head + max-pool (layer 1 epilogue) ----------------
template <int WRITEF, int ADDOUT>
__global__ __launch_bounds__(256) void k_norm_np(
    const float* __restrict__ hin, ushort_t* __restrict__ fout,
    const float* __restrict__ ab, const float* __restrict__ Wlin,
    const float* __restrict__ blin, const int* __restrict__ batch,
    float* __restrict__ node_pred, float* __restrict__ maxbuf, int rpb) {
  __shared__ float lmax[GG * TT];
  if (threadIdx.x < GG * TT) lmax[threadIdx.x] = -INFINITY;
  __syncthreads();

  const int lane = threadIdx.x & 63;
  const int wid  = threadIdx.x >> 6;
  const float a  = ab[lane];
  const float b2 = ab[HH + lane];
  const float4 w = ((const float4*)Wlin)[lane];
  const float4 bl = *(const float4*)blin;
  int r0 = blockIdx.x * rpb;
  int r1 = min(r0 + rpb, NN);

  for (int r = r0 + wid; r < r1; r += 4) {
    float h = hin[(size_t)r * HH + lane];
    float f = fmaxf(fmaf(a, h, b2), 0.f);
    if (WRITEF) fout[(size_t)r * HH + lane] = (ushort_t)f2bf(f);
    float p0 = f * w.x, p1 = f * w.y, p2 = f * w.z, p3 = f * w.w;
#pragma unroll
    for (int off = 32; off; off >>= 1) {
      p0 += __shfl_xor(p0, off);
      p1 += __shfl_xor(p1, off);
      p2 += __shfl_xor(p2, off);
      p3 += __shfl_xor(p3, off);
    }
    if (lane == 0) {
      float4 np;
      np.x = p0 + bl.x; np.y = p1 + bl.y; np.z = p2 + bl.z; np.w = p3 + bl.w;
      int g = batch[r];
      atomicMaxF(&lmax[g * TT + 0], np.x);
      atomicMaxF(&lmax[g * TT + 1], np.y);
      atomicMaxF(&lmax[g * TT + 2], np.z);
      atomicMaxF(&lmax[g * TT + 3], np.w);
      float4* op = (float4*)(node_pred + (size_t)r * TT);
      if (ADDOUT) {
        float4 o = *op;
        np.x += o.x; np.y += o.y; np.z += o.z; np.w += o.w;
      }
      *op = np;
    }
  }
  __syncthreads();
  if (threadIdx.x < GG * TT) atomicMaxF(&maxbuf[threadIdx.x], lmax[threadIdx.x]);
}

// ---------------- CSR build (with self-loops: row i = [self, edges...]) ----------------
__global__ __launch_bounds__(256) void k_count(const int* __restrict__ ei,
                                               int* __restrict__ deg) {
  int i = blockIdx.x * blockDim.x + threadIdx.x;
  int n = gridDim.x * blockDim.x;
  for (int e = i; e < NE; e += n) atomicAdd(&deg[ei[NE + e]], 1);
}

__global__ __launch_bounds__(256) void k_scanA(const int* __restrict__ deg,
                                               int* __restrict__ rowstart,
                                               int* __restrict__ bsum) {
  __shared__ int s[256];
  int t = threadIdx.x;
  int base = blockIdx.x * SCAN_BLK + t * 4;
  int d0 = 0, d1 = 0, d2 = 0, d3 = 0;
  if (base + 3 < NN) {
    int4 v = *(const int4*)(deg + base);
    d0 = v.x; d1 = v.y; d2 = v.z; d3 = v.w;
  } else {
    if (base + 0 < NN) d0 = deg[base + 0];
    if (base + 1 < NN) d1 = deg[base + 1];
    if (base + 2 < NN) d2 = deg[base + 2];
    if (base + 3 < NN) d3 = deg[base + 3];
  }
  int c0 = (base + 0 < NN) ? d0 + 1 : 0;
  int c1 = (base + 1 < NN) ? d1 + 1 : 0;
  int c2 = (base + 2 < NN) ? d2 + 1 : 0;
  int c3 = (base + 3 < NN) ? d3 + 1 : 0;
  int ts = c0 + c1 + c2 + c3;
  s[t] = ts;
  __syncthreads();
  for (int off = 1; off < 256; off <<= 1) {
    int v = (t >= off) ? s[t - off] : 0;
    __syncthreads();
    s[t] += v;
    __syncthreads();
  }
  int excl = s[t] - ts;
  if (base + 0 < NN) rowstart[base + 0] = excl;  excl += c0;
  if (base + 1 < NN) rowstart[base + 1] = excl;  excl += c1;
  if (base + 2 < NN) rowstart[base + 2] = excl;  excl += c2;
  if (base + 3 < NN) rowstart[base + 3] = excl;
  if (t == 255) bsum[blockIdx.x] = s[255];
}

__global__ void k_scanB(const int* __restrict__ bsum, int* __restrict__ bscan) {
  __shared__ int s[128];
  int t = threadIdx.x;
  int v = (t < NB_SCAN) ? bsum[t] : 0;
  s[t] = v;
  __syncthreads();
  for (int off = 1; off < 128; off <<= 1) {
    int u = (t >= off) ? s[t - off] : 0;
    __syncthreads();
    s[t] += u;
    __syncthreads();
  }
  if (t < NB_SCAN) bscan[t] = s[t] - v;
}

__global__ __launch_bounds__(256) void k_scanC(int* __restrict__ rowstart,
                                               const int* __restrict__ bscan,
                                               int* __restrict__ srcl) {
  int off = bscan[blockIdx.x];
  int base = blockIdx.x * SCAN_BLK + threadIdx.x * 4;
#pragma unroll
  for (int j = 0; j < 4; ++j) {
    int i = base + j;
    if (i < NN) {
      int r = rowstart[i] + off;
      rowstart[i] = r;
      srcl[r] = i;            // self-loop first entry
    }
  }
}

// ---------------- bucketed fill ----------------
// k_binit: per-bucket edge cursors from rowstart
__global__ void k_binit(const int* __restrict__ rowstart, int* __restrict__ Bcur) {
  int t = threadIdx.x;
  if (t < NBK) Bcur[t] = rowstart[t * BROWS] - t * BROWS;
}

// k_part: bin edges by dst-bucket via LDS, bulk-reserve, coalesced pair copy
__global__ __launch_bounds__(256) void k_part(
    const int* __restrict__ ei, int* __restrict__ Bcur,
    uint2* __restrict__ ebuf) {
  __shared__ int hist[256], start[256], cnt[256], gbase[256];
  __shared__ int ssrc[PCHUNK], sdst[PCHUNK];
  const int t = threadIdx.x;
  hist[t] = 0; cnt[t] = 0;
  __syncthreads();
  const int e0 = blockIdx.x * PCHUNK;
  for (int i = t; i < PCHUNK; i += 256)
    atomicAdd(&hist[ei[NE + e0 + i] >> 9], 1);
  __syncthreads();
  int v = hist[t];
  start[t] = v;
  __syncthreads();
  for (int off = 1; off < 256; off <<= 1) {
    int u = (t >= off) ? start[t - off] : 0;
    __syncthreads();
    start[t] += u;
    __syncthreads();
  }
  int incl = start[t];
  __syncthreads();
  start[t] = incl - v;                       // exclusive
  if (v > 0) gbase[t] = atomicAdd(&Bcur[t], v);
  __syncthreads();
  for (int i = t; i < PCHUNK; i += 256) {
    int src = ei[e0 + i];
    int dst = ei[NE + e0 + i];
    int b = dst >> 9;
    int p = start[b] + atomicAdd(&cnt[b], 1);
    ssrc[p] = src; sdst[p] = dst;
  }
  __syncthreads();
  for (int i = t; i < PCHUNK; i += 256) {
    int dst = sdst[i];
    int b = dst >> 9;
    uint2 pr; pr.x = (uint_t)ssrc[i]; pr.y = (uint_t)dst;
    ebuf[gbase[b] + (i - start[b])] = pr;
  }
}

// k_fill2: one block per bucket; row cursors in LDS; srcl writes in a 34KB window
__global__ __launch_bounds__(256) void k_fill2(
    const int* __restrict__ rowstart, const uint2* __restrict__ ebuf,
    int* __restrict__ srcl) {
  __shared__ int c[BROWS];
  const int b = blockIdx.x;
  const int r0 = b * BROWS;
  const int rend = min(r0 + BROWS, NN);
  for (int i = threadIdx.x; i < rend - r0; i += 256)
    c[i] = rowstart[r0 + i] + 1;             // slot 0 = self-loop
  __syncthreads();
  const int eb0 = rowstart[r0] - r0;
  const int eb1 = (b == NBK - 1) ? NE : rowstart[r0 + BROWS] - (r0 + BROWS);
  for (int e = eb0 + (int)threadIdx.x; e < eb1; e += 256) {
    uint2 pr = ebuf[e];
    int p = atomicAdd(&c[(int)pr.y - r0], 1);
    srcl[p] = (int)pr.x;
  }
}

// ---------------- gather: h2[r] = b + sum_{srcl entries incl self} g[s] ----------------
#define RF(x) __builtin_amdgcn_readfirstlane(x)
#define GLD(V, I) asm volatile("global_load_ushort %0, %1, %2" \
    : "=v"(V) : "v"(voff), "s"(g + (size_t)(I) * HH) : "memory")
#define WAIT16 do { asm volatile("s_waitcnt vmcnt(16)" ::: "memory"); \
    __builtin_amdgcn_sched_barrier(0); } while (0)
#define WAIT0 do { asm volatile("s_waitcnt vmcnt(0)" ::: "memory"); \
    __builtin_amdgcn_sched_barrier(0); } while (0)
#define ISSUE16(P, EB) do { \
  int j0 = RF(srcl[(EB) + 0]),  j1 = RF(srcl[(EB) + 1]); \
  int j2 = RF(srcl[(EB) + 2]),  j3 = RF(srcl[(EB) + 3]); \
  int j4 = RF(srcl[(EB) + 4]),  j5 = RF(srcl[(EB) + 5]); \
  int j6 = RF(srcl[(EB) + 6]),  j7 = RF(srcl[(EB) + 7]); \
  int j8 = RF(srcl[(EB) + 8]),  j9 = RF(srcl[(EB) + 9]); \
  int j10 = RF(srcl[(EB) + 10]), j11 = RF(srcl[(EB) + 11]); \
  int j12 = RF(srcl[(EB) + 12]), j13 = RF(srcl[(EB) + 13]); \
  int j14 = RF(srcl[(EB) + 14]), j15 = RF(srcl[(EB) + 15]); \
  GLD(P##0, j0);  GLD(P##1, j1);  GLD(P##2, j2);  GLD(P##3, j3); \
  GLD(P##4, j4);  GLD(P##5, j5);  GLD(P##6, j6);  GLD(P##7, j7); \
  GLD(P##8, j8);  GLD(P##9, j9);  GLD(P##10, j10); GLD(P##11, j11); \
  GLD(P##12, j12); GLD(P##13, j13); GLD(P##14, j14); GLD(P##15, j15); \
} while (0)
#define CJ(V, EI) do { \
  if ((EI) == nb) { \
    h2[(size_t)cur * HH + lane] = acc; ps += acc; pss += acc * acc; \
    cur++; nb = __builtin_amdgcn_readlane(rsv, cur - wra); acc = bc; \
  } \
  acc += bf2f(V); } while (0)
#define CONS16(P, EB) do { \
  CJ(P##0, (EB) + 0);  CJ(P##1, (EB) + 1);  CJ(P##2, (EB) + 2);  CJ(P##3, (EB) + 3); \
  CJ(P##4, (EB) + 4);  CJ(P##5, (EB) + 5);  CJ(P##6, (EB) + 6);  CJ(P##7, (EB) + 7); \
  CJ(P##8, (EB) + 8);  CJ(P##9, (EB) + 9);  CJ(P##10, (EB) + 10); CJ(P##11, (EB) + 11); \
  CJ(P##12, (EB) + 12); CJ(P##13, (EB) + 13); CJ(P##14, (EB) + 14); CJ(P##15, (EB) + 15); \
} while (0)

__global__ __launch_bounds__(256) void k_gather(
    const ushort_t* __restrict__ g, const int* __restrict__ rowstart,
    const int* __restrict__ srcl, const float* __restrict__ bias,
    float* __restrict__ h2, float* __restrict__ stats) {
  const int lane = threadIdx.x & 63;
  const int wid  = threadIdx.x >> 6;
  const float bc = bias[lane];
  const uint_t voff = lane * 2;
  const int wra = (blockIdx.x * 4 + wid) * 8;

  int ridx = wra + 1 + lane;
  int rsv = (ridx < NN) ? rowstart[ridx] : NTOT;

  int e    = RF(rowstart[wra]);
  int eEnd = __builtin_amdgcn_readlane(rsv, 7);
  int cur  = wra;
  int nb   = __builtin_amdgcn_readlane(rsv, 0);
  float acc = bc, ps = 0.f, pss = 0.f;

  uint_t A0, A1, A2, A3, A4, A5, A6, A7, A8, A9, A10, A11, A12, A13, A14, A15;
  uint_t B0, B1, B2, B3, B4, B5, B6, B7, B8, B9, B10, B11, B12, B13, B14, B15;

  int n = (eEnd - e) >> 4;
  if (n > 0) {
    int pend = e;
    ISSUE16(A, e); e += 16; n--;
    while (n >= 2) {
      int eb = e;
      ISSUE16(B, e); e += 16; n--;
      WAIT16; CONS16(A, pend); pend = eb;
      int ea = e;
      ISSUE16(A, e); e += 16; n--;
      WAIT16; CONS16(B, pend); pend = ea;
    }
    if (n == 1) {
      int eb = e;
      ISSUE16(B, e); e += 16;
      WAIT16; CONS16(A, pend); pend = eb;
      WAIT0;  CONS16(B, pend);
    } else {
      WAIT0;  CONS16(A, pend);
    }
  }
  for (; e < eEnd; ++e) {
    if (e == nb) {
      h2[(size_t)cur * HH + lane] = acc; ps += acc; pss += acc * acc;
      cur++; nb = __builtin_amdgcn_readlane(rsv, cur - wra); acc = bc;
    }
    int i = RF(srcl[e]);
    acc += bf2f(g[(size_t)i * HH + lane]);
  }
  h2[(size_t)cur * HH + lane] = acc; ps += acc; pss += acc * acc;

  __shared__ float sred[4][128];
  sred[wid][lane] = ps;
  sred[wid][64 + lane] = pss;
  __syncthreads();
  if (wid == 0) {
    float s0 = sred[0][lane] + sred[1][lane] + sred[2][lane] + sred[3][lane];
    float q0 = sred[0][64 + lane] + sred[1][64 + lane] + sred[2][64 + lane] + sred[3][64 + lane];
    atomicAdd(&stats[lane], s0);
    atomicAdd(&stats[HH + lane], q0);
  }
}

// ---------------- final: wsi = max0 + max1 ----------------
__global__ void k_wsi(const float* __restrict__ m0, const float* __restrict__ m1,
                      float* __restrict__ out) {
  int i = threadIdx.x;
  out[i] = m0[i] + m1[i];
}

extern "C" void kernel_launch(void* const* d_in, const int* in_sizes, int n_in,
                              void* d_out, int out_size, void* d_ws, size_t ws_size,
                              hipStream_t stream) {
  const float* x    = (const float*)d_in[0];
  const int*   ei   = (const int*)d_in[1];
  const int*   bat  = (const int*)d_in[2];
  const float* Wf   = (const float*)d_in[3];
  const float* bf   = (const float*)d_in[4];
  const float* g1   = (const float*)d_in[5];
  const float* be1  = (const float*)d_in[6];
  const float* Wl0  = (const float*)d_in[7];
  const float* bl0  = (const float*)d_in[8];
  const float* Wc   = (const float*)d_in[9];
  const float* bc   = (const float*)d_in[10];
  const float* g2   = (const float*)d_in[11];
  const float* be2  = (const float*)d_in[12];
  const float* Wl1  = (const float*)d_in[13];
  const float* bl1  = (const float*)d_in[14];

  float* out   = (float*)d_out;
  float* wsi   = out;                 // [8,4]
  float* npred = out + GG * TT;       // [N,4]

  float*    ws     = (float*)d_ws;
  float*    hbuf   = ws;                              // N*H fp32 (h1, then h2)
  ushort_t* gbf    = (ushort_t*)(hbuf + (size_t)NN * HH);  // N*H bf16 (g)
  float*    stats1 = (float*)(gbf + (size_t)NN * HH); // 256
  float*    stats2 = stats1 + 256;                    // 256
  float*    maxb   = stats2 + 256;                    // 64
  int*      deg      = (int*)(maxb + 64);             // N
  int*      rowstart = deg + NN;                      // N
  int*      Bcur     = rowstart + NN;                 // 256
  int*      bsum     = Bcur + 256;                    // 128
  int*      bscan    = bsum + 128;                    // 128
  int*      srcl     = bscan + 128;                   // NE+NN (self-loops)
  uint2*    ebuf     = (uint2*)(srcl + NTOT);         // NE pairs
  ushort_t* Wbf      = (ushort_t*)(ebuf + NE);        // DF*HH
  ushort_t* Wbf2     = Wbf + DF * HH;                 // HH*HH

  hipMemsetAsync(deg, 0, NN * sizeof(int), stream);
  k_init<<<dim3(1), dim3(512), 0, stream>>>(stats1, maxb);
  k_prep<<<dim3(64), dim3(256), 0, stream>>>(Wf, Wbf, DF * HH);
  k_prep<<<dim3(16), dim3(256), 0, stream>>>(Wc, Wbf2, HH * HH);

  // CSR build (self-loop slot reserved per row) — bucketed fill
  k_count<<<dim3(1024), dim3(256), 0, stream>>>(ei, deg);
  k_scanA<<<dim3(NB_SCAN), dim3(256), 0, stream>>>(deg, rowstart, bsum);
  k_scanB<<<dim3(1), dim3(128), 0, stream>>>(bsum, bscan);
  k_scanC<<<dim3(NB_SCAN), dim3(256), 0, stream>>>(rowstart, bscan, srcl);
  k_binit<<<dim3(1), dim3(256), 0, stream>>>(rowstart, Bcur);
  k_part<<<dim3(NPB), dim3(256), 0, stream>>>(ei, Bcur, ebuf);
  k_fill2<<<dim3(NBK), dim3(256), 0, stream>>>(rowstart, ebuf, srcl);

  // Layer 0: GEMM + stats
  k_gemm1_mfma<<<dim3(512), dim3(256), 0, stream>>>(x, Wbf, bf, hbuf, stats1);
  k_finalize_bn<<<dim3(1), dim3(64), 0, stream>>>(stats1, g1, be1, stats1 + 128);
  k_norm_gemm2<<<dim3(512), dim3(256), 0, stream>>>(
      hbuf, stats1 + 128, Wl0, bl0, bat, Wbf2, npred, maxb, gbf);

  // Layer 1: h2 = b + g + A.g (pipelined flat-stream gather)
  k_gather<<<dim3(NN / 32), dim3(256), 0, stream>>>(
      gbf, rowstart, srcl, bc, hbuf, stats2);
  k_finalize_bn<<<dim3(1), dim3(64), 0, stream>>>(stats2, g2, be2, stats2 + 128);
  k_norm_np<0, 1><<<dim3(512), dim3(256), 0, stream>>>(
      hbuf, gbf, stats2 + 128, Wl1, bl1, bat, npred, maxb + 32, (NN + 511) / 512);

  k_wsi<<<dim3(1), dim3(32), 0, stream>>>(maxb, maxb + 32, wsi);
}

// Round 13
// 370.511 us; speedup vs baseline: 2.1711x; 1.0097x over previous
//
#include <hip/hip_runtime.h>
#include <math.h>

#define NN 100000
#define NE 1600000
#define DF 256
#define HH 64
#define TT 4
#define GG 8
#define BN_EPS 1e-5f
#define NTOT (NE + NN)               // srcl entries incl. self-loops

#define SCAN_BLK 1024
#define NB_SCAN ((NN + SCAN_BLK - 1) / SCAN_BLK)   // 98

#define BROWS 512                    // rows per fill bucket
#define NBK ((NN + BROWS - 1) / BROWS)   // 196
#define PCHUNK 1600
#define NPB (NE / PCHUNK)            // 1000

typedef __attribute__((ext_vector_type(8))) short short8v;
typedef __attribute__((ext_vector_type(4))) float f32x4;
typedef unsigned short ushort_t;
typedef unsigned int uint_t;

__device__ __forceinline__ void atomicMaxF(float* addr, float val) {
  if (val >= 0.f) atomicMax((int*)addr, __float_as_int(val));
  else            atomicMin((unsigned int*)addr, __float_as_uint(val));
}

__device__ __forceinline__ short f2bf(float f) {
  uint_t u = __float_as_uint(f);
  u += 0x7FFFu + ((u >> 16) & 1u);
  return (short)(u >> 16);
}
__device__ __forceinline__ float bf2f(uint_t u) { return __uint_as_float(u << 16); }
__device__ __forceinline__ float bfhi(uint_t u) { return __uint_as_float(u & 0xFFFF0000u); }

// ---------------- init ----------------
__global__ void k_init(float* __restrict__ stats, float* __restrict__ maxb) {
  int i = threadIdx.x;
  if (i < 512) stats[i] = 0.f;
  if (i < 64)  maxb[i]  = -INFINITY;
}

// ---------------- prep: fp32 -> bf16 bits ----------------
__global__ void k_prep(const float* __restrict__ W, ushort_t* __restrict__ Wbf, int n) {
  int i = blockIdx.x * 256 + threadIdx.x;
  if (i < n) Wbf[i] = (ushort_t)f2bf(W[i]);
}

// ---------------- GEMM1 (MFMA bf16): h1 = x @ W_first + b (bf16 out), + BN stats ----------------
__global__ __launch_bounds__(256, 2) void k_gemm1_mfma(
    const float* __restrict__ x, const ushort_t* __restrict__ Wbf,
    const float* __restrict__ b, ushort_t* __restrict__ h1,
    float* __restrict__ stats) {
  const int lane = threadIdx.x & 63;
  const int li = lane & 15;
  const int lh = lane >> 4;
  const int gw = (blockIdx.x * 256 + (int)threadIdx.x) >> 6;
  const int nw = (gridDim.x * 256) >> 6;

  short8v bf[8][4];
#pragma unroll
  for (int s = 0; s < 8; ++s)
#pragma unroll
    for (int ct = 0; ct < 4; ++ct)
#pragma unroll
      for (int e = 0; e < 8; ++e)
        bf[s][ct][e] = (short)Wbf[(32 * s + 8 * lh + e) * HH + ct * 16 + li];

  float bias[4];
#pragma unroll
  for (int ct = 0; ct < 4; ++ct) bias[ct] = b[ct * 16 + li];

  float ps[4] = {0.f, 0.f, 0.f, 0.f}, pss[4] = {0.f, 0.f, 0.f, 0.f};

  for (int t = gw; t < NN / 16; t += nw) {
    const float* xb = x + (size_t)(t * 16 + li) * DF + 8 * lh;
    f32x4 acc[4];
#pragma unroll
    for (int ct = 0; ct < 4; ++ct) acc[ct] = (f32x4){0.f, 0.f, 0.f, 0.f};

#pragma unroll
    for (int s = 0; s < 8; ++s) {
      float4 a0 = *(const float4*)(xb + 32 * s);
      float4 a1 = *(const float4*)(xb + 32 * s + 4);
      short8v af;
      af[0] = f2bf(a0.x); af[1] = f2bf(a0.y); af[2] = f2bf(a0.z); af[3] = f2bf(a0.w);
      af[4] = f2bf(a1.x); af[5] = f2bf(a1.y); af[6] = f2bf(a1.z); af[7] = f2bf(a1.w);
#pragma unroll
      for (int ct = 0; ct < 4; ++ct)
        acc[ct] = __builtin_amdgcn_mfma_f32_16x16x32_bf16(af, bf[s][ct], acc[ct], 0, 0, 0);
    }

    ushort_t* hb = h1 + (size_t)t * 16 * HH;
#pragma unroll
    for (int ct = 0; ct < 4; ++ct) {
#pragma unroll
      for (int r = 0; r < 4; ++r) {
        float h = acc[ct][r] + bias[ct];
        hb[(lh * 4 + r) * HH + ct * 16 + li] = (ushort_t)f2bf(h);
        ps[ct] += h; pss[ct] += h * h;
      }
    }
  }

#pragma unroll
  for (int ct = 0; ct < 4; ++ct) {
    ps[ct]  += __shfl_xor(ps[ct], 16);  ps[ct]  += __shfl_xor(ps[ct], 32);
    pss[ct] += __shfl_xor(pss[ct], 16); pss[ct] += __shfl_xor(pss[ct], 32);
  }
  if (lane < 16) {
#pragma unroll
    for (int ct = 0; ct < 4; ++ct) {
      atomicAdd(&stats[ct * 16 + lane], ps[ct]);
      atomicAdd(&stats[HH + ct * 16 + lane], pss[ct]);
    }
  }
}

// ---------------- BN finalize ----------------
__global__ void k_finalize_bn(const float* __restrict__ sums,
                              const float* __restrict__ gamma,
                              const float* __restrict__ beta,
                              float* __restrict__ ab) {
  int c = threadIdx.x;                                // 64 threads
  float mu  = sums[c] * (1.f / NN);
  float var = sums[HH + c] * (1.f / NN) - mu * mu;
  float a = gamma[c] * rsqrtf(var + BN_EPS);
  ab[c] = a;
  ab[HH + c] = beta[c] - mu * a;
}

// ---------------- fused: normalize(h1 bf16)+ReLU; np0 + pool via 5th MFMA tile;
//                  g = f @ W_conv (bf16 out) ----------------
__global__ __launch_bounds__(256) void k_norm_gemm2(
    const ushort_t* __restrict__ h1, const float* __restrict__ ab,
    const float* __restrict__ Wl0, const float* __restrict__ bl0,
    const int* __restrict__ batch, const ushort_t* __restrict__ Wbf2,
    float* __restrict__ node_pred, float* __restrict__ maxbuf,
    ushort_t* __restrict__ g) {
  __shared__ float lmax[GG * TT];
  if (threadIdx.x < GG * TT) lmax[threadIdx.x] = -INFINITY;
  __syncthreads();

  const int lane = threadIdx.x & 63;
  const int li = lane & 15;
  const int lh = lane >> 4;
  const int gw = (blockIdx.x * 256 + (int)threadIdx.x) >> 6;
  const int nw = (gridDim.x * 256) >> 6;

  short8v bfr[2][4];
#pragma unroll
  for (int s = 0; s < 2; ++s)
#pragma unroll
    for (int ct = 0; ct < 4; ++ct)
#pragma unroll
      for (int e = 0; e < 8; ++e)
        bfr[s][ct][e] = (short)Wbf2[(32 * s + 8 * lh + e) * HH + ct * 16 + li];

  short8v bhd[2];
#pragma unroll
  for (int s = 0; s < 2; ++s)
#pragma unroll
    for (int e = 0; e < 8; ++e)
      bhd[s][e] = (li < TT) ? f2bf(Wl0[(32 * s + 8 * lh + e) * TT + li]) : (short)0;

  const float4 sa0 = *(const float4*)(ab + 8 * lh);
  const float4 sa1 = *(const float4*)(ab + 8 * lh + 4);
  const float4 sb0 = *(const float4*)(ab + HH + 8 * lh);
  const float4 sb1 = *(const float4*)(ab + HH + 8 * lh + 4);
  const float4 ta0 = *(const float4*)(ab + 32 + 8 * lh);
  const float4 ta1 = *(const float4*)(ab + 32 + 8 * lh + 4);
  const float4 tb0 = *(const float4*)(ab + HH + 32 + 8 * lh);
  const float4 tb1 = *(const float4*)(ab + HH + 32 + 8 * lh + 4);
  const float blv = (li < TT) ? bl0[li] : 0.f;

  for (int t = gw; t < NN / 16; t += nw) {
    const ushort_t* hb = h1 + (size_t)(t * 16 + li) * HH + 8 * lh;
    uint4 xa = *(const uint4*)(hb);        // 8 bf16: cols 8lh..8lh+7
    uint4 xc = *(const uint4*)(hb + 32);   // 8 bf16: cols 32+8lh..

    short8v af0, af1;
    af0[0] = f2bf(fmaxf(fmaf(sa0.x, bf2f(xa.x), sb0.x), 0.f));
    af0[1] = f2bf(fmaxf(fmaf(sa0.y, bfhi(xa.x), sb0.y), 0.f));
    af0[2] = f2bf(fmaxf(fmaf(sa0.z, bf2f(xa.y), sb0.z), 0.f));
    af0[3] = f2bf(fmaxf(fmaf(sa0.w, bfhi(xa.y), sb0.w), 0.f));
    af0[4] = f2bf(fmaxf(fmaf(sa1.x, bf2f(xa.z), sb1.x), 0.f));
    af0[5] = f2bf(fmaxf(fmaf(sa1.y, bfhi(xa.z), sb1.y), 0.f));
    af0[6] = f2bf(fmaxf(fmaf(sa1.z, bf2f(xa.w), sb1.z), 0.f));
    af0[7] = f2bf(fmaxf(fmaf(sa1.w, bfhi(xa.w), sb1.w), 0.f));
    af1[0] = f2bf(fmaxf(fmaf(ta0.x, bf2f(xc.x), tb0.x), 0.f));
    af1[1] = f2bf(fmaxf(fmaf(ta0.y, bfhi(xc.x), tb0.y), 0.f));
    af1[2] = f2bf(fmaxf(fmaf(ta0.z, bf2f(xc.y), tb0.z), 0.f));
    af1[3] = f2bf(fmaxf(fmaf(ta0.w, bfhi(xc.y), tb0.w), 0.f));
    af1[4] = f2bf(fmaxf(fmaf(ta1.x, bf2f(xc.z), tb1.x), 0.f));
    af1[5] = f2bf(fmaxf(fmaf(ta1.y, bfhi(xc.z), tb1.y), 0.f));
    af1[6] = f2bf(fmaxf(fmaf(ta1.z, bf2f(xc.w), tb1.z), 0.f));
    af1[7] = f2bf(fmaxf(fmaf(ta1.w, bfhi(xc.w), tb1.w), 0.f));

    f32x4 acc[4], acch;
#pragma unroll
    for (int ct = 0; ct < 4; ++ct) {
      acc[ct] = (f32x4){0.f, 0.f, 0.f, 0.f};
      acc[ct] = __builtin_amdgcn_mfma_f32_16x16x32_bf16(af0, bfr[0][ct], acc[ct], 0, 0, 0);
      acc[ct] = __builtin_amdgcn_mfma_f32_16x16x32_bf16(af1, bfr[1][ct], acc[ct], 0, 0, 0);
    }
    acch = (f32x4){0.f, 0.f, 0.f, 0.f};
    acch = __builtin_amdgcn_mfma_f32_16x16x32_bf16(af0, bhd[0], acch, 0, 0, 0);
    acch = __builtin_amdgcn_mfma_f32_16x16x32_bf16(af1, bhd[1], acch, 0, 0, 0);

    ushort_t* gb = g + (size_t)t * 16 * HH;
#pragma unroll
    for (int ct = 0; ct < 4; ++ct)
#pragma unroll
      for (int r = 0; r < 4; ++r)
        gb[(lh * 4 + r) * HH + ct * 16 + li] = (ushort_t)f2bf(acc[ct][r]);

    if (li < TT) {
#pragma unroll
      for (int r = 0; r < 4; ++r) {
        int row = t * 16 + lh * 4 + r;
        float np = acch[r] + blv;
        atomicMaxF(&lmax[batch[row] * TT + li], np);
        node_pred[(size_t)row * TT + li] = np;
      }
    }
  }
  __syncthreads();
  if (threadIdx.x < GG * TT) atomicMaxF(&maxbuf[threadIdx.x], lmax[threadIdx.x]);
}

// ---------------- normalize+ReLU + head + max-pool (layer 1 epilogue) ----------------
__global__ __launch_bounds__(256) void k_norm_np(
    const float* __restrict__ hin,
    const float* __restrict__ ab, const float* __restrict__ Wlin,
    const float* __restrict__ blin, const int* __restrict__ batch,
    float* __restrict__ node_pred, float* __restrict__ maxbuf, int rpb) {
  __shared__ float lmax[GG * TT];
  if (threadIdx.x < GG * TT) lmax[threadIdx.x] = -INFINITY;
  __syncthreads();

  const int lane = threadIdx.x & 63;
  const int wid  = threadIdx.x >> 6;
  const float a  = ab[lane];
  const float b2 = ab[HH + lane];
  const float4 w = ((const float4*)Wlin)[lane];
  const float4 bl = *(const float4*)blin;
  int r0 = blockIdx.x * rpb;
  int r1 = min(r0 + rpb, NN);

  for (int r = r0 + wid; r < r1; r += 4) {
    float h = hin[(size_t)r * HH + lane];
    float f = fmaxf(fmaf(a, h, b2), 0.f);
    float p0 = f * w.x, p1 = f * w.y, p2 = f * w.z, p3 = f * w.w;
#pragma unroll
    for (int off = 32; off; off >>= 1) {
      p0 += __shfl_xor(p0, off);
      p1 += __shfl_xor(p1, off);
      p2 += __shfl_xor(p2, off);
      p3 += __shfl_xor(p3, off);
    }
    if (lane == 0) {
      float4 np;
      np.x = p0 + bl.x; np.y = p1 + bl.y; np.z = p2 + bl.z; np.w = p3 + bl.w;
      int g = batch[r];
      atomicMaxF(&lmax[g * TT + 0], np.x);
      atomicMaxF(&lmax[g * TT + 1], np.y);
      atomicMaxF(&lmax[g * TT + 2], np.z);
      atomicMaxF(&lmax[g * TT + 3], np.w);
      float4* op = (float4*)(node_pred + (size_t)r * TT);
      float4 o = *op;
      np.x += o.x; np.y += o.y; np.z += o.z; np.w += o.w;
      *op = np;
    }
  }
  __syncthreads();
  if (threadIdx.x < GG * TT) atomicMaxF(&maxbuf[threadIdx.x], lmax[threadIdx.x]);
}

// ---------------- CSR build (with self-loops: row i = [self, edges...]) ----------------
__global__ __launch_bounds__(256) void k_count(const int* __restrict__ ei,
                                               int* __restrict__ deg) {
  int i = blockIdx.x * blockDim.x + threadIdx.x;
  int n = gridDim.x * blockDim.x;
  for (int e = i; e < NE; e += n) atomicAdd(&deg[ei[NE + e]], 1);
}

__global__ __launch_bounds__(256) void k_scanA(const int* __restrict__ deg,
                                               int* __restrict__ rowstart,
                                               int* __restrict__ bsum) {
  __shared__ int s[256];
  int t = threadIdx.x;
  int base = blockIdx.x * SCAN_BLK + t * 4;
  int d0 = 0, d1 = 0, d2 = 0, d3 = 0;
  if (base + 3 < NN) {
    int4 v = *(const int4*)(deg + base);
    d0 = v.x; d1 = v.y; d2 = v.z; d3 = v.w;
  } else {
    if (base + 0 < NN) d0 = deg[base + 0];
    if (base + 1 < NN) d1 = deg[base + 1];
    if (base + 2 < NN) d2 = deg[base + 2];
    if (base + 3 < NN) d3 = deg[base + 3];
  }
  int c0 = (base + 0 < NN) ? d0 + 1 : 0;
  int c1 = (base + 1 < NN) ? d1 + 1 : 0;
  int c2 = (base + 2 < NN) ? d2 + 1 : 0;
  int c3 = (base + 3 < NN) ? d3 + 1 : 0;
  int ts = c0 + c1 + c2 + c3;
  s[t] = ts;
  __syncthreads();
  for (int off = 1; off < 256; off <<= 1) {
    int v = (t >= off) ? s[t - off] : 0;
    __syncthreads();
    s[t] += v;
    __syncthreads();
  }
  int excl = s[t] - ts;
  if (base + 0 < NN) rowstart[base + 0] = excl;  excl += c0;
  if (base + 1 < NN) rowstart[base + 1] = excl;  excl += c1;
  if (base + 2 < NN) rowstart[base + 2] = excl;  excl += c2;
  if (base + 3 < NN) rowstart[base + 3] = excl;
  if (t == 255) bsum[blockIdx.x] = s[255];
}

__global__ void k_scanB(const int* __restrict__ bsum, int* __restrict__ bscan) {
  __shared__ int s[128];
  int t = threadIdx.x;
  int v = (t < NB_SCAN) ? bsum[t] : 0;
  s[t] = v;
  __syncthreads();
  for (int off = 1; off < 128; off <<= 1) {
    int u = (t >= off) ? s[t - off] : 0;
    __syncthreads();
    s[t] += u;
    __syncthreads();
  }
  if (t < NB_SCAN) bscan[t] = s[t] - v;
}

__global__ __launch_bounds__(256) void k_scanC(int* __restrict__ rowstart,
                                               const int* __restrict__ bscan,
                                               int* __restrict__ srcl) {
  int off = bscan[blockIdx.x];
  int base = blockIdx.x * SCAN_BLK + threadIdx.x * 4;
#pragma unroll
  for (int j = 0; j < 4; ++j) {
    int i = base + j;
    if (i < NN) {
      int r = rowstart[i] + off;
      rowstart[i] = r;
      srcl[r] = i;            // self-loop first entry
    }
  }
}

// ---------------- bucketed fill ----------------
__global__ void k_binit(const int* __restrict__ rowstart, int* __restrict__ Bcur) {
  int t = threadIdx.x;
  if (t < NBK) Bcur[t] = rowstart[t * BROWS] - t * BROWS;
}

__global__ __launch_bounds__(256) void k_part(
    const int* __restrict__ ei, int* __restrict__ Bcur,
    uint2* __restrict__ ebuf) {
  __shared__ int hist[256], start[256], cnt[256], gbase[256];
  __shared__ int ssrc[PCHUNK], sdst[PCHUNK];
  const int t = threadIdx.x;
  hist[t] = 0; cnt[t] = 0;
  __syncthreads();
  const int e0 = blockIdx.x * PCHUNK;
  for (int i = t; i < PCHUNK; i += 256)
    atomicAdd(&hist[ei[NE + e0 + i] >> 9], 1);
  __syncthreads();
  int v = hist[t];
  start[t] = v;
  __syncthreads();
  for (int off = 1; off < 256; off <<= 1) {
    int u = (t >= off) ? start[t - off] : 0;
    __syncthreads();
    start[t] += u;
    __syncthreads();
  }
  int incl = start[t];
  __syncthreads();
  start[t] = incl - v;                       // exclusive
  if (v > 0) gbase[t] = atomicAdd(&Bcur[t], v);
  __syncthreads();
  for (int i = t; i < PCHUNK; i += 256) {
    int src = ei[e0 + i];
    int dst = ei[NE + e0 + i];
    int b = dst >> 9;
    int p = start[b] + atomicAdd(&cnt[b], 1);
    ssrc[p] = src; sdst[p] = dst;
  }
  __syncthreads();
  for (int i = t; i < PCHUNK; i += 256) {
    int dst = sdst[i];
    int b = dst >> 9;
    uint2 pr; pr.x = (uint_t)ssrc[i]; pr.y = (uint_t)dst;
    ebuf[gbase[b] + (i - start[b])] = pr;
  }
}

__global__ __launch_bounds__(256) void k_fill2(
    const int* __restrict__ rowstart, const uint2* __restrict__ ebuf,
    int* __restrict__ srcl) {
  __shared__ int c[BROWS];
  const int b = blockIdx.x;
  const int r0 = b * BROWS;
  const int rend = min(r0 + BROWS, NN);
  for (int i = threadIdx.x; i < rend - r0; i += 256)
    c[i] = rowstart[r0 + i] + 1;             // slot 0 = self-loop
  __syncthreads();
  const int eb0 = rowstart[r0] - r0;
  const int eb1 = (b == NBK - 1) ? NE : rowstart[r0 + BROWS] - (r0 + BROWS);
  for (int e = eb0 + (int)threadIdx.x; e < eb1; e += 256) {
    uint2 pr = ebuf[e];
    int p = atomicAdd(&c[(int)pr.y - r0], 1);
    srcl[p] = (int)pr.x;
  }
}

// ---------------- gather: h2[r] = b + sum_{srcl entries incl self} g[s] ----------------
// Flat edge stream per wave (8 contiguous rows), 3-deep pipeline (48 loads
// in flight): issue A,B,C; steady state waits vmcnt(32) -> oldest chunk done
// (stores issued in between also drain, keeping the invariant).
#define RF(x) __builtin_amdgcn_readfirstlane(x)
#define GLD(V, I) asm volatile("global_load_ushort %0, %1, %2" \
    : "=v"(V) : "v"(voff), "s"(g + (size_t)(I) * HH) : "memory")
#define WAIT32 do { asm volatile("s_waitcnt vmcnt(32)" ::: "memory"); \
    __builtin_amdgcn_sched_barrier(0); } while (0)
#define WAIT16 do { asm volatile("s_waitcnt vmcnt(16)" ::: "memory"); \
    __builtin_amdgcn_sched_barrier(0); } while (0)
#define WAIT0 do { asm volatile("s_waitcnt vmcnt(0)" ::: "memory"); \
    __builtin_amdgcn_sched_barrier(0); } while (0)
#define ISSUE16(P, EB) do { \
  int j0 = RF(srcl[(EB) + 0]),  j1 = RF(srcl[(EB) + 1]); \
  int j2 = RF(srcl[(EB) + 2]),  j3 = RF(srcl[(EB) + 3]); \
  int j4 = RF(srcl[(EB) + 4]),  j5 = RF(srcl[(EB) + 5]); \
  int j6 = RF(srcl[(EB) + 6]),  j7 = RF(srcl[(EB) + 7]); \
  int j8 = RF(srcl[(EB) + 8]),  j9 = RF(srcl[(EB) + 9]); \
  int j10 = RF(srcl[(EB) + 10]), j11 = RF(srcl[(EB) + 11]); \
  int j12 = RF(srcl[(EB) + 12]), j13 = RF(srcl[(EB) + 13]); \
  int j14 = RF(srcl[(EB) + 14]), j15 = RF(srcl[(EB) + 15]); \
  GLD(P##0, j0);  GLD(P##1, j1);  GLD(P##2, j2);  GLD(P##3, j3); \
  GLD(P##4, j4);  GLD(P##5, j5);  GLD(P##6, j6);  GLD(P##7, j7); \
  GLD(P##8, j8);  GLD(P##9, j9);  GLD(P##10, j10); GLD(P##11, j11); \
  GLD(P##12, j12); GLD(P##13, j13); GLD(P##14, j14); GLD(P##15, j15); \
} while (0)
#define CJ(V, EI) do { \
  if ((EI) == nb) { \
    h2[(size_t)cur * HH + lane] = acc; ps += acc; pss += acc * acc; \
    cur++; nb = __builtin_amdgcn_readlane(rsv, cur - wra); acc = bc; \
  } \
  acc += bf2f(V); } while (0)
#define CONS16(P, EB) do { \
  CJ(P##0, (EB) + 0);  CJ(P##1, (EB) + 1);  CJ(P##2, (EB) + 2);  CJ(P##3, (EB) + 3); \
  CJ(P##4, (EB) + 4);  CJ(P##5, (EB) + 5);  CJ(P##6, (EB) + 6);  CJ(P##7, (EB) + 7); \
  CJ(P##8, (EB) + 8);  CJ(P##9, (EB) + 9);  CJ(P##10, (EB) + 10); CJ(P##11, (EB) + 11); \
  CJ(P##12, (EB) + 12); CJ(P##13, (EB) + 13); CJ(P##14, (EB) + 14); CJ(P##15, (EB) + 15); \
} while (0)

__global__ __launch_bounds__(256) void k_gather(
    const ushort_t* __restrict__ g, const int* __restrict__ rowstart,
    const int* __restrict__ srcl, const float* __restrict__ bias,
    float* __restrict__ h2, float* __restrict__ stats) {
  const int lane = threadIdx.x & 63;
  const int wid  = threadIdx.x >> 6;
  const float bc = bias[lane];
  const uint_t voff = lane * 2;
  const int wra = (blockIdx.x * 4 + wid) * 8;

  int ridx = wra + 1 + lane;
  int rsv = (ridx < NN) ? rowstart[ridx] : NTOT;

  int e    = RF(rowstart[wra]);
  int eEnd = __builtin_amdgcn_readlane(rsv, 7);
  int cur  = wra;
  int nb   = __builtin_amdgcn_readlane(rsv, 0);
  float acc = bc, ps = 0.f, pss = 0.f;

  uint_t A0, A1, A2, A3, A4, A5, A6, A7, A8, A9, A10, A11, A12, A13, A14, A15;
  uint_t B0, B1, B2, B3, B4, B5, B6, B7, B8, B9, B10, B11, B12, B13, B14, B15;
  uint_t C0, C1, C2, C3, C4, C5, C6, C7, C8, C9, C10, C11, C12, C13, C14, C15;

  int nf = (eEnd - e) >> 4;
  if (nf >= 3) {
    int pendA = e; ISSUE16(A, e); e += 16;
    int pendB = e; ISSUE16(B, e); e += 16;
    int pendC = e; ISSUE16(C, e); e += 16;
    nf -= 3;
    while (nf >= 3) {
      WAIT32; CONS16(A, pendA); pendA = e; ISSUE16(A, e); e += 16;
      WAIT32; CONS16(B, pendB); pendB = e; ISSUE16(B, e); e += 16;
      WAIT32; CONS16(C, pendC); pendC = e; ISSUE16(C, e); e += 16;
      nf -= 3;
    }
    if (nf == 0) {
      WAIT32; CONS16(A, pendA);
      WAIT16; CONS16(B, pendB);
      WAIT0;  CONS16(C, pendC);
    } else if (nf == 1) {
      WAIT32; CONS16(A, pendA); pendA = e; ISSUE16(A, e); e += 16;
      WAIT32; CONS16(B, pendB);
      WAIT16; CONS16(C, pendC);
      WAIT0;  CONS16(A, pendA);
    } else {
      WAIT32; CONS16(A, pendA); pendA = e; ISSUE16(A, e); e += 16;
      WAIT32; CONS16(B, pendB); pendB = e; ISSUE16(B, e); e += 16;
      WAIT32; CONS16(C, pendC);
      WAIT16; CONS16(A, pendA);
      WAIT0;  CONS16(B, pendB);
    }
  } else if (nf == 2) {
    int pendA = e; ISSUE16(A, e); e += 16;
    int pendB = e; ISSUE16(B, e); e += 16;
    WAIT16; CONS16(A, pendA);
    WAIT0;  CONS16(B, pendB);
  } else if (nf == 1) {
    int pendA = e; ISSUE16(A, e); e += 16;
    WAIT0;  CONS16(A, pendA);
  }
  for (; e < eEnd; ++e) {
    if (e == nb) {
      h2[(size_t)cur * HH + lane] = acc; ps += acc; pss += acc * acc;
      cur++; nb = __builtin_amdgcn_readlane(rsv, cur - wra); acc = bc;
    }
    int i = RF(srcl[e]);
    acc += bf2f(g[(size_t)i * HH + lane]);
  }
  h2[(size_t)cur * HH + lane] = acc; ps += acc; pss += acc * acc;

  __shared__ float sred[4][128];
  sred[wid][lane] = ps;
  sred[wid][64 + lane] = pss;
  __syncthreads();
  if (wid == 0) {
    float s0 = sred[0][lane] + sred[1][lane] + sred[2][lane] + sred[3][lane];
    float q0 = sred[0][64 + lane] + sred[1][64 + lane] + sred[2][64 + lane] + sred[3][64 + lane];
    atomicAdd(&stats[lane], s0);
    atomicAdd(&stats[HH + lane], q0);
  }
}

// ---------------- final: wsi = max0 + max1 ----------------
__global__ void k_wsi(const float* __restrict__ m0, const float* __restrict__ m1,
                      float* __restrict__ out) {
  int i = threadIdx.x;
  out[i] = m0[i] + m1[i];
}

extern "C" void kernel_launch(void* const* d_in, const int* in_sizes, int n_in,
                              void* d_out, int out_size, void* d_ws, size_t ws_size,
                              hipStream_t stream) {
  const float* x    = (const float*)d_in[0];
  const int*   ei   = (const int*)d_in[1];
  const int*   bat  = (const int*)d_in[2];
  const float* Wf   = (const float*)d_in[3];
  const float* bf   = (const float*)d_in[4];
  const float* g1   = (const float*)d_in[5];
  const float* be1  = (const float*)d_in[6];
  const float* Wl0  = (const float*)d_in[7];
  const float* bl0  = (const float*)d_in[8];
  const float* Wc   = (const float*)d_in[9];
  const float* bc   = (const float*)d_in[10];
  const float* g2   = (const float*)d_in[11];
  const float* be2  = (const float*)d_in[12];
  const float* Wl1  = (const float*)d_in[13];
  const float* bl1  = (const float*)d_in[14];

  float* out   = (float*)d_out;
  float* wsi   = out;                 // [8,4]
  float* npred = out + GG * TT;       // [N,4]

  float*    ws     = (float*)d_ws;
  float*    hbuf   = ws;                              // N*H fp32 (h2)
  ushort_t* h1bf   = (ushort_t*)(hbuf + (size_t)NN * HH);  // N*H bf16 (h1)
  ushort_t* gbf    = h1bf + (size_t)NN * HH;          // N*H bf16 (g)
  float*    stats1 = (float*)(gbf + (size_t)NN * HH); // 256
  float*    stats2 = stats1 + 256;                    // 256
  float*    maxb   = stats2 + 256;                    // 64
  int*      deg      = (int*)(maxb + 64);             // N
  int*      rowstart = deg + NN;                      // N
  int*      Bcur     = rowstart + NN;                 // 256
  int*      bsum     = Bcur + 256;                    // 128
  int*      bscan    = bsum + 128;                    // 128
  int*      srcl     = bscan + 128;                   // NE+NN (self-loops)
  uint2*    ebuf     = (uint2*)(srcl + NTOT);         // NE pairs
  ushort_t* Wbf      = (ushort_t*)(ebuf + NE);        // DF*HH
  ushort_t* Wbf2     = Wbf + DF * HH;                 // HH*HH

  hipMemsetAsync(deg, 0, NN * sizeof(int), stream);
  k_init<<<dim3(1), dim3(512), 0, stream>>>(stats1, maxb);
  k_prep<<<dim3(64), dim3(256), 0, stream>>>(Wf, Wbf, DF * HH);
  k_prep<<<dim3(16), dim3(256), 0, stream>>>(Wc, Wbf2, HH * HH);

  // CSR build (self-loop slot reserved per row) — bucketed fill
  k_count<<<dim3(1024), dim3(256), 0, stream>>>(ei, deg);
  k_scanA<<<dim3(NB_SCAN), dim3(256), 0, stream>>>(deg, rowstart, bsum);
  k_scanB<<<dim3(1), dim3(128), 0, stream>>>(bsum, bscan);
  k_scanC<<<dim3(NB_SCAN), dim3(256), 0, stream>>>(rowstart, bscan, srcl);
  k_binit<<<dim3(1), dim3(256), 0, stream>>>(rowstart, Bcur);
  k_part<<<dim3(NPB), dim3(256), 0, stream>>>(ei, Bcur, ebuf);
  k_fill2<<<dim3(NBK), dim3(256), 0, stream>>>(rowstart, ebuf, srcl);

  // Layer 0: GEMM + stats
  k_gemm1_mfma<<<dim3(512), dim3(256), 0, stream>>>(x, Wbf, bf, h1bf, stats1);
  k_finalize_bn<<<dim3(1), dim3(64), 0, stream>>>(stats1, g1, be1, stats1 + 128);
  k_norm_gemm2<<<dim3(512), dim3(256), 0, stream>>>(
      h1bf, stats1 + 128, Wl0, bl0, bat, Wbf2, npred, maxb, gbf);

  // Layer 1: h2 = b + g + A.g (3-deep pipelined flat-stream gather)
  k_gather<<<dim3(NN / 32), dim3(256), 0, stream>>>(
      gbf, rowstart, srcl, bc, hbuf, stats2);
  k_finalize_bn<<<dim3(1), dim3(64), 0, stream>>>(stats2, g2, be2, stats2 + 128);
  k_norm_np<<<dim3(512), dim3(256), 0, stream>>>(
      hbuf, stats2 + 128, Wl1, bl1, bat, npred, maxb + 32, (NN + 511) / 512);

  k_wsi<<<dim3(1), dim3(32), 0, stream>>>(maxb, maxb + 32, wsi);
}

// Round 14
// 299.689 us; speedup vs baseline: 2.6842x; 1.2363x over previous
//
#include <hip/hip_runtime.h>
#include <math.h>

#define NN 100000
#define NE 1600000
#define DF 256
#define HH 64
#define TT 4
#define GG 8
#define BN_EPS 1e-5f
#define NTOT (NE + NN)               // srcl entries incl. self-loops

#define BROWS 512                    // rows per bucket
#define NBK ((NN + BROWS - 1) / BROWS)   // 196
#define BCAP 10240                   // bucket capacity (mean 8192, sigma 90)
#define PCHUNK 1600
#define NPB (NE / PCHUNK)            // 1000

typedef __attribute__((ext_vector_type(8))) short short8v;
typedef __attribute__((ext_vector_type(4))) float f32x4;
typedef unsigned short ushort_t;
typedef unsigned int uint_t;

__device__ __forceinline__ void atomicMaxF(float* addr, float val) {
  if (val >= 0.f) atomicMax((int*)addr, __float_as_int(val));
  else            atomicMin((unsigned int*)addr, __float_as_uint(val));
}

__device__ __forceinline__ short f2bf(float f) {
  uint_t u = __float_as_uint(f);
  u += 0x7FFFu + ((u >> 16) & 1u);
  return (short)(u >> 16);
}
__device__ __forceinline__ float bf2f(uint_t u) { return __uint_as_float(u << 16); }
__device__ __forceinline__ float bfhi(uint_t u) { return __uint_as_float(u & 0xFFFF0000u); }

// ---------------- setup: W->bf16, stats=0, maxb=-inf, Bcnt=0 ----------------
__global__ void k_setup(const float* __restrict__ Wf, ushort_t* __restrict__ Wbf,
                        const float* __restrict__ Wc, ushort_t* __restrict__ Wbf2,
                        float* __restrict__ stats, float* __restrict__ maxb,
                        int* __restrict__ Bcnt) {
  int i = blockIdx.x * 256 + threadIdx.x;       // 80 blocks x 256 = 20480
  if (i < DF * HH) Wbf[i] = (ushort_t)f2bf(Wf[i]);
  else {
    int j = i - DF * HH;
    if (j < HH * HH) Wbf2[j] = (ushort_t)f2bf(Wc[j]);
  }
  if (i < 512) stats[i] = 0.f;
  if (i < 64)  maxb[i]  = -INFINITY;
  if (i < NBK) Bcnt[i]  = 0;
}

// ---------------- GEMM1 (MFMA bf16): h1 = x @ W_first + b (bf16 out), + BN stats ----------------
__global__ __launch_bounds__(256, 2) void k_gemm1_mfma(
    const float* __restrict__ x, const ushort_t* __restrict__ Wbf,
    const float* __restrict__ b, ushort_t* __restrict__ h1,
    float* __restrict__ stats) {
  const int lane = threadIdx.x & 63;
  const int li = lane & 15;
  const int lh = lane >> 4;
  const int gw = (blockIdx.x * 256 + (int)threadIdx.x) >> 6;
  const int nw = (gridDim.x * 256) >> 6;

  short8v bf[8][4];
#pragma unroll
  for (int s = 0; s < 8; ++s)
#pragma unroll
    for (int ct = 0; ct < 4; ++ct)
#pragma unroll
      for (int e = 0; e < 8; ++e)
        bf[s][ct][e] = (short)Wbf[(32 * s + 8 * lh + e) * HH + ct * 16 + li];

  float bias[4];
#pragma unroll
  for (int ct = 0; ct < 4; ++ct) bias[ct] = b[ct * 16 + li];

  float ps[4] = {0.f, 0.f, 0.f, 0.f}, pss[4] = {0.f, 0.f, 0.f, 0.f};

  for (int t = gw; t < NN / 16; t += nw) {
    const float* xb = x + (size_t)(t * 16 + li) * DF + 8 * lh;
    f32x4 acc[4];
#pragma unroll
    for (int ct = 0; ct < 4; ++ct) acc[ct] = (f32x4){0.f, 0.f, 0.f, 0.f};

#pragma unroll
    for (int s = 0; s < 8; ++s) {
      float4 a0 = *(const float4*)(xb + 32 * s);
      float4 a1 = *(const float4*)(xb + 32 * s + 4);
      short8v af;
      af[0] = f2bf(a0.x); af[1] = f2bf(a0.y); af[2] = f2bf(a0.z); af[3] = f2bf(a0.w);
      af[4] = f2bf(a1.x); af[5] = f2bf(a1.y); af[6] = f2bf(a1.z); af[7] = f2bf(a1.w);
#pragma unroll
      for (int ct = 0; ct < 4; ++ct)
        acc[ct] = __builtin_amdgcn_mfma_f32_16x16x32_bf16(af, bf[s][ct], acc[ct], 0, 0, 0);
    }

    ushort_t* hb = h1 + (size_t)t * 16 * HH;
#pragma unroll
    for (int ct = 0; ct < 4; ++ct) {
#pragma unroll
      for (int r = 0; r < 4; ++r) {
        float h = acc[ct][r] + bias[ct];
        hb[(lh * 4 + r) * HH + ct * 16 + li] = (ushort_t)f2bf(h);
        ps[ct] += h; pss[ct] += h * h;
      }
    }
  }

#pragma unroll
  for (int ct = 0; ct < 4; ++ct) {
    ps[ct]  += __shfl_xor(ps[ct], 16);  ps[ct]  += __shfl_xor(ps[ct], 32);
    pss[ct] += __shfl_xor(pss[ct], 16); pss[ct] += __shfl_xor(pss[ct], 32);
  }
  if (lane < 16) {
#pragma unroll
    for (int ct = 0; ct < 4; ++ct) {
      atomicAdd(&stats[ct * 16 + lane], ps[ct]);
      atomicAdd(&stats[HH + ct * 16 + lane], pss[ct]);
    }
  }
}

// ---------------- BN finalize ----------------
__global__ void k_finalize_bn(const float* __restrict__ sums,
                              const float* __restrict__ gamma,
                              const float* __restrict__ beta,
                              float* __restrict__ ab) {
  int c = threadIdx.x;                                // 64 threads
  float mu  = sums[c] * (1.f / NN);
  float var = sums[HH + c] * (1.f / NN) - mu * mu;
  float a = gamma[c] * rsqrtf(var + BN_EPS);
  ab[c] = a;
  ab[HH + c] = beta[c] - mu * a;
}

// ---------------- fused: normalize(h1 bf16)+ReLU; np0 + pool via 5th MFMA tile;
//                  g = f @ W_conv (bf16 out) ----------------
__global__ __launch_bounds__(256) void k_norm_gemm2(
    const ushort_t* __restrict__ h1, const float* __restrict__ ab,
    const float* __restrict__ Wl0, const float* __restrict__ bl0,
    const int* __restrict__ batch, const ushort_t* __restrict__ Wbf2,
    float* __restrict__ node_pred, float* __restrict__ maxbuf,
    ushort_t* __restrict__ g) {
  __shared__ float lmax[GG * TT];
  if (threadIdx.x < GG * TT) lmax[threadIdx.x] = -INFINITY;
  __syncthreads();

  const int lane = threadIdx.x & 63;
  const int li = lane & 15;
  const int lh = lane >> 4;
  const int gw = (blockIdx.x * 256 + (int)threadIdx.x) >> 6;
  const int nw = (gridDim.x * 256) >> 6;

  short8v bfr[2][4];
#pragma unroll
  for (int s = 0; s < 2; ++s)
#pragma unroll
    for (int ct = 0; ct < 4; ++ct)
#pragma unroll
      for (int e = 0; e < 8; ++e)
        bfr[s][ct][e] = (short)Wbf2[(32 * s + 8 * lh + e) * HH + ct * 16 + li];

  short8v bhd[2];
#pragma unroll
  for (int s = 0; s < 2; ++s)
#pragma unroll
    for (int e = 0; e < 8; ++e)
      bhd[s][e] = (li < TT) ? f2bf(Wl0[(32 * s + 8 * lh + e) * TT + li]) : (short)0;

  const float4 sa0 = *(const float4*)(ab + 8 * lh);
  const float4 sa1 = *(const float4*)(ab + 8 * lh + 4);
  const float4 sb0 = *(const float4*)(ab + HH + 8 * lh);
  const float4 sb1 = *(const float4*)(ab + HH + 8 * lh + 4);
  const float4 ta0 = *(const float4*)(ab + 32 + 8 * lh);
  const float4 ta1 = *(const float4*)(ab + 32 + 8 * lh + 4);
  const float4 tb0 = *(const float4*)(ab + HH + 32 + 8 * lh);
  const float4 tb1 = *(const float4*)(ab + HH + 32 + 8 * lh + 4);
  const float blv = (li < TT) ? bl0[li] : 0.f;

  for (int t = gw; t < NN / 16; t += nw) {
    const ushort_t* hb = h1 + (size_t)(t * 16 + li) * HH + 8 * lh;
    uint4 xa = *(const uint4*)(hb);
    uint4 xc = *(const uint4*)(hb + 32);

    short8v af0, af1;
    af0[0] = f2bf(fmaxf(fmaf(sa0.x, bf2f(xa.x), sb0.x), 0.f));
    af0[1] = f2bf(fmaxf(fmaf(sa0.y, bfhi(xa.x), sb0.y), 0.f));
    af0[2] = f2bf(fmaxf(fmaf(sa0.z, bf2f(xa.y), sb0.z), 0.f));
    af0[3] = f2bf(fmaxf(fmaf(sa0.w, bfhi(xa.y), sb0.w), 0.f));
    af0[4] = f2bf(fmaxf(fmaf(sa1.x, bf2f(xa.z), sb1.x), 0.f));
    af0[5] = f2bf(fmaxf(fmaf(sa1.y, bfhi(xa.z), sb1.y), 0.f));
    af0[6] = f2bf(fmaxf(fmaf(sa1.z, bf2f(xa.w), sb1.z), 0.f));
    af0[7] = f2bf(fmaxf(fmaf(sa1.w, bfhi(xa.w), sb1.w), 0.f));
    af1[0] = f2bf(fmaxf(fmaf(ta0.x, bf2f(xc.x), tb0.x), 0.f));
    af1[1] = f2bf(fmaxf(fmaf(ta0.y, bfhi(xc.x), tb0.y), 0.f));
    af1[2] = f2bf(fmaxf(fmaf(ta0.z, bf2f(xc.y), tb0.z), 0.f));
    af1[3] = f2bf(fmaxf(fmaf(ta0.w, bfhi(xc.y), tb0.w), 0.f));
    af1[4] = f2bf(fmaxf(fmaf(ta1.x, bf2f(xc.z), tb1.x), 0.f));
    af1[5] = f2bf(fmaxf(fmaf(ta1.y, bfhi(xc.z), tb1.y), 0.f));
    af1[6] = f2bf(fmaxf(fmaf(ta1.z, bf2f(xc.w), tb1.z), 0.f));
    af1[7] = f2bf(fmaxf(fmaf(ta1.w, bfhi(xc.w), tb1.w), 0.f));

    f32x4 acc[4], acch;
#pragma unroll
    for (int ct = 0; ct < 4; ++ct) {
      acc[ct] = (f32x4){0.f, 0.f, 0.f, 0.f};
      acc[ct] = __builtin_amdgcn_mfma_f32_16x16x32_bf16(af0, bfr[0][ct], acc[ct], 0, 0, 0);
      acc[ct] = __builtin_amdgcn_mfma_f32_16x16x32_bf16(af1, bfr[1][ct], acc[ct], 0, 0, 0);
    }
    acch = (f32x4){0.f, 0.f, 0.f, 0.f};
    acch = __builtin_amdgcn_mfma_f32_16x16x32_bf16(af0, bhd[0], acch, 0, 0, 0);
    acch = __builtin_amdgcn_mfma_f32_16x16x32_bf16(af1, bhd[1], acch, 0, 0, 0);

    ushort_t* gb = g + (size_t)t * 16 * HH;
#pragma unroll
    for (int ct = 0; ct < 4; ++ct)
#pragma unroll
      for (int r = 0; r < 4; ++r)
        gb[(lh * 4 + r) * HH + ct * 16 + li] = (ushort_t)f2bf(acc[ct][r]);

    if (li < TT) {
#pragma unroll
      for (int r = 0; r < 4; ++r) {
        int row = t * 16 + lh * 4 + r;
        float np = acch[r] + blv;
        atomicMaxF(&lmax[batch[row] * TT + li], np);
        node_pred[(size_t)row * TT + li] = np;
      }
    }
  }
  __syncthreads();
  if (threadIdx.x < GG * TT) atomicMaxF(&maxbuf[threadIdx.x], lmax[threadIdx.x]);
}

// ---------------- normalize+ReLU + head + max-pool (layer 1 epilogue, bf16 in) ----------------
__global__ __launch_bounds__(256) void k_norm_np(
    const ushort_t* __restrict__ hin,
    const float* __restrict__ ab, const float* __restrict__ Wlin,
    const float* __restrict__ blin, const int* __restrict__ batch,
    float* __restrict__ node_pred, float* __restrict__ maxbuf, int rpb) {
  __shared__ float lmax[GG * TT];
  if (threadIdx.x < GG * TT) lmax[threadIdx.x] = -INFINITY;
  __syncthreads();

  const int lane = threadIdx.x & 63;
  const int wid  = threadIdx.x >> 6;
  const float a  = ab[lane];
  const float b2 = ab[HH + lane];
  const float4 w = ((const float4*)Wlin)[lane];
  const float4 bl = *(const float4*)blin;
  int r0 = blockIdx.x * rpb;
  int r1 = min(r0 + rpb, NN);

  for (int r = r0 + wid; r < r1; r += 4) {
    float h = bf2f(hin[(size_t)r * HH + lane]);
    float f = fmaxf(fmaf(a, h, b2), 0.f);
    float p0 = f * w.x, p1 = f * w.y, p2 = f * w.z, p3 = f * w.w;
#pragma unroll
    for (int off = 32; off; off >>= 1) {
      p0 += __shfl_xor(p0, off);
      p1 += __shfl_xor(p1, off);
      p2 += __shfl_xor(p2, off);
      p3 += __shfl_xor(p3, off);
    }
    if (lane == 0) {
      float4 np;
      np.x = p0 + bl.x; np.y = p1 + bl.y; np.z = p2 + bl.z; np.w = p3 + bl.w;
      int g = batch[r];
      atomicMaxF(&lmax[g * TT + 0], np.x);
      atomicMaxF(&lmax[g * TT + 1], np.y);
      atomicMaxF(&lmax[g * TT + 2], np.z);
      atomicMaxF(&lmax[g * TT + 3], np.w);
      float4* op = (float4*)(node_pred + (size_t)r * TT);
      float4 o = *op;
      np.x += o.x; np.y += o.y; np.z += o.z; np.w += o.w;
      *op = np;
    }
  }
  __syncthreads();
  if (threadIdx.x < GG * TT) atomicMaxF(&maxbuf[threadIdx.x], lmax[threadIdx.x]);
}

// ---------------- bucketed CSR build ----------------
// k_part: bin edges by dst-bucket via LDS; fixed-capacity bucket regions.
__global__ __launch_bounds__(256) void k_part(
    const int* __restrict__ ei, int* __restrict__ Bcnt,
    uint2* __restrict__ ebuf) {
  __shared__ int hist[256], start[256], cnt[256], gbase[256];
  __shared__ int ssrc[PCHUNK], sdst[PCHUNK];
  const int t = threadIdx.x;
  hist[t] = 0; cnt[t] = 0;
  __syncthreads();
  const int e0 = blockIdx.x * PCHUNK;
  for (int i = t; i < PCHUNK; i += 256)
    atomicAdd(&hist[ei[NE + e0 + i] >> 9], 1);
  __syncthreads();
  int v = hist[t];
  start[t] = v;
  __syncthreads();
  for (int off = 1; off < 256; off <<= 1) {
    int u = (t >= off) ? start[t - off] : 0;
    __syncthreads();
    start[t] += u;
    __syncthreads();
  }
  int incl = start[t];
  __syncthreads();
  start[t] = incl - v;                       // exclusive
  if (v > 0) gbase[t] = atomicAdd(&Bcnt[t], v);
  __syncthreads();
  for (int i = t; i < PCHUNK; i += 256) {
    int src = ei[e0 + i];
    int dst = ei[NE + e0 + i];
    int b = dst >> 9;
    int p = start[b] + atomicAdd(&cnt[b], 1);
    ssrc[p] = src; sdst[p] = dst;
  }
  __syncthreads();
  for (int i = t; i < PCHUNK; i += 256) {
    int dst = sdst[i];
    int b = dst >> 9;
    uint2 pr; pr.x = (uint_t)ssrc[i]; pr.y = (uint_t)dst;
    ebuf[(size_t)b * BCAP + gbase[b] + (i - start[b])] = pr;
  }
}

// k_bscan: bucket bases = exclusive scan of (Bcnt[b] + rows_in_bucket)
__global__ void k_bscan(const int* __restrict__ Bcnt, int* __restrict__ Bbase) {
  __shared__ int s[256];
  int t = threadIdx.x;
  int v = 0;
  if (t < NBK) {
    int rows = min(BROWS, NN - t * BROWS);
    v = Bcnt[t] + rows;
  }
  s[t] = v;
  __syncthreads();
  for (int off = 1; off < 256; off <<= 1) {
    int u = (t >= off) ? s[t - off] : 0;
    __syncthreads();
    s[t] += u;
    __syncthreads();
  }
  if (t < NBK) Bbase[t] = s[t] - v;
}

// k_fill2: per bucket: LDS histogram -> LDS scan -> rowstart (coalesced) +
// self-loops + LDS-cursor scatter of srcl into a 34KB window.
__global__ __launch_bounds__(256) void k_fill2(
    const int* __restrict__ Bcnt, const int* __restrict__ Bbase,
    const uint2* __restrict__ ebuf, int* __restrict__ rowstart,
    int* __restrict__ srcl) {
  __shared__ int cnt[BROWS];
  __shared__ int ssum[256];
  const int b = blockIdx.x;
  const int r0 = b * BROWS;
  const int nrows = min(BROWS, NN - r0);
  const int ne = Bcnt[b];
  const int base = Bbase[b];
  const uint2* eb = ebuf + (size_t)b * BCAP;
  const int t = threadIdx.x;

  cnt[2 * t] = (2 * t < nrows) ? 1 : 0;
  cnt[2 * t + 1] = (2 * t + 1 < nrows) ? 1 : 0;
  __syncthreads();
  for (int j = t; j < ne; j += 256)
    atomicAdd(&cnt[(int)eb[j].y - r0], 1);
  __syncthreads();

  int a0 = cnt[2 * t], a1 = cnt[2 * t + 1];
  ssum[t] = a0 + a1;
  __syncthreads();
  for (int off = 1; off < 256; off <<= 1) {
    int u = (t >= off) ? ssum[t - off] : 0;
    __syncthreads();
    ssum[t] += u;
    __syncthreads();
  }
  int e0 = base + ssum[t] - (a0 + a1);       // abs rowstart of row 2t
  int e1 = e0 + a0;                          // abs rowstart of row 2t+1
  __syncthreads();
  if (2 * t < nrows)     { rowstart[r0 + 2 * t] = e0;     srcl[e0] = r0 + 2 * t; }
  if (2 * t + 1 < nrows) { rowstart[r0 + 2 * t + 1] = e1; srcl[e1] = r0 + 2 * t + 1; }
  cnt[2 * t] = e0 + 1;
  cnt[2 * t + 1] = e1 + 1;
  __syncthreads();
  for (int j = t; j < ne; j += 256) {
    uint2 pr = eb[j];
    int p = atomicAdd(&cnt[(int)pr.y - r0], 1);
    srcl[p] = (int)pr.x;
  }
}

// ---------------- gather: h2[r] = b + sum_{srcl entries incl self} g[s] ----------------
// Flat edge stream per wave (8 contiguous rows), 2-deep ping-pong pipeline
// (R12 config: VGPR 28, occupancy ~60% -- the proven best point). bf16 h2 out.
#define RF(x) __builtin_amdgcn_readfirstlane(x)
#define GLD(V, I) asm volatile("global_load_ushort %0, %1, %2" \
    : "=v"(V) : "v"(voff), "s"(g + (size_t)(I) * HH) : "memory")
#define WAIT16 do { asm volatile("s_waitcnt vmcnt(16)" ::: "memory"); \
    __builtin_amdgcn_sched_barrier(0); } while (0)
#define WAIT0 do { asm volatile("s_waitcnt vmcnt(0)" ::: "memory"); \
    __builtin_amdgcn_sched_barrier(0); } while (0)
#define ISSUE16(P, EB) do { \
  int j0 = RF(srcl[(EB) + 0]),  j1 = RF(srcl[(EB) + 1]); \
  int j2 = RF(srcl[(EB) + 2]),  j3 = RF(srcl[(EB) + 3]); \
  int j4 = RF(srcl[(EB) + 4]),  j5 = RF(srcl[(EB) + 5]); \
  int j6 = RF(srcl[(EB) + 6]),  j7 = RF(srcl[(EB) + 7]); \
  int j8 = RF(srcl[(EB) + 8]),  j9 = RF(srcl[(EB) + 9]); \
  int j10 = RF(srcl[(EB) + 10]), j11 = RF(srcl[(EB) + 11]); \
  int j12 = RF(srcl[(EB) + 12]), j13 = RF(srcl[(EB) + 13]); \
  int j14 = RF(srcl[(EB) + 14]), j15 = RF(srcl[(EB) + 15]); \
  GLD(P##0, j0);  GLD(P##1, j1);  GLD(P##2, j2);  GLD(P##3, j3); \
  GLD(P##4, j4);  GLD(P##5, j5);  GLD(P##6, j6);  GLD(P##7, j7); \
  GLD(P##8, j8);  GLD(P##9, j9);  GLD(P##10, j10); GLD(P##11, j11); \
  GLD(P##12, j12); GLD(P##13, j13); GLD(P##14, j14); GLD(P##15, j15); \
} while (0)
#define CJ(V, EI) do { \
  if ((EI) == nb) { \
    h2[(size_t)cur * HH + lane] = (ushort_t)f2bf(acc); ps += acc; pss += acc * acc; \
    cur++; nb = __builtin_amdgcn_readlane(rsv, cur - wra); acc = bc; \
  } \
  acc += bf2f(V); } while (0)
#define CONS16(P, EB) do { \
  CJ(P##0, (EB) + 0);  CJ(P##1, (EB) + 1);  CJ(P##2, (EB) + 2);  CJ(P##3, (EB) + 3); \
  CJ(P##4, (EB) + 4);  CJ(P##5, (EB) + 5);  CJ(P##6, (EB) + 6);  CJ(P##7, (EB) + 7); \
  CJ(P##8, (EB) + 8);  CJ(P##9, (EB) + 9);  CJ(P##10, (EB) + 10); CJ(P##11, (EB) + 11); \
  CJ(P##12, (EB) + 12); CJ(P##13, (EB) + 13); CJ(P##14, (EB) + 14); CJ(P##15, (EB) + 15); \
} while (0)

__global__ __launch_bounds__(256) void k_gather(
    const ushort_t* __restrict__ g, const int* __restrict__ rowstart,
    const int* __restrict__ srcl, const float* __restrict__ bias,
    ushort_t* __restrict__ h2, float* __restrict__ stats) {
  const int lane = threadIdx.x & 63;
  const int wid  = threadIdx.x >> 6;
  const float bc = bias[lane];
  const uint_t voff = lane * 2;
  const int wra = (blockIdx.x * 4 + wid) * 8;

  int ridx = wra + 1 + lane;
  int rsv = (ridx < NN) ? rowstart[ridx] : NTOT;

  int e    = RF(rowstart[wra]);
  int eEnd = __builtin_amdgcn_readlane(rsv, 7);
  int cur  = wra;
  int nb   = __builtin_amdgcn_readlane(rsv, 0);
  float acc = bc, ps = 0.f, pss = 0.f;

  uint_t A0, A1, A2, A3, A4, A5, A6, A7, A8, A9, A10, A11, A12, A13, A14, A15;
  uint_t B0, B1, B2, B3, B4, B5, B6, B7, B8, B9, B10, B11, B12, B13, B14, B15;

  int n = (eEnd - e) >> 4;
  if (n > 0) {
    int pend = e;
    ISSUE16(A, e); e += 16; n--;
    while (n >= 2) {
      int eb = e;
      ISSUE16(B, e); e += 16; n--;
      WAIT16; CONS16(A, pend); pend = eb;
      int ea = e;
      ISSUE16(A, e); e += 16; n--;
      WAIT16; CONS16(B, pend); pend = ea;
    }
    if (n == 1) {
      int eb = e;
      ISSUE16(B, e); e += 16;
      WAIT16; CONS16(A, pend); pend = eb;
      WAIT0;  CONS16(B, pend);
    } else {
      WAIT0;  CONS16(A, pend);
    }
  }
  for (; e < eEnd; ++e) {
    if (e == nb) {
      h2[(size_t)cur * HH + lane] = (ushort_t)f2bf(acc); ps += acc; pss += acc * acc;
      cur++; nb = __builtin_amdgcn_readlane(rsv, cur - wra); acc = bc;
    }
    int i = RF(srcl[e]);
    acc += bf2f(g[(size_t)i * HH + lane]);
  }
  h2[(size_t)cur * HH + lane] = (ushort_t)f2bf(acc); ps += acc; pss += acc * acc;

  __shared__ float sred[4][128];
  sred[wid][lane] = ps;
  sred[wid][64 + lane] = pss;
  __syncthreads();
  if (wid == 0) {
    float s0 = sred[0][lane] + sred[1][lane] + sred[2][lane] + sred[3][lane];
    float q0 = sred[0][64 + lane] + sred[1][64 + lane] + sred[2][64 + lane] + sred[3][64 + lane];
    atomicAdd(&stats[lane], s0);
    atomicAdd(&stats[HH + lane], q0);
  }
}

// ---------------- final: wsi = max0 + max1 ----------------
__global__ void k_wsi(const float* __restrict__ m0, const float* __restrict__ m1,
                      float* __restrict__ out) {
  int i = threadIdx.x;
  out[i] = m0[i] + m1[i];
}

extern "C" void kernel_launch(void* const* d_in, const int* in_sizes, int n_in,
                              void* d_out, int out_size, void* d_ws, size_t ws_size,
                              hipStream_t stream) {
  const float* x    = (const float*)d_in[0];
  const int*   ei   = (const int*)d_in[1];
  const int*   bat  = (const int*)d_in[2];
  const float* Wf   = (const float*)d_in[3];
  const float* bf   = (const float*)d_in[4];
  const float* g1   = (const float*)d_in[5];
  const float* be1  = (const float*)d_in[6];
  const float* Wl0  = (const float*)d_in[7];
  const float* bl0  = (const float*)d_in[8];
  const float* Wc   = (const float*)d_in[9];
  const float* bc   = (const float*)d_in[10];
  const float* g2   = (const float*)d_in[11];
  const float* be2  = (const float*)d_in[12];
  const float* Wl1  = (const float*)d_in[13];
  const float* bl1  = (const float*)d_in[14];

  float* out   = (float*)d_out;
  float* wsi   = out;                 // [8,4]
  float* npred = out + GG * TT;       // [N,4]

  ushort_t* h2bf   = (ushort_t*)d_ws;                 // N*H bf16 (h2)
  ushort_t* h1bf   = h2bf + (size_t)NN * HH;          // N*H bf16 (h1)
  ushort_t* gbf    = h1bf + (size_t)NN * HH;          // N*H bf16 (g)
  float*    stats1 = (float*)(gbf + (size_t)NN * HH); // 256
  float*    stats2 = stats1 + 256;                    // 256
  float*    maxb   = stats2 + 256;                    // 64
  int*      rowstart = (int*)(maxb + 64);             // N
  int*      Bcnt     = rowstart + NN;                 // 256
  int*      Bbase    = Bcnt + 256;                    // 256
  int*      srcl     = Bbase + 256;                   // NE+NN (self-loops)
  uint2*    ebuf     = (uint2*)(srcl + NTOT);         // NBK*BCAP pairs (16 MB)
  ushort_t* Wbf      = (ushort_t*)(ebuf + (size_t)NBK * BCAP);  // DF*HH
  ushort_t* Wbf2     = Wbf + DF * HH;                 // HH*HH

  // setup + bucketed CSR build
  k_setup<<<dim3(80), dim3(256), 0, stream>>>(Wf, Wbf, Wc, Wbf2, stats1, maxb, Bcnt);
  k_part<<<dim3(NPB), dim3(256), 0, stream>>>(ei, Bcnt, ebuf);
  k_bscan<<<dim3(1), dim3(256), 0, stream>>>(Bcnt, Bbase);
  k_fill2<<<dim3(NBK), dim3(256), 0, stream>>>(Bcnt, Bbase, ebuf, rowstart, srcl);

  // Layer 0: GEMM + stats
  k_gemm1_mfma<<<dim3(512), dim3(256), 0, stream>>>(x, Wbf, bf, h1bf, stats1);
  k_finalize_bn<<<dim3(1), dim3(64), 0, stream>>>(stats1, g1, be1, stats1 + 128);
  k_norm_gemm2<<<dim3(512), dim3(256), 0, stream>>>(
      h1bf, stats1 + 128, Wl0, bl0, bat, Wbf2, npred, maxb, gbf);

  // Layer 1: h2 = b + g + A.g (2-deep pipelined flat-stream gather)
  k_gather<<<dim3(NN / 32), dim3(256), 0, stream>>>(
      gbf, rowstart, srcl, bc, h2bf, stats2);
  k_finalize_bn<<<dim3(1), dim3(64), 0, stream>>>(stats2, g2, be2, stats2 + 128);
  k_norm_np<<<dim3(512), dim3(256), 0, stream>>>(
      h2bf, stats2 + 128, Wl1, bl1, bat, npred, maxb + 32, (NN + 511) / 512);

  k_wsi<<<dim3(1), dim3(32), 0, stream>>>(maxb, maxb + 32, wsi);
}